// Round 8
// baseline (389.297 us; speedup 1.0000x reference)
//
#include <hip/hip_runtime.h>

#define N_NODES 50000
#define N_EDGES 800000
#define F_IN    64
#define HEADS   4
#define CH      32
#define K_DIM   128
#define NEG     0.2f

__device__ __forceinline__ float lrelu(float x) { return x > 0.f ? x : NEG * x; }

// ---------------------------------------------------------------------------
// K0: fold We*ae -> v[o][f] (o=0..3 layer1 heads, 4..7 layer2 heads), and
//     cbias = dot(b2, lin_w) + lin_b
// ---------------------------------------------------------------------------
__global__ void k0_fold(const float* __restrict__ We1, const float* __restrict__ ae1,
                        const float* __restrict__ We2, const float* __restrict__ ae2,
                        const float* __restrict__ b2,  const float* __restrict__ linw,
                        const float* __restrict__ linb,
                        float* __restrict__ v, float* __restrict__ cbias) {
    int t = threadIdx.x; // 256 threads
    for (int idx = t; idx < 512; idx += 256) {
        int o = idx >> 6, f = idx & 63;
        const float* We = (o < 4) ? We1 : We2;
        const float* ae = (o < 4) ? ae1 : ae2;
        int h = o & 3;
        float s = 0.f;
        for (int c = 0; c < CH; ++c)
            s += We[f * K_DIM + h * CH + c] * ae[h * CH + c];
        v[o * 64 + f] = s;
    }
    if (t == 0) {
        float s = 0.f;
        for (int k = 0; k < K_DIM; ++k) s += b2[k] * linw[k];
        *cbias = s + linb[0];
    }
}

// ---------------------------------------------------------------------------
// Kc: degree count from ei only.
// ---------------------------------------------------------------------------
__global__ void __launch_bounds__(256)
kc_count(const int* __restrict__ ei, int* __restrict__ cnt) {
    int e = blockIdx.x * 256 + threadIdx.x;
    if (e >= N_EDGES) return;
    atomicAdd(cnt + ei[N_EDGES + e], 1);
}

// ---------------------------------------------------------------------------
// K2: exclusive prefix scan of cnt -> starts[N+1], cursor. Single block,
//     shuffle-based.
// ---------------------------------------------------------------------------
__global__ void __launch_bounds__(1024)
k2_scan(const int* __restrict__ cnt, int* __restrict__ starts, int* __restrict__ cursor) {
    __shared__ int wsum[16];
    __shared__ int s_carry;
    int t = threadIdx.x;
    int lane = t & 63, wid = t >> 6;
    if (t == 0) s_carry = 0;
    __syncthreads();
    for (int base = 0; base < N_NODES; base += 1024) {
        int i = base + t;
        int v = (i < N_NODES) ? cnt[i] : 0;
        int sc = v; // inclusive wave scan
#pragma unroll
        for (int s = 1; s < 64; s <<= 1) {
            int u = __shfl_up(sc, s, 64);
            if (lane >= s) sc += u;
        }
        if (lane == 63) wsum[wid] = sc;
        __syncthreads();
        if (wid == 0 && lane < 16) {
            int ws = wsum[lane];
#pragma unroll
            for (int s = 1; s < 16; s <<= 1) {
                int u = __shfl_up(ws, s, 64);
                if (lane >= s) ws += u;
            }
            wsum[lane] = ws;
        }
        __syncthreads();
        int carry = s_carry;
        int woff = (wid == 0) ? 0 : wsum[wid - 1];
        int excl = carry + woff + sc - v;
        if (i < N_NODES) { starts[i] = excl; cursor[i] = excl; }
        __syncthreads();
        if (t == 0) s_carry = carry + wsum[15];
    }
    __syncthreads();
    if (t == 0) starts[N_NODES] = s_carry;
}

// ---------------------------------------------------------------------------
// K1: per-edge a_e, PURE STREAM (R7 lesson: the fused atomic+scattered-write
//     side pinned k1 at ~140us across 3 structurally different compute
//     schemes; every pipe idle). Coalesced LDS-tile staging, v-row in 16
//     float4 regs, writes aer1/aer2 in EDGE ORDER (128 B contiguous/wave).
//     No atomics, no ei reads, no scattered stores.
// ---------------------------------------------------------------------------
__global__ void __launch_bounds__(256)
k1_edge(const float* __restrict__ ea, const float* __restrict__ v,
        float* __restrict__ aer1, float* __restrict__ aer2) {
    __shared__ float sx[2][32 * 68];
    int t = threadIdx.x;
    int o  = t & 7;   // output index (0..3: layer1 heads, 4..7: layer2 heads)
    int le = t >> 3;  // local edge within tile (0..31)
    float4 vr[16];
    {
        const float4* vrow = reinterpret_cast<const float4*>(v + o * 64);
#pragma unroll
        for (int c = 0; c < 16; ++c) vr[c] = vrow[c];
    }
    const float4* ea4 = reinterpret_cast<const float4*>(ea);
    int base = blockIdx.x * 256; // 8 tiles * 32 edges
    {
        size_t gb = (size_t)base * 16;
        float4 a = ea4[gb + t];
        float4 b = ea4[gb + t + 256];
        int g0 = t, g1 = t + 256;
        *reinterpret_cast<float4*>(&sx[0][(g0 >> 4) * 68 + (g0 & 15) * 4]) = a;
        *reinterpret_cast<float4*>(&sx[0][(g1 >> 4) * 68 + (g1 & 15) * 4]) = b;
    }
    __syncthreads();
    for (int tile = 0; tile < 8; ++tile) {
        float4 a, b;
        if (tile < 7) { // prefetch next tile (coalesced)
            size_t gb = (size_t)(base + (tile + 1) * 32) * 16;
            a = ea4[gb + t];
            b = ea4[gb + t + 256];
        }
        const float* row = &sx[tile & 1][le * 68];
        float4 ac = make_float4(0.f, 0.f, 0.f, 0.f);
#pragma unroll
        for (int c = 0; c < 16; ++c) {
            float4 x4 = *reinterpret_cast<const float4*>(row + c * 4);
            ac.x = fmaf(x4.x, vr[c].x, ac.x);
            ac.y = fmaf(x4.y, vr[c].y, ac.y);
            ac.z = fmaf(x4.z, vr[c].z, ac.z);
            ac.w = fmaf(x4.w, vr[c].w, ac.w);
        }
        float acc = (ac.x + ac.y) + (ac.z + ac.w);
        int eid = base + tile * 32 + le;
        float* ob = (o < 4) ? aer1 : aer2;
        ob[(size_t)eid * 4 + (o & 3)] = acc;   // edge-order: coalesced
        if (tile < 7) { // write next tile into other buffer
            int g0 = t, g1 = t + 256;
            int nb = (tile + 1) & 1;
            *reinterpret_cast<float4*>(&sx[nb][(g0 >> 4) * 68 + (g0 & 15) * 4]) = a;
            *reinterpret_cast<float4*>(&sx[nb][(g1 >> 4) * 68 + (g1 & 15) * 4]) = b;
        }
        __syncthreads();
    }
}

// ---------------------------------------------------------------------------
// K3: scatter into dst-sorted lists. Trivial thread-per-edge kernel, no LDS,
//     low VGPR -> max occupancy; scattered-store latency hidden by TLP.
//     Reads aer sequentially, writes el_* at cursor positions.
// ---------------------------------------------------------------------------
__global__ void __launch_bounds__(256)
k3_scatter(const int* __restrict__ ei, const float4* __restrict__ aer1,
           const float4* __restrict__ aer2, int* __restrict__ cursor,
           int* __restrict__ el_src, float4* __restrict__ el_ae1,
           float4* __restrict__ el_ae2) {
    int e = blockIdx.x * 256 + threadIdx.x;
    if (e >= N_EDGES) return;
    int dst = ei[N_EDGES + e];
    int pos = atomicAdd(cursor + dst, 1);   // issue atomic first (longest latency)
    int src = ei[e];
    float4 a1 = aer1[e];
    float4 a2 = aer2[e];
    el_src[pos] = src;
    el_ae1[pos] = a1;
    el_ae2[pos] = a2;
}

// ---------------------------------------------------------------------------
// K4: layer-1 node projection, register-tiled 4 nodes x 4 cols per thread.
// ---------------------------------------------------------------------------
__global__ void __launch_bounds__(256)
k4_proj1(const float* __restrict__ x, const float* __restrict__ W,
         const float* __restrict__ asf, const float* __restrict__ adf,
         float* __restrict__ hp, float* __restrict__ asn, float* __restrict__ adn) {
    __shared__ float sxT[F_IN * 33]; // [f][i], i in [0,32), pad 1
    int t = threadIdx.x;
    int n0 = blockIdx.x * 32;
    {
        int f = t & 63, i0 = t >> 6;
#pragma unroll
        for (int s = 0; s < 8; ++s) {
            int i = i0 + s * 4;
            int n = n0 + i;
            sxT[f * 33 + i] = (n < N_NODES) ? x[(size_t)n * F_IN + f] : 0.f;
        }
    }
    __syncthreads();
    int kq = t & 31, nq = t >> 5;
    float acc[4][4] = {};
    for (int f = 0; f < F_IN; ++f) {
        float a0 = sxT[f * 33 + nq * 4 + 0];
        float a1 = sxT[f * 33 + nq * 4 + 1];
        float a2 = sxT[f * 33 + nq * 4 + 2];
        float a3 = sxT[f * 33 + nq * 4 + 3];
        float4 w4 = *reinterpret_cast<const float4*>(W + (size_t)f * K_DIM + kq * 4);
        acc[0][0] += a0 * w4.x; acc[0][1] += a0 * w4.y; acc[0][2] += a0 * w4.z; acc[0][3] += a0 * w4.w;
        acc[1][0] += a1 * w4.x; acc[1][1] += a1 * w4.y; acc[1][2] += a1 * w4.z; acc[1][3] += a1 * w4.w;
        acc[2][0] += a2 * w4.x; acc[2][1] += a2 * w4.y; acc[2][2] += a2 * w4.z; acc[2][3] += a2 * w4.w;
        acc[3][0] += a3 * w4.x; acc[3][1] += a3 * w4.y; acc[3][2] += a3 * w4.z; acc[3][3] += a3 * w4.w;
    }
    int head = kq >> 3;
    float4 va = *reinterpret_cast<const float4*>(asf + kq * 4);
    float4 vd = *reinterpret_cast<const float4*>(adf + kq * 4);
#pragma unroll
    for (int i = 0; i < 4; ++i) {
        int n = n0 + nq * 4 + i;
        if (n < N_NODES)
            *reinterpret_cast<float4*>(hp + (size_t)n * K_DIM + kq * 4) =
                make_float4(acc[i][0], acc[i][1], acc[i][2], acc[i][3]);
        float s = acc[i][0] * va.x + acc[i][1] * va.y + acc[i][2] * va.z + acc[i][3] * va.w;
        float d = acc[i][0] * vd.x + acc[i][1] * vd.y + acc[i][2] * vd.z + acc[i][3] * vd.w;
#pragma unroll
        for (int m = 1; m < 8; m <<= 1) {
            s += __shfl_xor(s, m, 8);
            d += __shfl_xor(d, m, 8);
        }
        if ((kq & 7) == 0 && n < N_NODES) {
            asn[(size_t)n * 4 + head] = s;
            adn[(size_t)n * 4 + head] = d;
        }
    }
}

// ---------------------------------------------------------------------------
// K5: layer-1 gather aggregation. One 64-lane wave per node; lane owns 2
//     output columns. No atomics.
// ---------------------------------------------------------------------------
__global__ void __launch_bounds__(256)
k5_agg1(const int* __restrict__ starts, const int* __restrict__ el_src,
        const float* __restrict__ el_ae1,
        const float* __restrict__ asn, const float* __restrict__ adn,
        const float* __restrict__ hp, const float* __restrict__ b1,
        float* __restrict__ x2) {
    int t = threadIdx.x;
    int lane = t & 63;
    int node = blockIdx.x * 4 + (t >> 6);
    if (node >= N_NODES) return;
    int s = starts[node], e = starts[node + 1];
    int head = lane >> 4; // col pair = lane*2; head = (lane*2)>>5
    float adv = adn[(size_t)node * 4 + head];
    float accx = 0.f, accy = 0.f, dsum = 0.f, aesum = 0.f;
    for (int j = s; j < e; ++j) {
        int src = el_src[j];
        float ae = el_ae1[(size_t)j * 4 + head];
        float av = asn[(size_t)src * 4 + head];
        float ex = __expf(lrelu(av + adv + ae));
        float2 hv = *reinterpret_cast<const float2*>(hp + (size_t)src * K_DIM + lane * 2);
        accx += ex * hv.x;
        accy += ex * hv.y;
        dsum += ex;
        aesum += ae;
    }
    float deg = (float)(e - s);
    float al = aesum / fmaxf(deg, 1.f); // self-loop a_e = mean of incoming
    float exl = __expf(lrelu(asn[(size_t)node * 4 + head] + adv + al));
    float2 hv = *reinterpret_cast<const float2*>(hp + (size_t)node * K_DIM + lane * 2);
    accx += exl * hv.x;
    accy += exl * hv.y;
    dsum += exl;
    float2 bb = *reinterpret_cast<const float2*>(b1 + lane * 2);
    float2 o;
    o.x = fmaxf(accx / dsum + bb.x, 0.f);
    o.y = fmaxf(accy / dsum + bb.y, 0.f);
    *reinterpret_cast<float2*>(x2 + (size_t)node * K_DIM + lane * 2) = o;
}

// ---------------------------------------------------------------------------
// K6: layer-2 node projection, register-tiled like K4 (F=128). Outputs packed
//     asg[n] = {a_s2[4], g[4]} + adn2. h2p never materialized.
// ---------------------------------------------------------------------------
__global__ void __launch_bounds__(256)
k6_proj2(const float* __restrict__ x2, const float* __restrict__ W2,
         const float* __restrict__ asf, const float* __restrict__ adf,
         const float* __restrict__ linw,
         float* __restrict__ asg, float* __restrict__ adn) {
    __shared__ float sxT[K_DIM * 33]; // [f][i], i in [0,32), pad 1
    int t = threadIdx.x;
    int n0 = blockIdx.x * 32;
    {
        int f = t & 127, i0 = t >> 7;
#pragma unroll
        for (int s = 0; s < 16; ++s) {
            int i = i0 + s * 2;
            int n = n0 + i;
            sxT[f * 33 + i] = (n < N_NODES) ? x2[(size_t)n * K_DIM + f] : 0.f;
        }
    }
    __syncthreads();
    int kq = t & 31, nq = t >> 5;
    float acc[4][4] = {};
    for (int f = 0; f < K_DIM; ++f) {
        float a0 = sxT[f * 33 + nq * 4 + 0];
        float a1 = sxT[f * 33 + nq * 4 + 1];
        float a2 = sxT[f * 33 + nq * 4 + 2];
        float a3 = sxT[f * 33 + nq * 4 + 3];
        float4 w4 = *reinterpret_cast<const float4*>(W2 + (size_t)f * K_DIM + kq * 4);
        acc[0][0] += a0 * w4.x; acc[0][1] += a0 * w4.y; acc[0][2] += a0 * w4.z; acc[0][3] += a0 * w4.w;
        acc[1][0] += a1 * w4.x; acc[1][1] += a1 * w4.y; acc[1][2] += a1 * w4.z; acc[1][3] += a1 * w4.w;
        acc[2][0] += a2 * w4.x; acc[2][1] += a2 * w4.y; acc[2][2] += a2 * w4.z; acc[2][3] += a2 * w4.w;
        acc[3][0] += a3 * w4.x; acc[3][1] += a3 * w4.y; acc[3][2] += a3 * w4.z; acc[3][3] += a3 * w4.w;
    }
    int head = kq >> 3;
    float4 va = *reinterpret_cast<const float4*>(asf + kq * 4);
    float4 vd = *reinterpret_cast<const float4*>(adf + kq * 4);
    float4 vg = *reinterpret_cast<const float4*>(linw + kq * 4);
#pragma unroll
    for (int i = 0; i < 4; ++i) {
        int n = n0 + nq * 4 + i;
        float s = acc[i][0] * va.x + acc[i][1] * va.y + acc[i][2] * va.z + acc[i][3] * va.w;
        float d = acc[i][0] * vd.x + acc[i][1] * vd.y + acc[i][2] * vd.z + acc[i][3] * vd.w;
        float g = acc[i][0] * vg.x + acc[i][1] * vg.y + acc[i][2] * vg.z + acc[i][3] * vg.w;
#pragma unroll
        for (int m = 1; m < 8; m <<= 1) {
            s += __shfl_xor(s, m, 8);
            d += __shfl_xor(d, m, 8);
            g += __shfl_xor(g, m, 8);
        }
        if ((kq & 7) == 0 && n < N_NODES) {
            asg[(size_t)n * 8 + head] = s;
            asg[(size_t)n * 8 + 4 + head] = g;
            adn[(size_t)n * 4 + head] = d;
        }
    }
}

// ---------------------------------------------------------------------------
// K7: layer-2 gather: 16-lane group per node, lanes stride the edge list.
// ---------------------------------------------------------------------------
__global__ void __launch_bounds__(256)
k7_l2(const int* __restrict__ starts, const int* __restrict__ el_src,
      const float4* __restrict__ el_ae2, const float* __restrict__ asg,
      const float* __restrict__ adn, const float* __restrict__ cbias,
      float* __restrict__ out) {
    int t = threadIdx.x;
    int g16 = t & 15;
    int node = blockIdx.x * 16 + (t >> 4);
    if (node >= N_NODES) return;
    int s = starts[node], e = starts[node + 1];
    float4 ad4 = *reinterpret_cast<const float4*>(adn + (size_t)node * 4);
    float4 dsum = make_float4(0, 0, 0, 0);
    float4 gsum = make_float4(0, 0, 0, 0);
    float4 aesum = make_float4(0, 0, 0, 0);
    for (int j = s + g16; j < e; j += 16) {
        int src = el_src[j];
        float4 ae4 = el_ae2[j];
        const float* ap = asg + (size_t)src * 8;
        float4 as4 = *reinterpret_cast<const float4*>(ap);
        float4 g4  = *reinterpret_cast<const float4*>(ap + 4);
        float e0 = __expf(lrelu(as4.x + ad4.x + ae4.x));
        float e1 = __expf(lrelu(as4.y + ad4.y + ae4.y));
        float e2 = __expf(lrelu(as4.z + ad4.z + ae4.z));
        float e3 = __expf(lrelu(as4.w + ad4.w + ae4.w));
        dsum.x += e0; dsum.y += e1; dsum.z += e2; dsum.w += e3;
        gsum.x += e0 * g4.x; gsum.y += e1 * g4.y; gsum.z += e2 * g4.z; gsum.w += e3 * g4.w;
        aesum.x += ae4.x; aesum.y += ae4.y; aesum.z += ae4.z; aesum.w += ae4.w;
    }
#pragma unroll
    for (int m = 1; m < 16; m <<= 1) {
        dsum.x += __shfl_xor(dsum.x, m, 16);  dsum.y += __shfl_xor(dsum.y, m, 16);
        dsum.z += __shfl_xor(dsum.z, m, 16);  dsum.w += __shfl_xor(dsum.w, m, 16);
        gsum.x += __shfl_xor(gsum.x, m, 16);  gsum.y += __shfl_xor(gsum.y, m, 16);
        gsum.z += __shfl_xor(gsum.z, m, 16);  gsum.w += __shfl_xor(gsum.w, m, 16);
        aesum.x += __shfl_xor(aesum.x, m, 16); aesum.y += __shfl_xor(aesum.y, m, 16);
        aesum.z += __shfl_xor(aesum.z, m, 16); aesum.w += __shfl_xor(aesum.w, m, 16);
    }
    if (g16 == 0) {
        float deg = fmaxf((float)(e - s), 1.f);
        const float* ap = asg + (size_t)node * 8;
        float4 mas = *reinterpret_cast<const float4*>(ap);
        float4 mg  = *reinterpret_cast<const float4*>(ap + 4);
        float r = cbias[0];
        float e0;
        e0 = __expf(lrelu(mas.x + ad4.x + aesum.x / deg)); r += (gsum.x + e0 * mg.x) / (dsum.x + e0);
        e0 = __expf(lrelu(mas.y + ad4.y + aesum.y / deg)); r += (gsum.y + e0 * mg.y) / (dsum.y + e0);
        e0 = __expf(lrelu(mas.z + ad4.z + aesum.z / deg)); r += (gsum.z + e0 * mg.z) / (dsum.z + e0);
        e0 = __expf(lrelu(mas.w + ad4.w + aesum.w / deg)); r += (gsum.w + e0 * mg.w) / (dsum.w + e0);
        out[node] = r;
    }
}

// ---------------------------------------------------------------------------
extern "C" void kernel_launch(void* const* d_in, const int* in_sizes, int n_in,
                              void* d_out, int out_size, void* d_ws, size_t ws_size,
                              hipStream_t stream) {
    (void)in_sizes; (void)n_in; (void)out_size;
    const float* x    = (const float*)d_in[0];
    const float* ea   = (const float*)d_in[1];
    const float* W1   = (const float*)d_in[2];
    const float* as1  = (const float*)d_in[3];
    const float* ad1  = (const float*)d_in[4];
    const float* We1  = (const float*)d_in[5];
    const float* ae1  = (const float*)d_in[6];
    const float* b1   = (const float*)d_in[7];
    const float* W2   = (const float*)d_in[8];
    const float* as2  = (const float*)d_in[9];
    const float* ad2  = (const float*)d_in[10];
    const float* We2  = (const float*)d_in[11];
    const float* ae2  = (const float*)d_in[12];
    const float* b2   = (const float*)d_in[13];
    const float* linw = (const float*)d_in[14];
    const float* linb = (const float*)d_in[15];
    const int*   ei   = (const int*)d_in[16];
    float* out = (float*)d_out;
    float* ws  = (float*)d_ws;

    size_t off = 0;
    float* h1p   = ws + off; off += (size_t)N_NODES * K_DIM;
    float* x2    = ws + off; off += (size_t)N_NODES * K_DIM;
    float* asn1  = ws + off; off += (size_t)N_NODES * 4;
    float* adn1  = ws + off; off += (size_t)N_NODES * 4;
    float* asg2  = ws + off; off += (size_t)N_NODES * 8;
    float* adn2  = ws + off; off += (size_t)N_NODES * 4;
    float* vbuf  = ws + off; off += 512;
    float* cbias = ws + off; off += 64;
    int* starts  = (int*)(ws + off); off += (size_t)N_NODES + 8;
    int* cursor  = (int*)(ws + off); off += (size_t)N_NODES;
    int* el_src  = (int*)(ws + off); off += (size_t)N_EDGES;
    float* aer1  = ws + off; off += (size_t)N_EDGES * 4;
    float* aer2  = ws + off; off += (size_t)N_EDGES * 4;
    float* elae1 = ws + off; off += (size_t)N_EDGES * 4;
    float* elae2 = ws + off; off += (size_t)N_EDGES * 4;
    int* cnt     = (int*)(ws + off); off += (size_t)N_NODES;

    if (ws_size < off * sizeof(float)) return; // workspace too small: fail visibly

    hipMemsetAsync(cnt, 0, N_NODES * sizeof(int), stream);

    k0_fold<<<1, 256, 0, stream>>>(We1, ae1, We2, ae2, b2, linw, linb, vbuf, cbias);
    kc_count<<<(N_EDGES + 255) / 256, 256, 0, stream>>>(ei, cnt);
    k2_scan<<<1, 1024, 0, stream>>>(cnt, starts, cursor);
    k1_edge<<<N_EDGES / 256, 256, 0, stream>>>(ea, vbuf, aer1, aer2);
    k3_scatter<<<N_EDGES / 256, 256, 0, stream>>>(ei, (const float4*)aer1, (const float4*)aer2,
                                                  cursor, el_src, (float4*)elae1, (float4*)elae2);
    k4_proj1<<<(N_NODES + 31) / 32, 256, 0, stream>>>(x, W1, as1, ad1, h1p, asn1, adn1);
    k5_agg1<<<(N_NODES + 3) / 4, 256, 0, stream>>>(starts, el_src, elae1,
                                                   asn1, adn1, h1p, b1, x2);
    k6_proj2<<<(N_NODES + 31) / 32, 256, 0, stream>>>(x2, W2, as2, ad2, linw, asg2, adn2);
    k7_l2<<<(N_NODES + 15) / 16, 256, 0, stream>>>(starts, el_src, (const float4*)elae2,
                                                   asg2, adn2, cbias, out);
}

// Round 9
// 321.526 us; speedup vs baseline: 1.2108x; 1.2108x over previous
//
#include <hip/hip_runtime.h>

#define N_NODES 50000
#define N_EDGES 800000
#define F_IN    64
#define HEADS   4
#define CH      32
#define K_DIM   128
#define NEG     0.2f

__device__ __forceinline__ float lrelu(float x) { return x > 0.f ? x : NEG * x; }

// ---------------------------------------------------------------------------
// K0: fold We*ae -> v[o][f] (o=0..3 layer1 heads, 4..7 layer2 heads), and
//     cbias = dot(b2, lin_w) + lin_b
// ---------------------------------------------------------------------------
__global__ void k0_fold(const float* __restrict__ We1, const float* __restrict__ ae1,
                        const float* __restrict__ We2, const float* __restrict__ ae2,
                        const float* __restrict__ b2,  const float* __restrict__ linw,
                        const float* __restrict__ linb,
                        float* __restrict__ v, float* __restrict__ cbias) {
    int t = threadIdx.x; // 256 threads
    for (int idx = t; idx < 512; idx += 256) {
        int o = idx >> 6, f = idx & 63;
        const float* We = (o < 4) ? We1 : We2;
        const float* ae = (o < 4) ? ae1 : ae2;
        int h = o & 3;
        float s = 0.f;
        for (int c = 0; c < CH; ++c)
            s += We[f * K_DIM + h * CH + c] * ae[h * CH + c];
        v[o * 64 + f] = s;
    }
    if (t == 0) {
        float s = 0.f;
        for (int k = 0; k < K_DIM; ++k) s += b2[k] * linw[k];
        *cbias = s + linb[0];
    }
}

// ---------------------------------------------------------------------------
// Kc: degree count from ei only.
// ---------------------------------------------------------------------------
__global__ void __launch_bounds__(256)
kc_count(const int* __restrict__ ei, int* __restrict__ cnt) {
    int e = blockIdx.x * 256 + threadIdx.x;
    if (e >= N_EDGES) return;
    atomicAdd(cnt + ei[N_EDGES + e], 1);
}

// ---------------------------------------------------------------------------
// K2a/K2b: hierarchical exclusive scan (R8 lesson: single-block scan = one CU
//     doing 49 serial chunks while 255 idle). k2a: per-block sums. k2b: each
//     block adds prefix of block sums (49-iter scalar loop) + local scan.
// ---------------------------------------------------------------------------
__global__ void __launch_bounds__(1024)
k2a_bsum(const int* __restrict__ cnt, int* __restrict__ bsum) {
    __shared__ int ws[16];
    int t = threadIdx.x, lane = t & 63, wid = t >> 6;
    int i = blockIdx.x * 1024 + t;
    int v = (i < N_NODES) ? cnt[i] : 0;
#pragma unroll
    for (int m = 1; m < 64; m <<= 1) v += __shfl_xor(v, m, 64);
    if (lane == 0) ws[wid] = v;
    __syncthreads();
    if (t == 0) {
        int s = 0;
#pragma unroll
        for (int k = 0; k < 16; ++k) s += ws[k];
        bsum[blockIdx.x] = s;
    }
}

__global__ void __launch_bounds__(1024)
k2b_scan(const int* __restrict__ cnt, const int* __restrict__ bsum,
         int* __restrict__ starts, int* __restrict__ cursor, int nblk) {
    __shared__ int wsum[16];
    __shared__ int s_off;
    int t = threadIdx.x, lane = t & 63, wid = t >> 6;
    int bid = blockIdx.x;
    if (t == 0) {
        int o = 0;
        for (int b = 0; b < bid; ++b) o += bsum[b];
        s_off = o;
    }
    int i = bid * 1024 + t;
    int v = (i < N_NODES) ? cnt[i] : 0;
    int sc = v; // inclusive wave scan
#pragma unroll
    for (int s = 1; s < 64; s <<= 1) {
        int u = __shfl_up(sc, s, 64);
        if (lane >= s) sc += u;
    }
    if (lane == 63) wsum[wid] = sc;
    __syncthreads();
    if (wid == 0 && lane < 16) {
        int ws = wsum[lane];
#pragma unroll
        for (int s = 1; s < 16; s <<= 1) {
            int u = __shfl_up(ws, s, 64);
            if (lane >= s) ws += u;
        }
        wsum[lane] = ws;
    }
    __syncthreads();
    int off = s_off + ((wid == 0) ? 0 : wsum[wid - 1]);
    int excl = off + sc - v;
    if (i < N_NODES) { starts[i] = excl; cursor[i] = excl; }
    if (bid == nblk - 1 && t == 1023) starts[N_NODES] = s_off + wsum[15];
}

// ---------------------------------------------------------------------------
// K1: per-edge a_e, PURE STREAM. Coalesced LDS-tile staging, v-row in 16
//     float4 regs, writes aer1/aer2 in EDGE ORDER. No atomics, no scatter.
// ---------------------------------------------------------------------------
__global__ void __launch_bounds__(256)
k1_edge(const float* __restrict__ ea, const float* __restrict__ v,
        float* __restrict__ aer1, float* __restrict__ aer2) {
    __shared__ float sx[2][32 * 68];
    int t = threadIdx.x;
    int o  = t & 7;   // output index (0..3: layer1 heads, 4..7: layer2 heads)
    int le = t >> 3;  // local edge within tile (0..31)
    float4 vr[16];
    {
        const float4* vrow = reinterpret_cast<const float4*>(v + o * 64);
#pragma unroll
        for (int c = 0; c < 16; ++c) vr[c] = vrow[c];
    }
    const float4* ea4 = reinterpret_cast<const float4*>(ea);
    int base = blockIdx.x * 256; // 8 tiles * 32 edges
    {
        size_t gb = (size_t)base * 16;
        float4 a = ea4[gb + t];
        float4 b = ea4[gb + t + 256];
        int g0 = t, g1 = t + 256;
        *reinterpret_cast<float4*>(&sx[0][(g0 >> 4) * 68 + (g0 & 15) * 4]) = a;
        *reinterpret_cast<float4*>(&sx[0][(g1 >> 4) * 68 + (g1 & 15) * 4]) = b;
    }
    __syncthreads();
    for (int tile = 0; tile < 8; ++tile) {
        float4 a, b;
        if (tile < 7) { // prefetch next tile (coalesced)
            size_t gb = (size_t)(base + (tile + 1) * 32) * 16;
            a = ea4[gb + t];
            b = ea4[gb + t + 256];
        }
        const float* row = &sx[tile & 1][le * 68];
        float4 ac = make_float4(0.f, 0.f, 0.f, 0.f);
#pragma unroll
        for (int c = 0; c < 16; ++c) {
            float4 x4 = *reinterpret_cast<const float4*>(row + c * 4);
            ac.x = fmaf(x4.x, vr[c].x, ac.x);
            ac.y = fmaf(x4.y, vr[c].y, ac.y);
            ac.z = fmaf(x4.z, vr[c].z, ac.z);
            ac.w = fmaf(x4.w, vr[c].w, ac.w);
        }
        float acc = (ac.x + ac.y) + (ac.z + ac.w);
        int eid = base + tile * 32 + le;
        float* ob = (o < 4) ? aer1 : aer2;
        ob[(size_t)eid * 4 + (o & 3)] = acc;   // edge-order: coalesced
        if (tile < 7) { // write next tile into other buffer
            int g0 = t, g1 = t + 256;
            int nb = (tile + 1) & 1;
            *reinterpret_cast<float4*>(&sx[nb][(g0 >> 4) * 68 + (g0 & 15) * 4]) = a;
            *reinterpret_cast<float4*>(&sx[nb][(g1 >> 4) * 68 + (g1 & 15) * 4]) = b;
        }
        __syncthreads();
    }
}

// ---------------------------------------------------------------------------
// K3: scatter into dst-sorted lists. Thread-per-edge, no LDS, max occupancy.
// ---------------------------------------------------------------------------
__global__ void __launch_bounds__(256)
k3_scatter(const int* __restrict__ ei, const float4* __restrict__ aer1,
           const float4* __restrict__ aer2, int* __restrict__ cursor,
           int* __restrict__ el_src, float4* __restrict__ el_ae1,
           float4* __restrict__ el_ae2) {
    int e = blockIdx.x * 256 + threadIdx.x;
    if (e >= N_EDGES) return;
    int dst = ei[N_EDGES + e];
    int pos = atomicAdd(cursor + dst, 1);   // issue atomic first (longest latency)
    int src = ei[e];
    float4 a1 = aer1[e];
    float4 a2 = aer2[e];
    el_src[pos] = src;
    el_ae1[pos] = a1;
    el_ae2[pos] = a2;
}

// ---------------------------------------------------------------------------
// K4: layer-1 node projection, register-tiled 4 nodes x 4 cols per thread.
// ---------------------------------------------------------------------------
__global__ void __launch_bounds__(256)
k4_proj1(const float* __restrict__ x, const float* __restrict__ W,
         const float* __restrict__ asf, const float* __restrict__ adf,
         float* __restrict__ hp, float* __restrict__ asn, float* __restrict__ adn) {
    __shared__ float sxT[F_IN * 33]; // [f][i], i in [0,32), pad 1
    int t = threadIdx.x;
    int n0 = blockIdx.x * 32;
    {
        int f = t & 63, i0 = t >> 6;
#pragma unroll
        for (int s = 0; s < 8; ++s) {
            int i = i0 + s * 4;
            int n = n0 + i;
            sxT[f * 33 + i] = (n < N_NODES) ? x[(size_t)n * F_IN + f] : 0.f;
        }
    }
    __syncthreads();
    int kq = t & 31, nq = t >> 5;
    float acc[4][4] = {};
    for (int f = 0; f < F_IN; ++f) {
        float a0 = sxT[f * 33 + nq * 4 + 0];
        float a1 = sxT[f * 33 + nq * 4 + 1];
        float a2 = sxT[f * 33 + nq * 4 + 2];
        float a3 = sxT[f * 33 + nq * 4 + 3];
        float4 w4 = *reinterpret_cast<const float4*>(W + (size_t)f * K_DIM + kq * 4);
        acc[0][0] += a0 * w4.x; acc[0][1] += a0 * w4.y; acc[0][2] += a0 * w4.z; acc[0][3] += a0 * w4.w;
        acc[1][0] += a1 * w4.x; acc[1][1] += a1 * w4.y; acc[1][2] += a1 * w4.z; acc[1][3] += a1 * w4.w;
        acc[2][0] += a2 * w4.x; acc[2][1] += a2 * w4.y; acc[2][2] += a2 * w4.z; acc[2][3] += a2 * w4.w;
        acc[3][0] += a3 * w4.x; acc[3][1] += a3 * w4.y; acc[3][2] += a3 * w4.z; acc[3][3] += a3 * w4.w;
    }
    int head = kq >> 3;
    float4 va = *reinterpret_cast<const float4*>(asf + kq * 4);
    float4 vd = *reinterpret_cast<const float4*>(adf + kq * 4);
#pragma unroll
    for (int i = 0; i < 4; ++i) {
        int n = n0 + nq * 4 + i;
        if (n < N_NODES)
            *reinterpret_cast<float4*>(hp + (size_t)n * K_DIM + kq * 4) =
                make_float4(acc[i][0], acc[i][1], acc[i][2], acc[i][3]);
        float s = acc[i][0] * va.x + acc[i][1] * va.y + acc[i][2] * va.z + acc[i][3] * va.w;
        float d = acc[i][0] * vd.x + acc[i][1] * vd.y + acc[i][2] * vd.z + acc[i][3] * vd.w;
#pragma unroll
        for (int m = 1; m < 8; m <<= 1) {
            s += __shfl_xor(s, m, 8);
            d += __shfl_xor(d, m, 8);
        }
        if ((kq & 7) == 0 && n < N_NODES) {
            asn[(size_t)n * 4 + head] = s;
            adn[(size_t)n * 4 + head] = d;
        }
    }
}

// ---------------------------------------------------------------------------
// K5: layer-1 gather aggregation. One 64-lane wave per node; lane owns 2
//     output columns. 2-way unrolled prefetch: both edges' index loads issue
//     before either's dependent gathers (halves the serial chain).
// ---------------------------------------------------------------------------
__global__ void __launch_bounds__(256)
k5_agg1(const int* __restrict__ starts, const int* __restrict__ el_src,
        const float* __restrict__ el_ae1,
        const float* __restrict__ asn, const float* __restrict__ adn,
        const float* __restrict__ hp, const float* __restrict__ b1,
        float* __restrict__ x2) {
    int t = threadIdx.x;
    int lane = t & 63;
    int node = blockIdx.x * 4 + (t >> 6);
    if (node >= N_NODES) return;
    int s = starts[node], e = starts[node + 1];
    int head = lane >> 4; // col pair = lane*2; head = (lane*2)>>5
    float adv = adn[(size_t)node * 4 + head];
    float accx = 0.f, accy = 0.f, dsum = 0.f, aesum = 0.f;
    int j = s;
    for (; j + 2 <= e; j += 2) {
        int src0 = el_src[j];
        int src1 = el_src[j + 1];
        float ae0 = el_ae1[(size_t)j * 4 + head];
        float ae1 = el_ae1[(size_t)(j + 1) * 4 + head];
        float av0 = asn[(size_t)src0 * 4 + head];
        float av1 = asn[(size_t)src1 * 4 + head];
        float2 h0 = *reinterpret_cast<const float2*>(hp + (size_t)src0 * K_DIM + lane * 2);
        float2 h1 = *reinterpret_cast<const float2*>(hp + (size_t)src1 * K_DIM + lane * 2);
        float ex0 = __expf(lrelu(av0 + adv + ae0));
        float ex1 = __expf(lrelu(av1 + adv + ae1));
        accx = fmaf(ex0, h0.x, fmaf(ex1, h1.x, accx));
        accy = fmaf(ex0, h0.y, fmaf(ex1, h1.y, accy));
        dsum += ex0 + ex1;
        aesum += ae0 + ae1;
    }
    if (j < e) {
        int src = el_src[j];
        float ae = el_ae1[(size_t)j * 4 + head];
        float av = asn[(size_t)src * 4 + head];
        float ex = __expf(lrelu(av + adv + ae));
        float2 hv = *reinterpret_cast<const float2*>(hp + (size_t)src * K_DIM + lane * 2);
        accx = fmaf(ex, hv.x, accx);
        accy = fmaf(ex, hv.y, accy);
        dsum += ex;
        aesum += ae;
    }
    float deg = (float)(e - s);
    float al = aesum / fmaxf(deg, 1.f); // self-loop a_e = mean of incoming
    float exl = __expf(lrelu(asn[(size_t)node * 4 + head] + adv + al));
    float2 hv = *reinterpret_cast<const float2*>(hp + (size_t)node * K_DIM + lane * 2);
    accx += exl * hv.x;
    accy += exl * hv.y;
    dsum += exl;
    float2 bb = *reinterpret_cast<const float2*>(b1 + lane * 2);
    float2 o;
    o.x = fmaxf(accx / dsum + bb.x, 0.f);
    o.y = fmaxf(accy / dsum + bb.y, 0.f);
    *reinterpret_cast<float2*>(x2 + (size_t)node * K_DIM + lane * 2) = o;
}

// ---------------------------------------------------------------------------
// K6: layer-2 node projection, register-tiled like K4 (F=128). Outputs packed
//     asg[n] = {a_s2[4], g[4]} + adn2. h2p never materialized.
// ---------------------------------------------------------------------------
__global__ void __launch_bounds__(256)
k6_proj2(const float* __restrict__ x2, const float* __restrict__ W2,
         const float* __restrict__ asf, const float* __restrict__ adf,
         const float* __restrict__ linw,
         float* __restrict__ asg, float* __restrict__ adn) {
    __shared__ float sxT[K_DIM * 33]; // [f][i], i in [0,32), pad 1
    int t = threadIdx.x;
    int n0 = blockIdx.x * 32;
    {
        int f = t & 127, i0 = t >> 7;
#pragma unroll
        for (int s = 0; s < 16; ++s) {
            int i = i0 + s * 2;
            int n = n0 + i;
            sxT[f * 33 + i] = (n < N_NODES) ? x2[(size_t)n * K_DIM + f] : 0.f;
        }
    }
    __syncthreads();
    int kq = t & 31, nq = t >> 5;
    float acc[4][4] = {};
    for (int f = 0; f < K_DIM; ++f) {
        float a0 = sxT[f * 33 + nq * 4 + 0];
        float a1 = sxT[f * 33 + nq * 4 + 1];
        float a2 = sxT[f * 33 + nq * 4 + 2];
        float a3 = sxT[f * 33 + nq * 4 + 3];
        float4 w4 = *reinterpret_cast<const float4*>(W2 + (size_t)f * K_DIM + kq * 4);
        acc[0][0] += a0 * w4.x; acc[0][1] += a0 * w4.y; acc[0][2] += a0 * w4.z; acc[0][3] += a0 * w4.w;
        acc[1][0] += a1 * w4.x; acc[1][1] += a1 * w4.y; acc[1][2] += a1 * w4.z; acc[1][3] += a1 * w4.w;
        acc[2][0] += a2 * w4.x; acc[2][1] += a2 * w4.y; acc[2][2] += a2 * w4.z; acc[2][3] += a2 * w4.w;
        acc[3][0] += a3 * w4.x; acc[3][1] += a3 * w4.y; acc[3][2] += a3 * w4.z; acc[3][3] += a3 * w4.w;
    }
    int head = kq >> 3;
    float4 va = *reinterpret_cast<const float4*>(asf + kq * 4);
    float4 vd = *reinterpret_cast<const float4*>(adf + kq * 4);
    float4 vg = *reinterpret_cast<const float4*>(linw + kq * 4);
#pragma unroll
    for (int i = 0; i < 4; ++i) {
        int n = n0 + nq * 4 + i;
        float s = acc[i][0] * va.x + acc[i][1] * va.y + acc[i][2] * va.z + acc[i][3] * va.w;
        float d = acc[i][0] * vd.x + acc[i][1] * vd.y + acc[i][2] * vd.z + acc[i][3] * vd.w;
        float g = acc[i][0] * vg.x + acc[i][1] * vg.y + acc[i][2] * vg.z + acc[i][3] * vg.w;
#pragma unroll
        for (int m = 1; m < 8; m <<= 1) {
            s += __shfl_xor(s, m, 8);
            d += __shfl_xor(d, m, 8);
            g += __shfl_xor(g, m, 8);
        }
        if ((kq & 7) == 0 && n < N_NODES) {
            asg[(size_t)n * 8 + head] = s;
            asg[(size_t)n * 8 + 4 + head] = g;
            adn[(size_t)n * 4 + head] = d;
        }
    }
}

// ---------------------------------------------------------------------------
// K7: layer-2 gather: 16-lane group per node, lanes stride the edge list.
// ---------------------------------------------------------------------------
__global__ void __launch_bounds__(256)
k7_l2(const int* __restrict__ starts, const int* __restrict__ el_src,
      const float4* __restrict__ el_ae2, const float* __restrict__ asg,
      const float* __restrict__ adn, const float* __restrict__ cbias,
      float* __restrict__ out) {
    int t = threadIdx.x;
    int g16 = t & 15;
    int node = blockIdx.x * 16 + (t >> 4);
    if (node >= N_NODES) return;
    int s = starts[node], e = starts[node + 1];
    float4 ad4 = *reinterpret_cast<const float4*>(adn + (size_t)node * 4);
    float4 dsum = make_float4(0, 0, 0, 0);
    float4 gsum = make_float4(0, 0, 0, 0);
    float4 aesum = make_float4(0, 0, 0, 0);
    for (int j = s + g16; j < e; j += 16) {
        int src = el_src[j];
        float4 ae4 = el_ae2[j];
        const float* ap = asg + (size_t)src * 8;
        float4 as4 = *reinterpret_cast<const float4*>(ap);
        float4 g4  = *reinterpret_cast<const float4*>(ap + 4);
        float e0 = __expf(lrelu(as4.x + ad4.x + ae4.x));
        float e1 = __expf(lrelu(as4.y + ad4.y + ae4.y));
        float e2 = __expf(lrelu(as4.z + ad4.z + ae4.z));
        float e3 = __expf(lrelu(as4.w + ad4.w + ae4.w));
        dsum.x += e0; dsum.y += e1; dsum.z += e2; dsum.w += e3;
        gsum.x += e0 * g4.x; gsum.y += e1 * g4.y; gsum.z += e2 * g4.z; gsum.w += e3 * g4.w;
        aesum.x += ae4.x; aesum.y += ae4.y; aesum.z += ae4.z; aesum.w += ae4.w;
    }
#pragma unroll
    for (int m = 1; m < 16; m <<= 1) {
        dsum.x += __shfl_xor(dsum.x, m, 16);  dsum.y += __shfl_xor(dsum.y, m, 16);
        dsum.z += __shfl_xor(dsum.z, m, 16);  dsum.w += __shfl_xor(dsum.w, m, 16);
        gsum.x += __shfl_xor(gsum.x, m, 16);  gsum.y += __shfl_xor(gsum.y, m, 16);
        gsum.z += __shfl_xor(gsum.z, m, 16);  gsum.w += __shfl_xor(gsum.w, m, 16);
        aesum.x += __shfl_xor(aesum.x, m, 16); aesum.y += __shfl_xor(aesum.y, m, 16);
        aesum.z += __shfl_xor(aesum.z, m, 16); aesum.w += __shfl_xor(aesum.w, m, 16);
    }
    if (g16 == 0) {
        float deg = fmaxf((float)(e - s), 1.f);
        const float* ap = asg + (size_t)node * 8;
        float4 mas = *reinterpret_cast<const float4*>(ap);
        float4 mg  = *reinterpret_cast<const float4*>(ap + 4);
        float r = cbias[0];
        float e0;
        e0 = __expf(lrelu(mas.x + ad4.x + aesum.x / deg)); r += (gsum.x + e0 * mg.x) / (dsum.x + e0);
        e0 = __expf(lrelu(mas.y + ad4.y + aesum.y / deg)); r += (gsum.y + e0 * mg.y) / (dsum.y + e0);
        e0 = __expf(lrelu(mas.z + ad4.z + aesum.z / deg)); r += (gsum.z + e0 * mg.z) / (dsum.z + e0);
        e0 = __expf(lrelu(mas.w + ad4.w + aesum.w / deg)); r += (gsum.w + e0 * mg.w) / (dsum.w + e0);
        out[node] = r;
    }
}

// ---------------------------------------------------------------------------
extern "C" void kernel_launch(void* const* d_in, const int* in_sizes, int n_in,
                              void* d_out, int out_size, void* d_ws, size_t ws_size,
                              hipStream_t stream) {
    (void)in_sizes; (void)n_in; (void)out_size;
    const float* x    = (const float*)d_in[0];
    const float* ea   = (const float*)d_in[1];
    const float* W1   = (const float*)d_in[2];
    const float* as1  = (const float*)d_in[3];
    const float* ad1  = (const float*)d_in[4];
    const float* We1  = (const float*)d_in[5];
    const float* ae1  = (const float*)d_in[6];
    const float* b1   = (const float*)d_in[7];
    const float* W2   = (const float*)d_in[8];
    const float* as2  = (const float*)d_in[9];
    const float* ad2  = (const float*)d_in[10];
    const float* We2  = (const float*)d_in[11];
    const float* ae2  = (const float*)d_in[12];
    const float* b2   = (const float*)d_in[13];
    const float* linw = (const float*)d_in[14];
    const float* linb = (const float*)d_in[15];
    const int*   ei   = (const int*)d_in[16];
    float* out = (float*)d_out;
    float* ws  = (float*)d_ws;

    const int SCAN_BLK = (N_NODES + 1023) / 1024; // 49

    size_t off = 0;
    float* h1p   = ws + off; off += (size_t)N_NODES * K_DIM;
    float* x2    = ws + off; off += (size_t)N_NODES * K_DIM;
    float* asn1  = ws + off; off += (size_t)N_NODES * 4;
    float* adn1  = ws + off; off += (size_t)N_NODES * 4;
    float* asg2  = ws + off; off += (size_t)N_NODES * 8;
    float* adn2  = ws + off; off += (size_t)N_NODES * 4;
    float* vbuf  = ws + off; off += 512;
    float* cbias = ws + off; off += 64;
    int* starts  = (int*)(ws + off); off += (size_t)N_NODES + 8;
    int* cursor  = (int*)(ws + off); off += (size_t)N_NODES;
    int* bsum    = (int*)(ws + off); off += 64;
    int* el_src  = (int*)(ws + off); off += (size_t)N_EDGES;
    float* aer1  = ws + off; off += (size_t)N_EDGES * 4;
    float* aer2  = ws + off; off += (size_t)N_EDGES * 4;
    float* elae1 = ws + off; off += (size_t)N_EDGES * 4;
    float* elae2 = ws + off; off += (size_t)N_EDGES * 4;
    int* cnt     = (int*)(ws + off); off += (size_t)N_NODES;

    if (ws_size < off * sizeof(float)) return; // workspace too small: fail visibly

    hipMemsetAsync(cnt, 0, N_NODES * sizeof(int), stream);

    k0_fold<<<1, 256, 0, stream>>>(We1, ae1, We2, ae2, b2, linw, linb, vbuf, cbias);
    kc_count<<<(N_EDGES + 255) / 256, 256, 0, stream>>>(ei, cnt);
    k2a_bsum<<<SCAN_BLK, 1024, 0, stream>>>(cnt, bsum);
    k2b_scan<<<SCAN_BLK, 1024, 0, stream>>>(cnt, bsum, starts, cursor, SCAN_BLK);
    k1_edge<<<N_EDGES / 256, 256, 0, stream>>>(ea, vbuf, aer1, aer2);
    k3_scatter<<<N_EDGES / 256, 256, 0, stream>>>(ei, (const float4*)aer1, (const float4*)aer2,
                                                  cursor, el_src, (float4*)elae1, (float4*)elae2);
    k4_proj1<<<(N_NODES + 31) / 32, 256, 0, stream>>>(x, W1, as1, ad1, h1p, asn1, adn1);
    k5_agg1<<<(N_NODES + 3) / 4, 256, 0, stream>>>(starts, el_src, elae1,
                                                   asn1, adn1, h1p, b1, x2);
    k6_proj2<<<(N_NODES + 31) / 32, 256, 0, stream>>>(x2, W2, as2, ad2, linw, asg2, adn2);
    k7_l2<<<(N_NODES + 15) / 16, 256, 0, stream>>>(starts, el_src, (const float4*)elae2,
                                                   asg2, adn2, cbias, out);
}

// Round 10
// 310.100 us; speedup vs baseline: 1.2554x; 1.0368x over previous
//
#include <hip/hip_runtime.h>

#define N_NODES 50000
#define N_EDGES 800000
#define F_IN    64
#define HEADS   4
#define CH      32
#define K_DIM   128
#define NEG     0.2f

__device__ __forceinline__ float lrelu(float x) { return x > 0.f ? x : NEG * x; }

// ---------------------------------------------------------------------------
// K0: fold We*ae -> v[o][f] (o=0..3 layer1 heads, 4..7 layer2 heads), and
//     cbias = dot(b2, lin_w) + lin_b
// ---------------------------------------------------------------------------
__global__ void k0_fold(const float* __restrict__ We1, const float* __restrict__ ae1,
                        const float* __restrict__ We2, const float* __restrict__ ae2,
                        const float* __restrict__ b2,  const float* __restrict__ linw,
                        const float* __restrict__ linb,
                        float* __restrict__ v, float* __restrict__ cbias) {
    int t = threadIdx.x; // 256 threads
    for (int idx = t; idx < 512; idx += 256) {
        int o = idx >> 6, f = idx & 63;
        const float* We = (o < 4) ? We1 : We2;
        const float* ae = (o < 4) ? ae1 : ae2;
        int h = o & 3;
        float s = 0.f;
        for (int c = 0; c < CH; ++c)
            s += We[f * K_DIM + h * CH + c] * ae[h * CH + c];
        v[o * 64 + f] = s;
    }
    if (t == 0) {
        float s = 0.f;
        for (int k = 0; k < K_DIM; ++k) s += b2[k] * linw[k];
        *cbias = s + linb[0];
    }
}

// ---------------------------------------------------------------------------
// Kc: degree count from ei only.
// ---------------------------------------------------------------------------
__global__ void __launch_bounds__(256)
kc_count(const int* __restrict__ ei, int* __restrict__ cnt) {
    int e = blockIdx.x * 256 + threadIdx.x;
    if (e >= N_EDGES) return;
    atomicAdd(cnt + ei[N_EDGES + e], 1);
}

// ---------------------------------------------------------------------------
// K2a/K2b: hierarchical exclusive scan.
// ---------------------------------------------------------------------------
__global__ void __launch_bounds__(1024)
k2a_bsum(const int* __restrict__ cnt, int* __restrict__ bsum) {
    __shared__ int ws[16];
    int t = threadIdx.x, lane = t & 63, wid = t >> 6;
    int i = blockIdx.x * 1024 + t;
    int v = (i < N_NODES) ? cnt[i] : 0;
#pragma unroll
    for (int m = 1; m < 64; m <<= 1) v += __shfl_xor(v, m, 64);
    if (lane == 0) ws[wid] = v;
    __syncthreads();
    if (t == 0) {
        int s = 0;
#pragma unroll
        for (int k = 0; k < 16; ++k) s += ws[k];
        bsum[blockIdx.x] = s;
    }
}

__global__ void __launch_bounds__(1024)
k2b_scan(const int* __restrict__ cnt, const int* __restrict__ bsum,
         int* __restrict__ starts, int* __restrict__ cursor, int nblk) {
    __shared__ int wsum[16];
    __shared__ int s_off;
    int t = threadIdx.x, lane = t & 63, wid = t >> 6;
    int bid = blockIdx.x;
    if (t == 0) {
        int o = 0;
        for (int b = 0; b < bid; ++b) o += bsum[b];
        s_off = o;
    }
    int i = bid * 1024 + t;
    int v = (i < N_NODES) ? cnt[i] : 0;
    int sc = v; // inclusive wave scan
#pragma unroll
    for (int s = 1; s < 64; s <<= 1) {
        int u = __shfl_up(sc, s, 64);
        if (lane >= s) sc += u;
    }
    if (lane == 63) wsum[wid] = sc;
    __syncthreads();
    if (wid == 0 && lane < 16) {
        int ws = wsum[lane];
#pragma unroll
        for (int s = 1; s < 16; s <<= 1) {
            int u = __shfl_up(ws, s, 64);
            if (lane >= s) ws += u;
        }
        wsum[lane] = ws;
    }
    __syncthreads();
    int off = s_off + ((wid == 0) ? 0 : wsum[wid - 1]);
    int excl = off + sc - v;
    if (i < N_NODES) { starts[i] = excl; cursor[i] = excl; }
    if (bid == nblk - 1 && t == 1023) starts[N_NODES] = s_off + wsum[15];
}

// ---------------------------------------------------------------------------
// K1: per-edge a_e, PURE STREAM. Coalesced LDS-tile staging, v-row in 16
//     float4 regs, writes aer1/aer2 in EDGE ORDER. No atomics, no scatter.
// ---------------------------------------------------------------------------
__global__ void __launch_bounds__(256)
k1_edge(const float* __restrict__ ea, const float* __restrict__ v,
        float* __restrict__ aer1, float* __restrict__ aer2) {
    __shared__ float sx[2][32 * 68];
    int t = threadIdx.x;
    int o  = t & 7;   // output index (0..3: layer1 heads, 4..7: layer2 heads)
    int le = t >> 3;  // local edge within tile (0..31)
    float4 vr[16];
    {
        const float4* vrow = reinterpret_cast<const float4*>(v + o * 64);
#pragma unroll
        for (int c = 0; c < 16; ++c) vr[c] = vrow[c];
    }
    const float4* ea4 = reinterpret_cast<const float4*>(ea);
    int base = blockIdx.x * 256; // 8 tiles * 32 edges
    {
        size_t gb = (size_t)base * 16;
        float4 a = ea4[gb + t];
        float4 b = ea4[gb + t + 256];
        int g0 = t, g1 = t + 256;
        *reinterpret_cast<float4*>(&sx[0][(g0 >> 4) * 68 + (g0 & 15) * 4]) = a;
        *reinterpret_cast<float4*>(&sx[0][(g1 >> 4) * 68 + (g1 & 15) * 4]) = b;
    }
    __syncthreads();
    for (int tile = 0; tile < 8; ++tile) {
        float4 a, b;
        if (tile < 7) { // prefetch next tile (coalesced)
            size_t gb = (size_t)(base + (tile + 1) * 32) * 16;
            a = ea4[gb + t];
            b = ea4[gb + t + 256];
        }
        const float* row = &sx[tile & 1][le * 68];
        float4 ac = make_float4(0.f, 0.f, 0.f, 0.f);
#pragma unroll
        for (int c = 0; c < 16; ++c) {
            float4 x4 = *reinterpret_cast<const float4*>(row + c * 4);
            ac.x = fmaf(x4.x, vr[c].x, ac.x);
            ac.y = fmaf(x4.y, vr[c].y, ac.y);
            ac.z = fmaf(x4.z, vr[c].z, ac.z);
            ac.w = fmaf(x4.w, vr[c].w, ac.w);
        }
        float acc = (ac.x + ac.y) + (ac.z + ac.w);
        int eid = base + tile * 32 + le;
        float* ob = (o < 4) ? aer1 : aer2;
        ob[(size_t)eid * 4 + (o & 3)] = acc;   // edge-order: coalesced
        if (tile < 7) { // write next tile into other buffer
            int g0 = t, g1 = t + 256;
            int nb = (tile + 1) & 1;
            *reinterpret_cast<float4*>(&sx[nb][(g0 >> 4) * 68 + (g0 & 15) * 4]) = a;
            *reinterpret_cast<float4*>(&sx[nb][(g1 >> 4) * 68 + (g1 & 15) * 4]) = b;
        }
        __syncthreads();
    }
}

// ---------------------------------------------------------------------------
// K3: scatter into dst-sorted 64 B edge records (R9 lesson: 36 B records
//     straddling lines -> WRITE_SIZE 100 MB vs 28.8 MB payload, partial-line
//     RMW). Record = [src pad pad pad | ae1 x4 | ae2 x4 | pad x4]; four
//     back-to-back float4 stores write the FULL line -> no fetch-before-write,
//     each line written exactly once. ~51 MB clean writes.
// ---------------------------------------------------------------------------
__global__ void __launch_bounds__(256)
k3_scatter(const int* __restrict__ ei, const float4* __restrict__ aer1,
           const float4* __restrict__ aer2, int* __restrict__ cursor,
           float4* __restrict__ el) {
    int e = blockIdx.x * 256 + threadIdx.x;
    if (e >= N_EDGES) return;
    int dst = ei[N_EDGES + e];
    int pos = atomicAdd(cursor + dst, 1);   // issue atomic first (longest latency)
    int src = ei[e];
    float4 a1 = aer1[e];
    float4 a2 = aer2[e];
    float4* r = el + (size_t)pos * 4;
    r[0] = make_float4(__int_as_float(src), 0.f, 0.f, 0.f);
    r[1] = a1;
    r[2] = a2;
    r[3] = make_float4(0.f, 0.f, 0.f, 0.f);
}

// ---------------------------------------------------------------------------
// K4: layer-1 node projection, register-tiled 4 nodes x 4 cols per thread.
// ---------------------------------------------------------------------------
__global__ void __launch_bounds__(256)
k4_proj1(const float* __restrict__ x, const float* __restrict__ W,
         const float* __restrict__ asf, const float* __restrict__ adf,
         float* __restrict__ hp, float* __restrict__ asn, float* __restrict__ adn) {
    __shared__ float sxT[F_IN * 33]; // [f][i], i in [0,32), pad 1
    int t = threadIdx.x;
    int n0 = blockIdx.x * 32;
    {
        int f = t & 63, i0 = t >> 6;
#pragma unroll
        for (int s = 0; s < 8; ++s) {
            int i = i0 + s * 4;
            int n = n0 + i;
            sxT[f * 33 + i] = (n < N_NODES) ? x[(size_t)n * F_IN + f] : 0.f;
        }
    }
    __syncthreads();
    int kq = t & 31, nq = t >> 5;
    float acc[4][4] = {};
    for (int f = 0; f < F_IN; ++f) {
        float a0 = sxT[f * 33 + nq * 4 + 0];
        float a1 = sxT[f * 33 + nq * 4 + 1];
        float a2 = sxT[f * 33 + nq * 4 + 2];
        float a3 = sxT[f * 33 + nq * 4 + 3];
        float4 w4 = *reinterpret_cast<const float4*>(W + (size_t)f * K_DIM + kq * 4);
        acc[0][0] += a0 * w4.x; acc[0][1] += a0 * w4.y; acc[0][2] += a0 * w4.z; acc[0][3] += a0 * w4.w;
        acc[1][0] += a1 * w4.x; acc[1][1] += a1 * w4.y; acc[1][2] += a1 * w4.z; acc[1][3] += a1 * w4.w;
        acc[2][0] += a2 * w4.x; acc[2][1] += a2 * w4.y; acc[2][2] += a2 * w4.z; acc[2][3] += a2 * w4.w;
        acc[3][0] += a3 * w4.x; acc[3][1] += a3 * w4.y; acc[3][2] += a3 * w4.z; acc[3][3] += a3 * w4.w;
    }
    int head = kq >> 3;
    float4 va = *reinterpret_cast<const float4*>(asf + kq * 4);
    float4 vd = *reinterpret_cast<const float4*>(adf + kq * 4);
#pragma unroll
    for (int i = 0; i < 4; ++i) {
        int n = n0 + nq * 4 + i;
        if (n < N_NODES)
            *reinterpret_cast<float4*>(hp + (size_t)n * K_DIM + kq * 4) =
                make_float4(acc[i][0], acc[i][1], acc[i][2], acc[i][3]);
        float s = acc[i][0] * va.x + acc[i][1] * va.y + acc[i][2] * va.z + acc[i][3] * va.w;
        float d = acc[i][0] * vd.x + acc[i][1] * vd.y + acc[i][2] * vd.z + acc[i][3] * vd.w;
#pragma unroll
        for (int m = 1; m < 8; m <<= 1) {
            s += __shfl_xor(s, m, 8);
            d += __shfl_xor(d, m, 8);
        }
        if ((kq & 7) == 0 && n < N_NODES) {
            asn[(size_t)n * 4 + head] = s;
            adn[(size_t)n * 4 + head] = d;
        }
    }
}

// ---------------------------------------------------------------------------
// K5: layer-1 gather aggregation. One 64-lane wave per node; lane owns 2
//     output columns. 2-way unrolled. Edge records: wave-uniform base ->
//     broadcast loads of src + ae1[head].
// ---------------------------------------------------------------------------
__global__ void __launch_bounds__(256)
k5_agg1(const int* __restrict__ starts, const float* __restrict__ el,
        const float* __restrict__ asn, const float* __restrict__ adn,
        const float* __restrict__ hp, const float* __restrict__ b1,
        float* __restrict__ x2) {
    int t = threadIdx.x;
    int lane = t & 63;
    int node = blockIdx.x * 4 + (t >> 6);
    if (node >= N_NODES) return;
    int s = starts[node], e = starts[node + 1];
    int head = lane >> 4; // col pair = lane*2; head = (lane*2)>>5
    float adv = adn[(size_t)node * 4 + head];
    float accx = 0.f, accy = 0.f, dsum = 0.f, aesum = 0.f;
    int j = s;
    for (; j + 2 <= e; j += 2) {
        const float* r0 = el + (size_t)j * 16;
        const float* r1 = el + (size_t)(j + 1) * 16;
        int src0 = __float_as_int(r0[0]);
        int src1 = __float_as_int(r1[0]);
        float ae0 = r0[4 + head];
        float ae1 = r1[4 + head];
        float av0 = asn[(size_t)src0 * 4 + head];
        float av1 = asn[(size_t)src1 * 4 + head];
        float2 h0 = *reinterpret_cast<const float2*>(hp + (size_t)src0 * K_DIM + lane * 2);
        float2 h1 = *reinterpret_cast<const float2*>(hp + (size_t)src1 * K_DIM + lane * 2);
        float ex0 = __expf(lrelu(av0 + adv + ae0));
        float ex1 = __expf(lrelu(av1 + adv + ae1));
        accx = fmaf(ex0, h0.x, fmaf(ex1, h1.x, accx));
        accy = fmaf(ex0, h0.y, fmaf(ex1, h1.y, accy));
        dsum += ex0 + ex1;
        aesum += ae0 + ae1;
    }
    if (j < e) {
        const float* r0 = el + (size_t)j * 16;
        int src = __float_as_int(r0[0]);
        float ae = r0[4 + head];
        float av = asn[(size_t)src * 4 + head];
        float ex = __expf(lrelu(av + adv + ae));
        float2 hv = *reinterpret_cast<const float2*>(hp + (size_t)src * K_DIM + lane * 2);
        accx = fmaf(ex, hv.x, accx);
        accy = fmaf(ex, hv.y, accy);
        dsum += ex;
        aesum += ae;
    }
    float deg = (float)(e - s);
    float al = aesum / fmaxf(deg, 1.f); // self-loop a_e = mean of incoming
    float exl = __expf(lrelu(asn[(size_t)node * 4 + head] + adv + al));
    float2 hv = *reinterpret_cast<const float2*>(hp + (size_t)node * K_DIM + lane * 2);
    accx += exl * hv.x;
    accy += exl * hv.y;
    dsum += exl;
    float2 bb = *reinterpret_cast<const float2*>(b1 + lane * 2);
    float2 o;
    o.x = fmaxf(accx / dsum + bb.x, 0.f);
    o.y = fmaxf(accy / dsum + bb.y, 0.f);
    *reinterpret_cast<float2*>(x2 + (size_t)node * K_DIM + lane * 2) = o;
}

// ---------------------------------------------------------------------------
// K6: layer-2 node projection, register-tiled like K4 (F=128). Outputs packed
//     asg[n] = {a_s2[4], g[4]} + adn2. h2p never materialized.
// ---------------------------------------------------------------------------
__global__ void __launch_bounds__(256)
k6_proj2(const float* __restrict__ x2, const float* __restrict__ W2,
         const float* __restrict__ asf, const float* __restrict__ adf,
         const float* __restrict__ linw,
         float* __restrict__ asg, float* __restrict__ adn) {
    __shared__ float sxT[K_DIM * 33]; // [f][i], i in [0,32), pad 1
    int t = threadIdx.x;
    int n0 = blockIdx.x * 32;
    {
        int f = t & 127, i0 = t >> 7;
#pragma unroll
        for (int s = 0; s < 16; ++s) {
            int i = i0 + s * 2;
            int n = n0 + i;
            sxT[f * 33 + i] = (n < N_NODES) ? x2[(size_t)n * K_DIM + f] : 0.f;
        }
    }
    __syncthreads();
    int kq = t & 31, nq = t >> 5;
    float acc[4][4] = {};
    for (int f = 0; f < K_DIM; ++f) {
        float a0 = sxT[f * 33 + nq * 4 + 0];
        float a1 = sxT[f * 33 + nq * 4 + 1];
        float a2 = sxT[f * 33 + nq * 4 + 2];
        float a3 = sxT[f * 33 + nq * 4 + 3];
        float4 w4 = *reinterpret_cast<const float4*>(W2 + (size_t)f * K_DIM + kq * 4);
        acc[0][0] += a0 * w4.x; acc[0][1] += a0 * w4.y; acc[0][2] += a0 * w4.z; acc[0][3] += a0 * w4.w;
        acc[1][0] += a1 * w4.x; acc[1][1] += a1 * w4.y; acc[1][2] += a1 * w4.z; acc[1][3] += a1 * w4.w;
        acc[2][0] += a2 * w4.x; acc[2][1] += a2 * w4.y; acc[2][2] += a2 * w4.z; acc[2][3] += a2 * w4.w;
        acc[3][0] += a3 * w4.x; acc[3][1] += a3 * w4.y; acc[3][2] += a3 * w4.z; acc[3][3] += a3 * w4.w;
    }
    int head = kq >> 3;
    float4 va = *reinterpret_cast<const float4*>(asf + kq * 4);
    float4 vd = *reinterpret_cast<const float4*>(adf + kq * 4);
    float4 vg = *reinterpret_cast<const float4*>(linw + kq * 4);
#pragma unroll
    for (int i = 0; i < 4; ++i) {
        int n = n0 + nq * 4 + i;
        float s = acc[i][0] * va.x + acc[i][1] * va.y + acc[i][2] * va.z + acc[i][3] * va.w;
        float d = acc[i][0] * vd.x + acc[i][1] * vd.y + acc[i][2] * vd.z + acc[i][3] * vd.w;
        float g = acc[i][0] * vg.x + acc[i][1] * vg.y + acc[i][2] * vg.z + acc[i][3] * vg.w;
#pragma unroll
        for (int m = 1; m < 8; m <<= 1) {
            s += __shfl_xor(s, m, 8);
            d += __shfl_xor(d, m, 8);
            g += __shfl_xor(g, m, 8);
        }
        if ((kq & 7) == 0 && n < N_NODES) {
            asg[(size_t)n * 8 + head] = s;
            asg[(size_t)n * 8 + 4 + head] = g;
            adn[(size_t)n * 4 + head] = d;
        }
    }
}

// ---------------------------------------------------------------------------
// K7: layer-2 gather: 16-lane group per node, lanes stride the edge list.
//     Per-lane reads of the 64 B record: src (dword0) + ae2 (aligned float4
//     at +32 B) -> one line per edge.
// ---------------------------------------------------------------------------
__global__ void __launch_bounds__(256)
k7_l2(const int* __restrict__ starts, const float* __restrict__ el,
      const float* __restrict__ asg, const float* __restrict__ adn,
      const float* __restrict__ cbias, float* __restrict__ out) {
    int t = threadIdx.x;
    int g16 = t & 15;
    int node = blockIdx.x * 16 + (t >> 4);
    if (node >= N_NODES) return;
    int s = starts[node], e = starts[node + 1];
    float4 ad4 = *reinterpret_cast<const float4*>(adn + (size_t)node * 4);
    float4 dsum = make_float4(0, 0, 0, 0);
    float4 gsum = make_float4(0, 0, 0, 0);
    float4 aesum = make_float4(0, 0, 0, 0);
    for (int j = s + g16; j < e; j += 16) {
        const float* rb = el + (size_t)j * 16;
        int src = __float_as_int(rb[0]);
        float4 ae4 = *reinterpret_cast<const float4*>(rb + 8);
        const float* ap = asg + (size_t)src * 8;
        float4 as4 = *reinterpret_cast<const float4*>(ap);
        float4 g4  = *reinterpret_cast<const float4*>(ap + 4);
        float e0 = __expf(lrelu(as4.x + ad4.x + ae4.x));
        float e1 = __expf(lrelu(as4.y + ad4.y + ae4.y));
        float e2 = __expf(lrelu(as4.z + ad4.z + ae4.z));
        float e3 = __expf(lrelu(as4.w + ad4.w + ae4.w));
        dsum.x += e0; dsum.y += e1; dsum.z += e2; dsum.w += e3;
        gsum.x += e0 * g4.x; gsum.y += e1 * g4.y; gsum.z += e2 * g4.z; gsum.w += e3 * g4.w;
        aesum.x += ae4.x; aesum.y += ae4.y; aesum.z += ae4.z; aesum.w += ae4.w;
    }
#pragma unroll
    for (int m = 1; m < 16; m <<= 1) {
        dsum.x += __shfl_xor(dsum.x, m, 16);  dsum.y += __shfl_xor(dsum.y, m, 16);
        dsum.z += __shfl_xor(dsum.z, m, 16);  dsum.w += __shfl_xor(dsum.w, m, 16);
        gsum.x += __shfl_xor(gsum.x, m, 16);  gsum.y += __shfl_xor(gsum.y, m, 16);
        gsum.z += __shfl_xor(gsum.z, m, 16);  gsum.w += __shfl_xor(gsum.w, m, 16);
        aesum.x += __shfl_xor(aesum.x, m, 16); aesum.y += __shfl_xor(aesum.y, m, 16);
        aesum.z += __shfl_xor(aesum.z, m, 16); aesum.w += __shfl_xor(aesum.w, m, 16);
    }
    if (g16 == 0) {
        float deg = fmaxf((float)(e - s), 1.f);
        const float* ap = asg + (size_t)node * 8;
        float4 mas = *reinterpret_cast<const float4*>(ap);
        float4 mg  = *reinterpret_cast<const float4*>(ap + 4);
        float r = cbias[0];
        float e0;
        e0 = __expf(lrelu(mas.x + ad4.x + aesum.x / deg)); r += (gsum.x + e0 * mg.x) / (dsum.x + e0);
        e0 = __expf(lrelu(mas.y + ad4.y + aesum.y / deg)); r += (gsum.y + e0 * mg.y) / (dsum.y + e0);
        e0 = __expf(lrelu(mas.z + ad4.z + aesum.z / deg)); r += (gsum.z + e0 * mg.z) / (dsum.z + e0);
        e0 = __expf(lrelu(mas.w + ad4.w + aesum.w / deg)); r += (gsum.w + e0 * mg.w) / (dsum.w + e0);
        out[node] = r;
    }
}

// ---------------------------------------------------------------------------
extern "C" void kernel_launch(void* const* d_in, const int* in_sizes, int n_in,
                              void* d_out, int out_size, void* d_ws, size_t ws_size,
                              hipStream_t stream) {
    (void)in_sizes; (void)n_in; (void)out_size;
    const float* x    = (const float*)d_in[0];
    const float* ea   = (const float*)d_in[1];
    const float* W1   = (const float*)d_in[2];
    const float* as1  = (const float*)d_in[3];
    const float* ad1  = (const float*)d_in[4];
    const float* We1  = (const float*)d_in[5];
    const float* ae1  = (const float*)d_in[6];
    const float* b1   = (const float*)d_in[7];
    const float* W2   = (const float*)d_in[8];
    const float* as2  = (const float*)d_in[9];
    const float* ad2  = (const float*)d_in[10];
    const float* We2  = (const float*)d_in[11];
    const float* ae2  = (const float*)d_in[12];
    const float* b2   = (const float*)d_in[13];
    const float* linw = (const float*)d_in[14];
    const float* linb = (const float*)d_in[15];
    const int*   ei   = (const int*)d_in[16];
    float* out = (float*)d_out;
    float* ws  = (float*)d_ws;

    const int SCAN_BLK = (N_NODES + 1023) / 1024; // 49

    size_t off = 0;
    float* h1p   = ws + off; off += (size_t)N_NODES * K_DIM;
    float* x2    = ws + off; off += (size_t)N_NODES * K_DIM;
    float* asn1  = ws + off; off += (size_t)N_NODES * 4;
    float* adn1  = ws + off; off += (size_t)N_NODES * 4;
    float* asg2  = ws + off; off += (size_t)N_NODES * 8;
    float* adn2  = ws + off; off += (size_t)N_NODES * 4;
    float* vbuf  = ws + off; off += 512;
    float* cbias = ws + off; off += 64;
    int* starts  = (int*)(ws + off); off += (size_t)N_NODES + 8;
    int* cursor  = (int*)(ws + off); off += (size_t)N_NODES;
    int* bsum    = (int*)(ws + off); off += 64;
    // pad to 16-float (64 B) boundary for el records
    off = (off + 15) & ~(size_t)15;
    float* el    = ws + off; off += (size_t)N_EDGES * 16; // 64 B records
    float* aer1  = ws + off; off += (size_t)N_EDGES * 4;
    float* aer2  = ws + off; off += (size_t)N_EDGES * 4;
    int* cnt     = (int*)(ws + off); off += (size_t)N_NODES;

    if (ws_size < off * sizeof(float)) return; // workspace too small: fail visibly

    hipMemsetAsync(cnt, 0, N_NODES * sizeof(int), stream);

    k0_fold<<<1, 256, 0, stream>>>(We1, ae1, We2, ae2, b2, linw, linb, vbuf, cbias);
    kc_count<<<(N_EDGES + 255) / 256, 256, 0, stream>>>(ei, cnt);
    k2a_bsum<<<SCAN_BLK, 1024, 0, stream>>>(cnt, bsum);
    k2b_scan<<<SCAN_BLK, 1024, 0, stream>>>(cnt, bsum, starts, cursor, SCAN_BLK);
    k1_edge<<<N_EDGES / 256, 256, 0, stream>>>(ea, vbuf, aer1, aer2);
    k3_scatter<<<N_EDGES / 256, 256, 0, stream>>>(ei, (const float4*)aer1, (const float4*)aer2,
                                                  cursor, (float4*)el);
    k4_proj1<<<(N_NODES + 31) / 32, 256, 0, stream>>>(x, W1, as1, ad1, h1p, asn1, adn1);
    k5_agg1<<<(N_NODES + 3) / 4, 256, 0, stream>>>(starts, el, asn1, adn1, h1p, b1, x2);
    k6_proj2<<<(N_NODES + 31) / 32, 256, 0, stream>>>(x2, W2, as2, ad2, linw, asg2, adn2);
    k7_l2<<<(N_NODES + 15) / 16, 256, 0, stream>>>(starts, el, asg2, adn2, cbias, out);
}

// Round 11
// 289.961 us; speedup vs baseline: 1.3426x; 1.0695x over previous
//
#include <hip/hip_runtime.h>
#include <hip/hip_fp16.h>

#define N_NODES 50000
#define N_EDGES 800000
#define F_IN    64
#define HEADS   4
#define CH      32
#define K_DIM   128
#define NEG     0.2f

__device__ __forceinline__ float lrelu(float x) { return x > 0.f ? x : NEG * x; }

// ---------------------------------------------------------------------------
// K0: fold We*ae -> v[o][f] (o=0..3 layer1 heads, 4..7 layer2 heads), and
//     cbias = dot(b2, lin_w) + lin_b
// ---------------------------------------------------------------------------
__global__ void k0_fold(const float* __restrict__ We1, const float* __restrict__ ae1,
                        const float* __restrict__ We2, const float* __restrict__ ae2,
                        const float* __restrict__ b2,  const float* __restrict__ linw,
                        const float* __restrict__ linb,
                        float* __restrict__ v, float* __restrict__ cbias) {
    int t = threadIdx.x; // 256 threads
    for (int idx = t; idx < 512; idx += 256) {
        int o = idx >> 6, f = idx & 63;
        const float* We = (o < 4) ? We1 : We2;
        const float* ae = (o < 4) ? ae1 : ae2;
        int h = o & 3;
        float s = 0.f;
        for (int c = 0; c < CH; ++c)
            s += We[f * K_DIM + h * CH + c] * ae[h * CH + c];
        v[o * 64 + f] = s;
    }
    if (t == 0) {
        float s = 0.f;
        for (int k = 0; k < K_DIM; ++k) s += b2[k] * linw[k];
        *cbias = s + linb[0];
    }
}

// ---------------------------------------------------------------------------
// Kc: degree count from ei only.
// ---------------------------------------------------------------------------
__global__ void __launch_bounds__(256)
kc_count(const int* __restrict__ ei, int* __restrict__ cnt) {
    int e = blockIdx.x * 256 + threadIdx.x;
    if (e >= N_EDGES) return;
    atomicAdd(cnt + ei[N_EDGES + e], 1);
}

// ---------------------------------------------------------------------------
// K2a/K2b: hierarchical exclusive scan.
// ---------------------------------------------------------------------------
__global__ void __launch_bounds__(1024)
k2a_bsum(const int* __restrict__ cnt, int* __restrict__ bsum) {
    __shared__ int ws[16];
    int t = threadIdx.x, lane = t & 63, wid = t >> 6;
    int i = blockIdx.x * 1024 + t;
    int v = (i < N_NODES) ? cnt[i] : 0;
#pragma unroll
    for (int m = 1; m < 64; m <<= 1) v += __shfl_xor(v, m, 64);
    if (lane == 0) ws[wid] = v;
    __syncthreads();
    if (t == 0) {
        int s = 0;
#pragma unroll
        for (int k = 0; k < 16; ++k) s += ws[k];
        bsum[blockIdx.x] = s;
    }
}

__global__ void __launch_bounds__(1024)
k2b_scan(const int* __restrict__ cnt, const int* __restrict__ bsum,
         int* __restrict__ starts, int* __restrict__ cursor, int nblk) {
    __shared__ int wsum[16];
    __shared__ int s_off;
    int t = threadIdx.x, lane = t & 63, wid = t >> 6;
    int bid = blockIdx.x;
    if (t == 0) {
        int o = 0;
        for (int b = 0; b < bid; ++b) o += bsum[b];
        s_off = o;
    }
    int i = bid * 1024 + t;
    int v = (i < N_NODES) ? cnt[i] : 0;
    int sc = v; // inclusive wave scan
#pragma unroll
    for (int s = 1; s < 64; s <<= 1) {
        int u = __shfl_up(sc, s, 64);
        if (lane >= s) sc += u;
    }
    if (lane == 63) wsum[wid] = sc;
    __syncthreads();
    if (wid == 0 && lane < 16) {
        int ws = wsum[lane];
#pragma unroll
        for (int s = 1; s < 16; s <<= 1) {
            int u = __shfl_up(ws, s, 64);
            if (lane >= s) ws += u;
        }
        wsum[lane] = ws;
    }
    __syncthreads();
    int off = s_off + ((wid == 0) ? 0 : wsum[wid - 1]);
    int excl = off + sc - v;
    if (i < N_NODES) { starts[i] = excl; cursor[i] = excl; }
    if (bid == nblk - 1 && t == 1023) starts[N_NODES] = s_off + wsum[15];
}

// ---------------------------------------------------------------------------
// K1: per-edge a_e, PURE STREAM. Coalesced LDS-tile staging, v-row in 16
//     float4 regs, writes aer1/aer2 in EDGE ORDER. No atomics, no scatter.
// ---------------------------------------------------------------------------
__global__ void __launch_bounds__(256)
k1_edge(const float* __restrict__ ea, const float* __restrict__ v,
        float* __restrict__ aer1, float* __restrict__ aer2) {
    __shared__ float sx[2][32 * 68];
    int t = threadIdx.x;
    int o  = t & 7;   // output index (0..3: layer1 heads, 4..7: layer2 heads)
    int le = t >> 3;  // local edge within tile (0..31)
    float4 vr[16];
    {
        const float4* vrow = reinterpret_cast<const float4*>(v + o * 64);
#pragma unroll
        for (int c = 0; c < 16; ++c) vr[c] = vrow[c];
    }
    const float4* ea4 = reinterpret_cast<const float4*>(ea);
    int base = blockIdx.x * 256; // 8 tiles * 32 edges
    {
        size_t gb = (size_t)base * 16;
        float4 a = ea4[gb + t];
        float4 b = ea4[gb + t + 256];
        int g0 = t, g1 = t + 256;
        *reinterpret_cast<float4*>(&sx[0][(g0 >> 4) * 68 + (g0 & 15) * 4]) = a;
        *reinterpret_cast<float4*>(&sx[0][(g1 >> 4) * 68 + (g1 & 15) * 4]) = b;
    }
    __syncthreads();
    for (int tile = 0; tile < 8; ++tile) {
        float4 a, b;
        if (tile < 7) { // prefetch next tile (coalesced)
            size_t gb = (size_t)(base + (tile + 1) * 32) * 16;
            a = ea4[gb + t];
            b = ea4[gb + t + 256];
        }
        const float* row = &sx[tile & 1][le * 68];
        float4 ac = make_float4(0.f, 0.f, 0.f, 0.f);
#pragma unroll
        for (int c = 0; c < 16; ++c) {
            float4 x4 = *reinterpret_cast<const float4*>(row + c * 4);
            ac.x = fmaf(x4.x, vr[c].x, ac.x);
            ac.y = fmaf(x4.y, vr[c].y, ac.y);
            ac.z = fmaf(x4.z, vr[c].z, ac.z);
            ac.w = fmaf(x4.w, vr[c].w, ac.w);
        }
        float acc = (ac.x + ac.y) + (ac.z + ac.w);
        int eid = base + tile * 32 + le;
        float* ob = (o < 4) ? aer1 : aer2;
        ob[(size_t)eid * 4 + (o & 3)] = acc;   // edge-order: coalesced
        if (tile < 7) { // write next tile into other buffer
            int g0 = t, g1 = t + 256;
            int nb = (tile + 1) & 1;
            *reinterpret_cast<float4*>(&sx[nb][(g0 >> 4) * 68 + (g0 & 15) * 4]) = a;
            *reinterpret_cast<float4*>(&sx[nb][(g1 >> 4) * 68 + (g1 & 15) * 4]) = b;
        }
        __syncthreads();
    }
}

// ---------------------------------------------------------------------------
// K4: layer-1 node projection, register-tiled 4 nodes x 4 cols per thread.
//     hp written as FP16 (R10: halves k5's gather bytes; ~5e-4 rel error,
//     12x threshold headroom). Runs BEFORE k3 so asn1 can be embedded.
// ---------------------------------------------------------------------------
__global__ void __launch_bounds__(256)
k4_proj1(const float* __restrict__ x, const float* __restrict__ W,
         const float* __restrict__ asf, const float* __restrict__ adf,
         __half* __restrict__ hp, float* __restrict__ asn, float* __restrict__ adn) {
    __shared__ float sxT[F_IN * 33]; // [f][i], i in [0,32), pad 1
    int t = threadIdx.x;
    int n0 = blockIdx.x * 32;
    {
        int f = t & 63, i0 = t >> 6;
#pragma unroll
        for (int s = 0; s < 8; ++s) {
            int i = i0 + s * 4;
            int n = n0 + i;
            sxT[f * 33 + i] = (n < N_NODES) ? x[(size_t)n * F_IN + f] : 0.f;
        }
    }
    __syncthreads();
    int kq = t & 31, nq = t >> 5;
    float acc[4][4] = {};
    for (int f = 0; f < F_IN; ++f) {
        float a0 = sxT[f * 33 + nq * 4 + 0];
        float a1 = sxT[f * 33 + nq * 4 + 1];
        float a2 = sxT[f * 33 + nq * 4 + 2];
        float a3 = sxT[f * 33 + nq * 4 + 3];
        float4 w4 = *reinterpret_cast<const float4*>(W + (size_t)f * K_DIM + kq * 4);
        acc[0][0] += a0 * w4.x; acc[0][1] += a0 * w4.y; acc[0][2] += a0 * w4.z; acc[0][3] += a0 * w4.w;
        acc[1][0] += a1 * w4.x; acc[1][1] += a1 * w4.y; acc[1][2] += a1 * w4.z; acc[1][3] += a1 * w4.w;
        acc[2][0] += a2 * w4.x; acc[2][1] += a2 * w4.y; acc[2][2] += a2 * w4.z; acc[2][3] += a2 * w4.w;
        acc[3][0] += a3 * w4.x; acc[3][1] += a3 * w4.y; acc[3][2] += a3 * w4.z; acc[3][3] += a3 * w4.w;
    }
    int head = kq >> 3;
    float4 va = *reinterpret_cast<const float4*>(asf + kq * 4);
    float4 vd = *reinterpret_cast<const float4*>(adf + kq * 4);
#pragma unroll
    for (int i = 0; i < 4; ++i) {
        int n = n0 + nq * 4 + i;
        if (n < N_NODES) {
            __half2* hp2 = reinterpret_cast<__half2*>(hp + (size_t)n * K_DIM + kq * 4);
            hp2[0] = __float22half2_rn(make_float2(acc[i][0], acc[i][1]));
            hp2[1] = __float22half2_rn(make_float2(acc[i][2], acc[i][3]));
        }
        float s = acc[i][0] * va.x + acc[i][1] * va.y + acc[i][2] * va.z + acc[i][3] * va.w;
        float d = acc[i][0] * vd.x + acc[i][1] * vd.y + acc[i][2] * vd.z + acc[i][3] * vd.w;
#pragma unroll
        for (int m = 1; m < 8; m <<= 1) {
            s += __shfl_xor(s, m, 8);
            d += __shfl_xor(d, m, 8);
        }
        if ((kq & 7) == 0 && n < N_NODES) {
            asn[(size_t)n * 4 + head] = s;
            adn[(size_t)n * 4 + head] = d;
        }
    }
}

// ---------------------------------------------------------------------------
// K3: scatter into dst-sorted 64 B edge records, now EMBEDDING a_s1[src]+ae1
//     (R10: removes k5's per-edge asn gather -> 1-deep chain). Record:
//     [src pad pad pad | as1[src]+ae1 x4 | ae2 x4 | ae1raw x4]. Four float4
//     stores = full line, no RMW. asn1 gather (16 B, L2) issues alongside
//     the atomic. Requires k4 before k3.
// ---------------------------------------------------------------------------
__global__ void __launch_bounds__(256)
k3_scatter(const int* __restrict__ ei, const float4* __restrict__ aer1,
           const float4* __restrict__ aer2, const float* __restrict__ asn,
           int* __restrict__ cursor, float4* __restrict__ el) {
    int e = blockIdx.x * 256 + threadIdx.x;
    if (e >= N_EDGES) return;
    int dst = ei[N_EDGES + e];
    int src = ei[e];
    int pos = atomicAdd(cursor + dst, 1);   // atomic in flight alongside gathers
    float4 a1 = aer1[e];
    float4 a2 = aer2[e];
    float4 as4 = *reinterpret_cast<const float4*>(asn + (size_t)src * 4);
    float4* r = el + (size_t)pos * 4;
    r[0] = make_float4(__int_as_float(src), 0.f, 0.f, 0.f);
    r[1] = make_float4(as4.x + a1.x, as4.y + a1.y, as4.z + a1.z, as4.w + a1.w);
    r[2] = a2;
    r[3] = a1;
}

// ---------------------------------------------------------------------------
// K5: layer-1 gather aggregation. One 64-lane wave per node; lane owns 2
//     output columns. 1-deep chain (sa pre-embedded), fp16 hp rows (256 B).
// ---------------------------------------------------------------------------
__global__ void __launch_bounds__(256)
k5_agg1(const int* __restrict__ starts, const float* __restrict__ el,
        const float* __restrict__ asn, const float* __restrict__ adn,
        const __half* __restrict__ hp, const float* __restrict__ b1,
        float* __restrict__ x2) {
    int t = threadIdx.x;
    int lane = t & 63;
    int node = blockIdx.x * 4 + (t >> 6);
    if (node >= N_NODES) return;
    int s = starts[node], e = starts[node + 1];
    int head = lane >> 4; // col pair = lane*2; head = (lane*2)>>5
    float adv = adn[(size_t)node * 4 + head];
    float accx = 0.f, accy = 0.f, dsum = 0.f, aesum = 0.f;
    int j = s;
    for (; j + 2 <= e; j += 2) {
        const float* r0 = el + (size_t)j * 16;
        const float* r1 = el + (size_t)(j + 1) * 16;
        int src0 = __float_as_int(r0[0]);
        int src1 = __float_as_int(r1[0]);
        float sa0 = r0[4 + head];
        float sa1 = r1[4 + head];
        float ar0 = r0[12 + head];
        float ar1 = r1[12 + head];
        float2 h0 = __half22float2(*reinterpret_cast<const __half2*>(hp + (size_t)src0 * K_DIM + lane * 2));
        float2 h1 = __half22float2(*reinterpret_cast<const __half2*>(hp + (size_t)src1 * K_DIM + lane * 2));
        float ex0 = __expf(lrelu(sa0 + adv));
        float ex1 = __expf(lrelu(sa1 + adv));
        accx = fmaf(ex0, h0.x, fmaf(ex1, h1.x, accx));
        accy = fmaf(ex0, h0.y, fmaf(ex1, h1.y, accy));
        dsum += ex0 + ex1;
        aesum += ar0 + ar1;
    }
    if (j < e) {
        const float* r0 = el + (size_t)j * 16;
        int src = __float_as_int(r0[0]);
        float sa = r0[4 + head];
        float ar = r0[12 + head];
        float ex = __expf(lrelu(sa + adv));
        float2 hv = __half22float2(*reinterpret_cast<const __half2*>(hp + (size_t)src * K_DIM + lane * 2));
        accx = fmaf(ex, hv.x, accx);
        accy = fmaf(ex, hv.y, accy);
        dsum += ex;
        aesum += ar;
    }
    float deg = (float)(e - s);
    float al = aesum / fmaxf(deg, 1.f); // self-loop a_e = mean of incoming
    float exl = __expf(lrelu(asn[(size_t)node * 4 + head] + adv + al));
    float2 hv = __half22float2(*reinterpret_cast<const __half2*>(hp + (size_t)node * K_DIM + lane * 2));
    accx += exl * hv.x;
    accy += exl * hv.y;
    dsum += exl;
    float2 bb = *reinterpret_cast<const float2*>(b1 + lane * 2);
    float2 o;
    o.x = fmaxf(accx / dsum + bb.x, 0.f);
    o.y = fmaxf(accy / dsum + bb.y, 0.f);
    *reinterpret_cast<float2*>(x2 + (size_t)node * K_DIM + lane * 2) = o;
}

// ---------------------------------------------------------------------------
// K6: layer-2 node projection, register-tiled like K4 (F=128). Outputs packed
//     asg[n] = {a_s2[4], g[4]} + adn2. h2p never materialized.
// ---------------------------------------------------------------------------
__global__ void __launch_bounds__(256)
k6_proj2(const float* __restrict__ x2, const float* __restrict__ W2,
         const float* __restrict__ asf, const float* __restrict__ adf,
         const float* __restrict__ linw,
         float* __restrict__ asg, float* __restrict__ adn) {
    __shared__ float sxT[K_DIM * 33]; // [f][i], i in [0,32), pad 1
    int t = threadIdx.x;
    int n0 = blockIdx.x * 32;
    {
        int f = t & 127, i0 = t >> 7;
#pragma unroll
        for (int s = 0; s < 16; ++s) {
            int i = i0 + s * 2;
            int n = n0 + i;
            sxT[f * 33 + i] = (n < N_NODES) ? x2[(size_t)n * K_DIM + f] : 0.f;
        }
    }
    __syncthreads();
    int kq = t & 31, nq = t >> 5;
    float acc[4][4] = {};
    for (int f = 0; f < K_DIM; ++f) {
        float a0 = sxT[f * 33 + nq * 4 + 0];
        float a1 = sxT[f * 33 + nq * 4 + 1];
        float a2 = sxT[f * 33 + nq * 4 + 2];
        float a3 = sxT[f * 33 + nq * 4 + 3];
        float4 w4 = *reinterpret_cast<const float4*>(W2 + (size_t)f * K_DIM + kq * 4);
        acc[0][0] += a0 * w4.x; acc[0][1] += a0 * w4.y; acc[0][2] += a0 * w4.z; acc[0][3] += a0 * w4.w;
        acc[1][0] += a1 * w4.x; acc[1][1] += a1 * w4.y; acc[1][2] += a1 * w4.z; acc[1][3] += a1 * w4.w;
        acc[2][0] += a2 * w4.x; acc[2][1] += a2 * w4.y; acc[2][2] += a2 * w4.z; acc[2][3] += a2 * w4.w;
        acc[3][0] += a3 * w4.x; acc[3][1] += a3 * w4.y; acc[3][2] += a3 * w4.z; acc[3][3] += a3 * w4.w;
    }
    int head = kq >> 3;
    float4 va = *reinterpret_cast<const float4*>(asf + kq * 4);
    float4 vd = *reinterpret_cast<const float4*>(adf + kq * 4);
    float4 vg = *reinterpret_cast<const float4*>(linw + kq * 4);
#pragma unroll
    for (int i = 0; i < 4; ++i) {
        int n = n0 + nq * 4 + i;
        float s = acc[i][0] * va.x + acc[i][1] * va.y + acc[i][2] * va.z + acc[i][3] * va.w;
        float d = acc[i][0] * vd.x + acc[i][1] * vd.y + acc[i][2] * vd.z + acc[i][3] * vd.w;
        float g = acc[i][0] * vg.x + acc[i][1] * vg.y + acc[i][2] * vg.z + acc[i][3] * vg.w;
#pragma unroll
        for (int m = 1; m < 8; m <<= 1) {
            s += __shfl_xor(s, m, 8);
            d += __shfl_xor(d, m, 8);
            g += __shfl_xor(g, m, 8);
        }
        if ((kq & 7) == 0 && n < N_NODES) {
            asg[(size_t)n * 8 + head] = s;
            asg[(size_t)n * 8 + 4 + head] = g;
            adn[(size_t)n * 4 + head] = d;
        }
    }
}

// ---------------------------------------------------------------------------
// K7: layer-2 gather: 16-lane group per node, lanes stride the edge list.
//     Per-lane reads of the 64 B record: src (dword0) + ae2 (aligned float4
//     at +32 B) -> one line per edge.
// ---------------------------------------------------------------------------
__global__ void __launch_bounds__(256)
k7_l2(const int* __restrict__ starts, const float* __restrict__ el,
      const float* __restrict__ asg, const float* __restrict__ adn,
      const float* __restrict__ cbias, float* __restrict__ out) {
    int t = threadIdx.x;
    int g16 = t & 15;
    int node = blockIdx.x * 16 + (t >> 4);
    if (node >= N_NODES) return;
    int s = starts[node], e = starts[node + 1];
    float4 ad4 = *reinterpret_cast<const float4*>(adn + (size_t)node * 4);
    float4 dsum = make_float4(0, 0, 0, 0);
    float4 gsum = make_float4(0, 0, 0, 0);
    float4 aesum = make_float4(0, 0, 0, 0);
    for (int j = s + g16; j < e; j += 16) {
        const float* rb = el + (size_t)j * 16;
        int src = __float_as_int(rb[0]);
        float4 ae4 = *reinterpret_cast<const float4*>(rb + 8);
        const float* ap = asg + (size_t)src * 8;
        float4 as4 = *reinterpret_cast<const float4*>(ap);
        float4 g4  = *reinterpret_cast<const float4*>(ap + 4);
        float e0 = __expf(lrelu(as4.x + ad4.x + ae4.x));
        float e1 = __expf(lrelu(as4.y + ad4.y + ae4.y));
        float e2 = __expf(lrelu(as4.z + ad4.z + ae4.z));
        float e3 = __expf(lrelu(as4.w + ad4.w + ae4.w));
        dsum.x += e0; dsum.y += e1; dsum.z += e2; dsum.w += e3;
        gsum.x += e0 * g4.x; gsum.y += e1 * g4.y; gsum.z += e2 * g4.z; gsum.w += e3 * g4.w;
        aesum.x += ae4.x; aesum.y += ae4.y; aesum.z += ae4.z; aesum.w += ae4.w;
    }
#pragma unroll
    for (int m = 1; m < 16; m <<= 1) {
        dsum.x += __shfl_xor(dsum.x, m, 16);  dsum.y += __shfl_xor(dsum.y, m, 16);
        dsum.z += __shfl_xor(dsum.z, m, 16);  dsum.w += __shfl_xor(dsum.w, m, 16);
        gsum.x += __shfl_xor(gsum.x, m, 16);  gsum.y += __shfl_xor(gsum.y, m, 16);
        gsum.z += __shfl_xor(gsum.z, m, 16);  gsum.w += __shfl_xor(gsum.w, m, 16);
        aesum.x += __shfl_xor(aesum.x, m, 16); aesum.y += __shfl_xor(aesum.y, m, 16);
        aesum.z += __shfl_xor(aesum.z, m, 16); aesum.w += __shfl_xor(aesum.w, m, 16);
    }
    if (g16 == 0) {
        float deg = fmaxf((float)(e - s), 1.f);
        const float* ap = asg + (size_t)node * 8;
        float4 mas = *reinterpret_cast<const float4*>(ap);
        float4 mg  = *reinterpret_cast<const float4*>(ap + 4);
        float r = cbias[0];
        float e0;
        e0 = __expf(lrelu(mas.x + ad4.x + aesum.x / deg)); r += (gsum.x + e0 * mg.x) / (dsum.x + e0);
        e0 = __expf(lrelu(mas.y + ad4.y + aesum.y / deg)); r += (gsum.y + e0 * mg.y) / (dsum.y + e0);
        e0 = __expf(lrelu(mas.z + ad4.z + aesum.z / deg)); r += (gsum.z + e0 * mg.z) / (dsum.z + e0);
        e0 = __expf(lrelu(mas.w + ad4.w + aesum.w / deg)); r += (gsum.w + e0 * mg.w) / (dsum.w + e0);
        out[node] = r;
    }
}

// ---------------------------------------------------------------------------
extern "C" void kernel_launch(void* const* d_in, const int* in_sizes, int n_in,
                              void* d_out, int out_size, void* d_ws, size_t ws_size,
                              hipStream_t stream) {
    (void)in_sizes; (void)n_in; (void)out_size;
    const float* x    = (const float*)d_in[0];
    const float* ea   = (const float*)d_in[1];
    const float* W1   = (const float*)d_in[2];
    const float* as1  = (const float*)d_in[3];
    const float* ad1  = (const float*)d_in[4];
    const float* We1  = (const float*)d_in[5];
    const float* ae1  = (const float*)d_in[6];
    const float* b1   = (const float*)d_in[7];
    const float* W2   = (const float*)d_in[8];
    const float* as2  = (const float*)d_in[9];
    const float* ad2  = (const float*)d_in[10];
    const float* We2  = (const float*)d_in[11];
    const float* ae2  = (const float*)d_in[12];
    const float* b2   = (const float*)d_in[13];
    const float* linw = (const float*)d_in[14];
    const float* linb = (const float*)d_in[15];
    const int*   ei   = (const int*)d_in[16];
    float* out = (float*)d_out;
    float* ws  = (float*)d_ws;

    const int SCAN_BLK = (N_NODES + 1023) / 1024; // 49

    size_t off = 0;
    __half* h1p  = (__half*)(ws + off); off += (size_t)N_NODES * K_DIM / 2; // fp16
    float* x2    = ws + off; off += (size_t)N_NODES * K_DIM;
    float* asn1  = ws + off; off += (size_t)N_NODES * 4;
    float* adn1  = ws + off; off += (size_t)N_NODES * 4;
    float* asg2  = ws + off; off += (size_t)N_NODES * 8;
    float* adn2  = ws + off; off += (size_t)N_NODES * 4;
    float* vbuf  = ws + off; off += 512;
    float* cbias = ws + off; off += 64;
    int* starts  = (int*)(ws + off); off += (size_t)N_NODES + 8;
    int* cursor  = (int*)(ws + off); off += (size_t)N_NODES;
    int* bsum    = (int*)(ws + off); off += 64;
    // pad to 16-float (64 B) boundary for el records
    off = (off + 15) & ~(size_t)15;
    float* el    = ws + off; off += (size_t)N_EDGES * 16; // 64 B records
    float* aer1  = ws + off; off += (size_t)N_EDGES * 4;
    float* aer2  = ws + off; off += (size_t)N_EDGES * 4;
    int* cnt     = (int*)(ws + off); off += (size_t)N_NODES;

    if (ws_size < off * sizeof(float)) return; // workspace too small: fail visibly

    hipMemsetAsync(cnt, 0, N_NODES * sizeof(int), stream);

    k0_fold<<<1, 256, 0, stream>>>(We1, ae1, We2, ae2, b2, linw, linb, vbuf, cbias);
    kc_count<<<(N_EDGES + 255) / 256, 256, 0, stream>>>(ei, cnt);
    k2a_bsum<<<SCAN_BLK, 1024, 0, stream>>>(cnt, bsum);
    k2b_scan<<<SCAN_BLK, 1024, 0, stream>>>(cnt, bsum, starts, cursor, SCAN_BLK);
    k1_edge<<<N_EDGES / 256, 256, 0, stream>>>(ea, vbuf, aer1, aer2);
    k4_proj1<<<(N_NODES + 31) / 32, 256, 0, stream>>>(x, W1, as1, ad1, h1p, asn1, adn1);
    k3_scatter<<<N_EDGES / 256, 256, 0, stream>>>(ei, (const float4*)aer1, (const float4*)aer2,
                                                  asn1, cursor, (float4*)el);
    k5_agg1<<<(N_NODES + 3) / 4, 256, 0, stream>>>(starts, el, asn1, adn1, h1p, b1, x2);
    k6_proj2<<<(N_NODES + 31) / 32, 256, 0, stream>>>(x2, W2, as2, ad2, linw, asg2, adn2);
    k7_l2<<<(N_NODES + 15) / 16, 256, 0, stream>>>(starts, el, asg2, adn2, cbias, out);
}

// Round 12
// 278.836 us; speedup vs baseline: 1.3961x; 1.0399x over previous
//
#include <hip/hip_runtime.h>
#include <hip/hip_fp16.h>

#define N_NODES 50000
#define N_EDGES 800000
#define F_IN    64
#define HEADS   4
#define CH      32
#define K_DIM   128
#define NEG     0.2f

__device__ __forceinline__ float lrelu(float x) { return x > 0.f ? x : NEG * x; }

__device__ __forceinline__ float h2bits(__half2 h) {
    return *reinterpret_cast<float*>(&h);
}
// pick head-th fp16 from two packed half2 words (lo2 = heads 0,1; hi2 = heads 2,3)
__device__ __forceinline__ float pick_half(float lo2, float hi2, int head) {
    float f = (head < 2) ? lo2 : hi2;
    __half2 h = *reinterpret_cast<__half2*>(&f);
    return (head & 1) ? __high2float(h) : __low2float(h);
}

// ---------------------------------------------------------------------------
// KC: degree count from ei; LAST block instead performs the weight fold
//     (We*ae -> v, cbias) -- merged k0, saves a launch.
// ---------------------------------------------------------------------------
__global__ void __launch_bounds__(256)
kc_fold(const int* __restrict__ ei, int* __restrict__ cnt,
        const float* __restrict__ We1, const float* __restrict__ ae1,
        const float* __restrict__ We2, const float* __restrict__ ae2,
        const float* __restrict__ b2,  const float* __restrict__ linw,
        const float* __restrict__ linb,
        float* __restrict__ v, float* __restrict__ cbias) {
    if (blockIdx.x >= N_EDGES / 256) { // fold block
        int t = threadIdx.x;
        for (int idx = t; idx < 512; idx += 256) {
            int o = idx >> 6, f = idx & 63;
            const float* We = (o < 4) ? We1 : We2;
            const float* ae = (o < 4) ? ae1 : ae2;
            int h = o & 3;
            float s = 0.f;
            for (int c = 0; c < CH; ++c)
                s += We[f * K_DIM + h * CH + c] * ae[h * CH + c];
            v[o * 64 + f] = s;
        }
        if (t == 0) {
            float s = 0.f;
            for (int k = 0; k < K_DIM; ++k) s += b2[k] * linw[k];
            *cbias = s + linb[0];
        }
        return;
    }
    int e = blockIdx.x * 256 + threadIdx.x;
    atomicAdd(cnt + ei[N_EDGES + e], 1);
}

// ---------------------------------------------------------------------------
// K2a/K2b: hierarchical exclusive scan.
// ---------------------------------------------------------------------------
__global__ void __launch_bounds__(1024)
k2a_bsum(const int* __restrict__ cnt, int* __restrict__ bsum) {
    __shared__ int ws[16];
    int t = threadIdx.x, lane = t & 63, wid = t >> 6;
    int i = blockIdx.x * 1024 + t;
    int v = (i < N_NODES) ? cnt[i] : 0;
#pragma unroll
    for (int m = 1; m < 64; m <<= 1) v += __shfl_xor(v, m, 64);
    if (lane == 0) ws[wid] = v;
    __syncthreads();
    if (t == 0) {
        int s = 0;
#pragma unroll
        for (int k = 0; k < 16; ++k) s += ws[k];
        bsum[blockIdx.x] = s;
    }
}

__global__ void __launch_bounds__(1024)
k2b_scan(const int* __restrict__ cnt, const int* __restrict__ bsum,
         int* __restrict__ starts, int* __restrict__ cursor, int nblk) {
    __shared__ int wsum[16];
    __shared__ int s_off;
    int t = threadIdx.x, lane = t & 63, wid = t >> 6;
    int bid = blockIdx.x;
    if (t == 0) {
        int o = 0;
        for (int b = 0; b < bid; ++b) o += bsum[b];
        s_off = o;
    }
    int i = bid * 1024 + t;
    int v = (i < N_NODES) ? cnt[i] : 0;
    int sc = v; // inclusive wave scan
#pragma unroll
    for (int s = 1; s < 64; s <<= 1) {
        int u = __shfl_up(sc, s, 64);
        if (lane >= s) sc += u;
    }
    if (lane == 63) wsum[wid] = sc;
    __syncthreads();
    if (wid == 0 && lane < 16) {
        int ws = wsum[lane];
#pragma unroll
        for (int s = 1; s < 16; s <<= 1) {
            int u = __shfl_up(ws, s, 64);
            if (lane >= s) ws += u;
        }
        wsum[lane] = ws;
    }
    __syncthreads();
    int off = s_off + ((wid == 0) ? 0 : wsum[wid - 1]);
    int excl = off + sc - v;
    if (i < N_NODES) { starts[i] = excl; cursor[i] = excl; }
    if (bid == nblk - 1 && t == 1023) starts[N_NODES] = s_off + wsum[15];
}

// ---------------------------------------------------------------------------
// K1: per-edge a_e, PURE STREAM. Coalesced LDS-tile staging, v-row in 16
//     float4 regs, writes aer1/aer2 in EDGE ORDER. No atomics, no scatter.
// ---------------------------------------------------------------------------
__global__ void __launch_bounds__(256)
k1_edge(const float* __restrict__ ea, const float* __restrict__ v,
        float* __restrict__ aer1, float* __restrict__ aer2) {
    __shared__ float sx[2][32 * 68];
    int t = threadIdx.x;
    int o  = t & 7;   // output index (0..3: layer1 heads, 4..7: layer2 heads)
    int le = t >> 3;  // local edge within tile (0..31)
    float4 vr[16];
    {
        const float4* vrow = reinterpret_cast<const float4*>(v + o * 64);
#pragma unroll
        for (int c = 0; c < 16; ++c) vr[c] = vrow[c];
    }
    const float4* ea4 = reinterpret_cast<const float4*>(ea);
    int base = blockIdx.x * 256; // 8 tiles * 32 edges
    {
        size_t gb = (size_t)base * 16;
        float4 a = ea4[gb + t];
        float4 b = ea4[gb + t + 256];
        int g0 = t, g1 = t + 256;
        *reinterpret_cast<float4*>(&sx[0][(g0 >> 4) * 68 + (g0 & 15) * 4]) = a;
        *reinterpret_cast<float4*>(&sx[0][(g1 >> 4) * 68 + (g1 & 15) * 4]) = b;
    }
    __syncthreads();
    for (int tile = 0; tile < 8; ++tile) {
        float4 a, b;
        if (tile < 7) { // prefetch next tile (coalesced)
            size_t gb = (size_t)(base + (tile + 1) * 32) * 16;
            a = ea4[gb + t];
            b = ea4[gb + t + 256];
        }
        const float* row = &sx[tile & 1][le * 68];
        float4 ac = make_float4(0.f, 0.f, 0.f, 0.f);
#pragma unroll
        for (int c = 0; c < 16; ++c) {
            float4 x4 = *reinterpret_cast<const float4*>(row + c * 4);
            ac.x = fmaf(x4.x, vr[c].x, ac.x);
            ac.y = fmaf(x4.y, vr[c].y, ac.y);
            ac.z = fmaf(x4.z, vr[c].z, ac.z);
            ac.w = fmaf(x4.w, vr[c].w, ac.w);
        }
        float acc = (ac.x + ac.y) + (ac.z + ac.w);
        int eid = base + tile * 32 + le;
        float* ob = (o < 4) ? aer1 : aer2;
        ob[(size_t)eid * 4 + (o & 3)] = acc;   // edge-order: coalesced
        if (tile < 7) { // write next tile into other buffer
            int g0 = t, g1 = t + 256;
            int nb = (tile + 1) & 1;
            *reinterpret_cast<float4*>(&sx[nb][(g0 >> 4) * 68 + (g0 & 15) * 4]) = a;
            *reinterpret_cast<float4*>(&sx[nb][(g1 >> 4) * 68 + (g1 & 15) * 4]) = b;
        }
        __syncthreads();
    }
}

// ---------------------------------------------------------------------------
// K4: layer-1 node projection, register-tiled 4 nodes x 4 cols per thread.
//     hp written as FP16. Runs BEFORE k3 so asn1 can be embedded.
// ---------------------------------------------------------------------------
__global__ void __launch_bounds__(256)
k4_proj1(const float* __restrict__ x, const float* __restrict__ W,
         const float* __restrict__ asf, const float* __restrict__ adf,
         __half* __restrict__ hp, float* __restrict__ asn, float* __restrict__ adn) {
    __shared__ float sxT[F_IN * 33]; // [f][i], i in [0,32), pad 1
    int t = threadIdx.x;
    int n0 = blockIdx.x * 32;
    {
        int f = t & 63, i0 = t >> 6;
#pragma unroll
        for (int s = 0; s < 8; ++s) {
            int i = i0 + s * 4;
            int n = n0 + i;
            sxT[f * 33 + i] = (n < N_NODES) ? x[(size_t)n * F_IN + f] : 0.f;
        }
    }
    __syncthreads();
    int kq = t & 31, nq = t >> 5;
    float acc[4][4] = {};
    for (int f = 0; f < F_IN; ++f) {
        float a0 = sxT[f * 33 + nq * 4 + 0];
        float a1 = sxT[f * 33 + nq * 4 + 1];
        float a2 = sxT[f * 33 + nq * 4 + 2];
        float a3 = sxT[f * 33 + nq * 4 + 3];
        float4 w4 = *reinterpret_cast<const float4*>(W + (size_t)f * K_DIM + kq * 4);
        acc[0][0] += a0 * w4.x; acc[0][1] += a0 * w4.y; acc[0][2] += a0 * w4.z; acc[0][3] += a0 * w4.w;
        acc[1][0] += a1 * w4.x; acc[1][1] += a1 * w4.y; acc[1][2] += a1 * w4.z; acc[1][3] += a1 * w4.w;
        acc[2][0] += a2 * w4.x; acc[2][1] += a2 * w4.y; acc[2][2] += a2 * w4.z; acc[2][3] += a2 * w4.w;
        acc[3][0] += a3 * w4.x; acc[3][1] += a3 * w4.y; acc[3][2] += a3 * w4.z; acc[3][3] += a3 * w4.w;
    }
    int head = kq >> 3;
    float4 va = *reinterpret_cast<const float4*>(asf + kq * 4);
    float4 vd = *reinterpret_cast<const float4*>(adf + kq * 4);
#pragma unroll
    for (int i = 0; i < 4; ++i) {
        int n = n0 + nq * 4 + i;
        if (n < N_NODES) {
            __half2* hp2 = reinterpret_cast<__half2*>(hp + (size_t)n * K_DIM + kq * 4);
            hp2[0] = __float22half2_rn(make_float2(acc[i][0], acc[i][1]));
            hp2[1] = __float22half2_rn(make_float2(acc[i][2], acc[i][3]));
        }
        float s = acc[i][0] * va.x + acc[i][1] * va.y + acc[i][2] * va.z + acc[i][3] * va.w;
        float d = acc[i][0] * vd.x + acc[i][1] * vd.y + acc[i][2] * vd.z + acc[i][3] * vd.w;
#pragma unroll
        for (int m = 1; m < 8; m <<= 1) {
            s += __shfl_xor(s, m, 8);
            d += __shfl_xor(d, m, 8);
        }
        if ((kq & 7) == 0 && n < N_NODES) {
            asn[(size_t)n * 4 + head] = s;
            adn[(size_t)n * 4 + head] = d;
        }
    }
}

// ---------------------------------------------------------------------------
// K3: scatter into dst-sorted 32 B fp16 edge records (R11: 64 B records were
//     154 MB of el traffic for ~36 B payload). Record (8 floats):
//     [src | h2(sa01) h2(sa23) | h2(ae1_01) h2(ae1_23) | h2(ae2_01) h2(ae2_23)
//      | pad].  Two contiguous float4 stores = one full 32 B sector.
// ---------------------------------------------------------------------------
__global__ void __launch_bounds__(256)
k3_scatter(const int* __restrict__ ei, const float4* __restrict__ aer1,
           const float4* __restrict__ aer2, const float* __restrict__ asn,
           int* __restrict__ cursor, float4* __restrict__ el) {
    int e = blockIdx.x * 256 + threadIdx.x;
    if (e >= N_EDGES) return;
    int dst = ei[N_EDGES + e];
    int src = ei[e];
    int pos = atomicAdd(cursor + dst, 1);   // atomic in flight alongside gathers
    float4 a1 = aer1[e];
    float4 a2 = aer2[e];
    float4 as4 = *reinterpret_cast<const float4*>(asn + (size_t)src * 4);
    __half2 sa01 = __float22half2_rn(make_float2(as4.x + a1.x, as4.y + a1.y));
    __half2 sa23 = __float22half2_rn(make_float2(as4.z + a1.z, as4.w + a1.w));
    __half2 e101 = __float22half2_rn(make_float2(a1.x, a1.y));
    __half2 e123 = __float22half2_rn(make_float2(a1.z, a1.w));
    __half2 e201 = __float22half2_rn(make_float2(a2.x, a2.y));
    __half2 e223 = __float22half2_rn(make_float2(a2.z, a2.w));
    float4* r = el + (size_t)pos * 2;
    r[0] = make_float4(__int_as_float(src), h2bits(sa01), h2bits(sa23), h2bits(e101));
    r[1] = make_float4(h2bits(e123), h2bits(e201), h2bits(e223), 0.f);
}

// ---------------------------------------------------------------------------
// K5: layer-1 gather aggregation. One 64-lane wave per node; lane owns 2
//     output columns. 1-deep chain, fp16 hp rows, 32 B records.
// ---------------------------------------------------------------------------
__global__ void __launch_bounds__(256)
k5_agg1(const int* __restrict__ starts, const float* __restrict__ el,
        const float* __restrict__ asn, const float* __restrict__ adn,
        const __half* __restrict__ hp, const float* __restrict__ b1,
        float* __restrict__ x2) {
    int t = threadIdx.x;
    int lane = t & 63;
    int node = blockIdx.x * 4 + (t >> 6);
    if (node >= N_NODES) return;
    int s = starts[node], e = starts[node + 1];
    int head = lane >> 4; // col pair = lane*2; head = (lane*2)>>5
    float adv = adn[(size_t)node * 4 + head];
    float accx = 0.f, accy = 0.f, dsum = 0.f, aesum = 0.f;
    int j = s;
    for (; j + 2 <= e; j += 2) {
        const float* r0 = el + (size_t)j * 8;
        const float* r1 = r0 + 8;
        float4 ra0 = *reinterpret_cast<const float4*>(r0);
        float  rb0 = r0[4];
        float4 ra1 = *reinterpret_cast<const float4*>(r1);
        float  rb1 = r1[4];
        int src0 = __float_as_int(ra0.x);
        int src1 = __float_as_int(ra1.x);
        float sa0 = pick_half(ra0.y, ra0.z, head);
        float sa1 = pick_half(ra1.y, ra1.z, head);
        float ar0 = pick_half(ra0.w, rb0, head);
        float ar1 = pick_half(ra1.w, rb1, head);
        float2 h0 = __half22float2(*reinterpret_cast<const __half2*>(hp + (size_t)src0 * K_DIM + lane * 2));
        float2 h1 = __half22float2(*reinterpret_cast<const __half2*>(hp + (size_t)src1 * K_DIM + lane * 2));
        float ex0 = __expf(lrelu(sa0 + adv));
        float ex1 = __expf(lrelu(sa1 + adv));
        accx = fmaf(ex0, h0.x, fmaf(ex1, h1.x, accx));
        accy = fmaf(ex0, h0.y, fmaf(ex1, h1.y, accy));
        dsum += ex0 + ex1;
        aesum += ar0 + ar1;
    }
    if (j < e) {
        const float* r0 = el + (size_t)j * 8;
        float4 ra0 = *reinterpret_cast<const float4*>(r0);
        float  rb0 = r0[4];
        int src = __float_as_int(ra0.x);
        float sa = pick_half(ra0.y, ra0.z, head);
        float ar = pick_half(ra0.w, rb0, head);
        float ex = __expf(lrelu(sa + adv));
        float2 hv = __half22float2(*reinterpret_cast<const __half2*>(hp + (size_t)src * K_DIM + lane * 2));
        accx = fmaf(ex, hv.x, accx);
        accy = fmaf(ex, hv.y, accy);
        dsum += ex;
        aesum += ar;
    }
    float deg = (float)(e - s);
    float al = aesum / fmaxf(deg, 1.f); // self-loop a_e = mean of incoming
    float exl = __expf(lrelu(asn[(size_t)node * 4 + head] + adv + al));
    float2 hv = __half22float2(*reinterpret_cast<const __half2*>(hp + (size_t)node * K_DIM + lane * 2));
    accx += exl * hv.x;
    accy += exl * hv.y;
    dsum += exl;
    float2 bb = *reinterpret_cast<const float2*>(b1 + lane * 2);
    float2 o;
    o.x = fmaxf(accx / dsum + bb.x, 0.f);
    o.y = fmaxf(accy / dsum + bb.y, 0.f);
    *reinterpret_cast<float2*>(x2 + (size_t)node * K_DIM + lane * 2) = o;
}

// ---------------------------------------------------------------------------
// K6: layer-2 node projection, register-tiled (F=128). Outputs packed
//     asg[n] = {a_s2[4], g[4]} + adn2. h2p never materialized.
// ---------------------------------------------------------------------------
__global__ void __launch_bounds__(256)
k6_proj2(const float* __restrict__ x2, const float* __restrict__ W2,
         const float* __restrict__ asf, const float* __restrict__ adf,
         const float* __restrict__ linw,
         float* __restrict__ asg, float* __restrict__ adn) {
    __shared__ float sxT[K_DIM * 33]; // [f][i], i in [0,32), pad 1
    int t = threadIdx.x;
    int n0 = blockIdx.x * 32;
    {
        int f = t & 127, i0 = t >> 7;
#pragma unroll
        for (int s = 0; s < 16; ++s) {
            int i = i0 + s * 2;
            int n = n0 + i;
            sxT[f * 33 + i] = (n < N_NODES) ? x2[(size_t)n * K_DIM + f] : 0.f;
        }
    }
    __syncthreads();
    int kq = t & 31, nq = t >> 5;
    float acc[4][4] = {};
    for (int f = 0; f < K_DIM; ++f) {
        float a0 = sxT[f * 33 + nq * 4 + 0];
        float a1 = sxT[f * 33 + nq * 4 + 1];
        float a2 = sxT[f * 33 + nq * 4 + 2];
        float a3 = sxT[f * 33 + nq * 4 + 3];
        float4 w4 = *reinterpret_cast<const float4*>(W2 + (size_t)f * K_DIM + kq * 4);
        acc[0][0] += a0 * w4.x; acc[0][1] += a0 * w4.y; acc[0][2] += a0 * w4.z; acc[0][3] += a0 * w4.w;
        acc[1][0] += a1 * w4.x; acc[1][1] += a1 * w4.y; acc[1][2] += a1 * w4.z; acc[1][3] += a1 * w4.w;
        acc[2][0] += a2 * w4.x; acc[2][1] += a2 * w4.y; acc[2][2] += a2 * w4.z; acc[2][3] += a2 * w4.w;
        acc[3][0] += a3 * w4.x; acc[3][1] += a3 * w4.y; acc[3][2] += a3 * w4.z; acc[3][3] += a3 * w4.w;
    }
    int head = kq >> 3;
    float4 va = *reinterpret_cast<const float4*>(asf + kq * 4);
    float4 vd = *reinterpret_cast<const float4*>(adf + kq * 4);
    float4 vg = *reinterpret_cast<const float4*>(linw + kq * 4);
#pragma unroll
    for (int i = 0; i < 4; ++i) {
        int n = n0 + nq * 4 + i;
        float s = acc[i][0] * va.x + acc[i][1] * va.y + acc[i][2] * va.z + acc[i][3] * va.w;
        float d = acc[i][0] * vd.x + acc[i][1] * vd.y + acc[i][2] * vd.z + acc[i][3] * vd.w;
        float g = acc[i][0] * vg.x + acc[i][1] * vg.y + acc[i][2] * vg.z + acc[i][3] * vg.w;
#pragma unroll
        for (int m = 1; m < 8; m <<= 1) {
            s += __shfl_xor(s, m, 8);
            d += __shfl_xor(d, m, 8);
            g += __shfl_xor(g, m, 8);
        }
        if ((kq & 7) == 0 && n < N_NODES) {
            asg[(size_t)n * 8 + head] = s;
            asg[(size_t)n * 8 + 4 + head] = g;
            adn[(size_t)n * 4 + head] = d;
        }
    }
}

// ---------------------------------------------------------------------------
// K7: layer-2 gather: 16-lane group per node, lanes stride the edge list.
//     Record reads: src (dword0) + float4 at +16 B (ae2 half2s in .y/.z).
// ---------------------------------------------------------------------------
__global__ void __launch_bounds__(256)
k7_l2(const int* __restrict__ starts, const float* __restrict__ el,
      const float* __restrict__ asg, const float* __restrict__ adn,
      const float* __restrict__ cbias, float* __restrict__ out) {
    int t = threadIdx.x;
    int g16 = t & 15;
    int node = blockIdx.x * 16 + (t >> 4);
    if (node >= N_NODES) return;
    int s = starts[node], e = starts[node + 1];
    float4 ad4 = *reinterpret_cast<const float4*>(adn + (size_t)node * 4);
    float4 dsum = make_float4(0, 0, 0, 0);
    float4 gsum = make_float4(0, 0, 0, 0);
    float4 aesum = make_float4(0, 0, 0, 0);
    for (int j = s + g16; j < e; j += 16) {
        const float* rb = el + (size_t)j * 8;
        int src = __float_as_int(rb[0]);
        float4 r2 = *reinterpret_cast<const float4*>(rb + 4); // f4..f7
        float f5 = r2.y, f6 = r2.z;
        __half2 h01 = *reinterpret_cast<__half2*>(&f5);
        __half2 h23 = *reinterpret_cast<__half2*>(&f6);
        float4 ae4 = make_float4(__low2float(h01), __high2float(h01),
                                 __low2float(h23), __high2float(h23));
        const float* ap = asg + (size_t)src * 8;
        float4 as4 = *reinterpret_cast<const float4*>(ap);
        float4 g4  = *reinterpret_cast<const float4*>(ap + 4);
        float e0 = __expf(lrelu(as4.x + ad4.x + ae4.x));
        float e1 = __expf(lrelu(as4.y + ad4.y + ae4.y));
        float e2 = __expf(lrelu(as4.z + ad4.z + ae4.z));
        float e3 = __expf(lrelu(as4.w + ad4.w + ae4.w));
        dsum.x += e0; dsum.y += e1; dsum.z += e2; dsum.w += e3;
        gsum.x += e0 * g4.x; gsum.y += e1 * g4.y; gsum.z += e2 * g4.z; gsum.w += e3 * g4.w;
        aesum.x += ae4.x; aesum.y += ae4.y; aesum.z += ae4.z; aesum.w += ae4.w;
    }
#pragma unroll
    for (int m = 1; m < 16; m <<= 1) {
        dsum.x += __shfl_xor(dsum.x, m, 16);  dsum.y += __shfl_xor(dsum.y, m, 16);
        dsum.z += __shfl_xor(dsum.z, m, 16);  dsum.w += __shfl_xor(dsum.w, m, 16);
        gsum.x += __shfl_xor(gsum.x, m, 16);  gsum.y += __shfl_xor(gsum.y, m, 16);
        gsum.z += __shfl_xor(gsum.z, m, 16);  gsum.w += __shfl_xor(gsum.w, m, 16);
        aesum.x += __shfl_xor(aesum.x, m, 16); aesum.y += __shfl_xor(aesum.y, m, 16);
        aesum.z += __shfl_xor(aesum.z, m, 16); aesum.w += __shfl_xor(aesum.w, m, 16);
    }
    if (g16 == 0) {
        float deg = fmaxf((float)(e - s), 1.f);
        const float* ap = asg + (size_t)node * 8;
        float4 mas = *reinterpret_cast<const float4*>(ap);
        float4 mg  = *reinterpret_cast<const float4*>(ap + 4);
        float r = cbias[0];
        float e0;
        e0 = __expf(lrelu(mas.x + ad4.x + aesum.x / deg)); r += (gsum.x + e0 * mg.x) / (dsum.x + e0);
        e0 = __expf(lrelu(mas.y + ad4.y + aesum.y / deg)); r += (gsum.y + e0 * mg.y) / (dsum.y + e0);
        e0 = __expf(lrelu(mas.z + ad4.z + aesum.z / deg)); r += (gsum.z + e0 * mg.z) / (dsum.z + e0);
        e0 = __expf(lrelu(mas.w + ad4.w + aesum.w / deg)); r += (gsum.w + e0 * mg.w) / (dsum.w + e0);
        out[node] = r;
    }
}

// ---------------------------------------------------------------------------
extern "C" void kernel_launch(void* const* d_in, const int* in_sizes, int n_in,
                              void* d_out, int out_size, void* d_ws, size_t ws_size,
                              hipStream_t stream) {
    (void)in_sizes; (void)n_in; (void)out_size;
    const float* x    = (const float*)d_in[0];
    const float* ea   = (const float*)d_in[1];
    const float* W1   = (const float*)d_in[2];
    const float* as1  = (const float*)d_in[3];
    const float* ad1  = (const float*)d_in[4];
    const float* We1  = (const float*)d_in[5];
    const float* ae1  = (const float*)d_in[6];
    const float* b1   = (const float*)d_in[7];
    const float* W2   = (const float*)d_in[8];
    const float* as2  = (const float*)d_in[9];
    const float* ad2  = (const float*)d_in[10];
    const float* We2  = (const float*)d_in[11];
    const float* ae2  = (const float*)d_in[12];
    const float* b2   = (const float*)d_in[13];
    const float* linw = (const float*)d_in[14];
    const float* linb = (const float*)d_in[15];
    const int*   ei   = (const int*)d_in[16];
    float* out = (float*)d_out;
    float* ws  = (float*)d_ws;

    const int SCAN_BLK = (N_NODES + 1023) / 1024; // 49

    size_t off = 0;
    __half* h1p  = (__half*)(ws + off); off += (size_t)N_NODES * K_DIM / 2; // fp16
    float* x2    = ws + off; off += (size_t)N_NODES * K_DIM;
    float* asn1  = ws + off; off += (size_t)N_NODES * 4;
    float* adn1  = ws + off; off += (size_t)N_NODES * 4;
    float* asg2  = ws + off; off += (size_t)N_NODES * 8;
    float* adn2  = ws + off; off += (size_t)N_NODES * 4;
    float* vbuf  = ws + off; off += 512;
    float* cbias = ws + off; off += 64;
    int* starts  = (int*)(ws + off); off += (size_t)N_NODES + 8;
    int* cursor  = (int*)(ws + off); off += (size_t)N_NODES;
    int* bsum    = (int*)(ws + off); off += 64;
    // pad to 8-float (32 B) boundary for el records
    off = (off + 7) & ~(size_t)7;
    float* el    = ws + off; off += (size_t)N_EDGES * 8; // 32 B fp16 records
    float* aer1  = ws + off; off += (size_t)N_EDGES * 4;
    float* aer2  = ws + off; off += (size_t)N_EDGES * 4;
    int* cnt     = (int*)(ws + off); off += (size_t)N_NODES;

    if (ws_size < off * sizeof(float)) return; // workspace too small: fail visibly

    hipMemsetAsync(cnt, 0, N_NODES * sizeof(int), stream);

    kc_fold<<<N_EDGES / 256 + 1, 256, 0, stream>>>(ei, cnt, We1, ae1, We2, ae2,
                                                   b2, linw, linb, vbuf, cbias);
    k2a_bsum<<<SCAN_BLK, 1024, 0, stream>>>(cnt, bsum);
    k2b_scan<<<SCAN_BLK, 1024, 0, stream>>>(cnt, bsum, starts, cursor, SCAN_BLK);
    k1_edge<<<N_EDGES / 256, 256, 0, stream>>>(ea, vbuf, aer1, aer2);
    k4_proj1<<<(N_NODES + 31) / 32, 256, 0, stream>>>(x, W1, as1, ad1, h1p, asn1, adn1);
    k3_scatter<<<N_EDGES / 256, 256, 0, stream>>>(ei, (const float4*)aer1, (const float4*)aer2,
                                                  asn1, cursor, (float4*)el);
    k5_agg1<<<(N_NODES + 3) / 4, 256, 0, stream>>>(starts, el, asn1, adn1, h1p, b1, x2);
    k6_proj2<<<(N_NODES + 31) / 32, 256, 0, stream>>>(x2, W2, as2, ad2, linw, asg2, adn2);
    k7_l2<<<(N_NODES + 15) / 16, 256, 0, stream>>>(starts, el, asg2, adn2, cbias, out);
}

// Round 13
// 257.786 us; speedup vs baseline: 1.5102x; 1.0817x over previous
//
#include <hip/hip_runtime.h>
#include <hip/hip_fp16.h>

#define N_NODES 50000
#define N_EDGES 800000
#define F_IN    64
#define HEADS   4
#define CH      32
#define K_DIM   128
#define NEG     0.2f

__device__ __forceinline__ float lrelu(float x) { return x > 0.f ? x : NEG * x; }

__device__ __forceinline__ float h2bits(__half2 h) {
    return *reinterpret_cast<float*>(&h);
}
// pick head-th fp16 from two packed half2 words (lo2 = heads 0,1; hi2 = heads 2,3)
__device__ __forceinline__ float pick_half(float lo2, float hi2, int head) {
    float f = (head < 2) ? lo2 : hi2;
    __half2 h = *reinterpret_cast<__half2*>(&f);
    return (head & 1) ? __high2float(h) : __low2float(h);
}

// ---------------------------------------------------------------------------
// KC: degree count + per-edge rank (atomic return value) from ei. LAST block
//     performs the weight folds instead:
//       v[8][64]   : We*ae edge-projection folds (layers 1,2)
//       u[12][128] : W2-based node folds for layer 2 (q = h*3+type,
//                    type 0=a_s2, 1=a_d2, 2=g)  [R12: k6's GEMM collapses to
//                    12 dots since h2p is only consumed via per-head dots]
//       cbias      : dot(b2,linw)+linb
// ---------------------------------------------------------------------------
__global__ void __launch_bounds__(256)
kc_fold(const int* __restrict__ ei, int* __restrict__ cnt, int* __restrict__ rank,
        const float* __restrict__ We1, const float* __restrict__ ae1,
        const float* __restrict__ We2, const float* __restrict__ ae2,
        const float* __restrict__ as2, const float* __restrict__ ad2,
        const float* __restrict__ W2,
        const float* __restrict__ b2,  const float* __restrict__ linw,
        const float* __restrict__ linb,
        float* __restrict__ v, float* __restrict__ u, float* __restrict__ cbias) {
    if (blockIdx.x >= N_EDGES / 256) { // fold block
        int t = threadIdx.x;
        for (int idx = t; idx < 512; idx += 256) {
            int o = idx >> 6, f = idx & 63;
            const float* We = (o < 4) ? We1 : We2;
            const float* ae = (o < 4) ? ae1 : ae2;
            int h = o & 3;
            float s = 0.f;
            for (int c = 0; c < CH; ++c)
                s += We[f * K_DIM + h * CH + c] * ae[h * CH + c];
            v[o * 64 + f] = s;
        }
        for (int idx = t; idx < 12 * K_DIM; idx += 256) {
            int q = idx >> 7, f = idx & 127;
            int h = q / 3, type = q % 3;
            const float* w = (type == 0) ? as2 : (type == 1) ? ad2 : linw;
            float s = 0.f;
            for (int c = 0; c < CH; ++c)
                s += W2[(size_t)f * K_DIM + h * CH + c] * w[h * CH + c];
            u[idx] = s;
        }
        if (t == 0) {
            float s = 0.f;
            for (int k = 0; k < K_DIM; ++k) s += b2[k] * linw[k];
            *cbias = s + linb[0];
        }
        return;
    }
    int e = blockIdx.x * 256 + threadIdx.x;
    rank[e] = atomicAdd(cnt + ei[N_EDGES + e], 1);
}

// ---------------------------------------------------------------------------
// K2a/K2b: hierarchical exclusive scan (starts only; cursor eliminated --
//     k3 uses starts[dst]+rank[e]).
// ---------------------------------------------------------------------------
__global__ void __launch_bounds__(1024)
k2a_bsum(const int* __restrict__ cnt, int* __restrict__ bsum) {
    __shared__ int ws[16];
    int t = threadIdx.x, lane = t & 63, wid = t >> 6;
    int i = blockIdx.x * 1024 + t;
    int v = (i < N_NODES) ? cnt[i] : 0;
#pragma unroll
    for (int m = 1; m < 64; m <<= 1) v += __shfl_xor(v, m, 64);
    if (lane == 0) ws[wid] = v;
    __syncthreads();
    if (t == 0) {
        int s = 0;
#pragma unroll
        for (int k = 0; k < 16; ++k) s += ws[k];
        bsum[blockIdx.x] = s;
    }
}

__global__ void __launch_bounds__(1024)
k2b_scan(const int* __restrict__ cnt, const int* __restrict__ bsum,
         int* __restrict__ starts, int nblk) {
    __shared__ int wsum[16];
    __shared__ int s_off;
    int t = threadIdx.x, lane = t & 63, wid = t >> 6;
    int bid = blockIdx.x;
    if (t == 0) {
        int o = 0;
        for (int b = 0; b < bid; ++b) o += bsum[b];
        s_off = o;
    }
    int i = bid * 1024 + t;
    int v = (i < N_NODES) ? cnt[i] : 0;
    int sc = v; // inclusive wave scan
#pragma unroll
    for (int s = 1; s < 64; s <<= 1) {
        int u = __shfl_up(sc, s, 64);
        if (lane >= s) sc += u;
    }
    if (lane == 63) wsum[wid] = sc;
    __syncthreads();
    if (wid == 0 && lane < 16) {
        int ws = wsum[lane];
#pragma unroll
        for (int s = 1; s < 16; s <<= 1) {
            int u = __shfl_up(ws, s, 64);
            if (lane >= s) ws += u;
        }
        wsum[lane] = ws;
    }
    __syncthreads();
    int off = s_off + ((wid == 0) ? 0 : wsum[wid - 1]);
    int excl = off + sc - v;
    if (i < N_NODES) starts[i] = excl;
    if (bid == nblk - 1 && t == 1023) starts[N_NODES] = s_off + wsum[15];
}

// ---------------------------------------------------------------------------
// K1: per-edge a_e, PURE STREAM. Coalesced LDS-tile staging, v-row in 16
//     float4 regs, writes aer1/aer2 in EDGE ORDER. No atomics, no scatter.
// ---------------------------------------------------------------------------
__global__ void __launch_bounds__(256)
k1_edge(const float* __restrict__ ea, const float* __restrict__ v,
        float* __restrict__ aer1, float* __restrict__ aer2) {
    __shared__ float sx[2][32 * 68];
    int t = threadIdx.x;
    int o  = t & 7;   // output index (0..3: layer1 heads, 4..7: layer2 heads)
    int le = t >> 3;  // local edge within tile (0..31)
    float4 vr[16];
    {
        const float4* vrow = reinterpret_cast<const float4*>(v + o * 64);
#pragma unroll
        for (int c = 0; c < 16; ++c) vr[c] = vrow[c];
    }
    const float4* ea4 = reinterpret_cast<const float4*>(ea);
    int base = blockIdx.x * 256; // 8 tiles * 32 edges
    {
        size_t gb = (size_t)base * 16;
        float4 a = ea4[gb + t];
        float4 b = ea4[gb + t + 256];
        int g0 = t, g1 = t + 256;
        *reinterpret_cast<float4*>(&sx[0][(g0 >> 4) * 68 + (g0 & 15) * 4]) = a;
        *reinterpret_cast<float4*>(&sx[0][(g1 >> 4) * 68 + (g1 & 15) * 4]) = b;
    }
    __syncthreads();
    for (int tile = 0; tile < 8; ++tile) {
        float4 a, b;
        if (tile < 7) { // prefetch next tile (coalesced)
            size_t gb = (size_t)(base + (tile + 1) * 32) * 16;
            a = ea4[gb + t];
            b = ea4[gb + t + 256];
        }
        const float* row = &sx[tile & 1][le * 68];
        float4 ac = make_float4(0.f, 0.f, 0.f, 0.f);
#pragma unroll
        for (int c = 0; c < 16; ++c) {
            float4 x4 = *reinterpret_cast<const float4*>(row + c * 4);
            ac.x = fmaf(x4.x, vr[c].x, ac.x);
            ac.y = fmaf(x4.y, vr[c].y, ac.y);
            ac.z = fmaf(x4.z, vr[c].z, ac.z);
            ac.w = fmaf(x4.w, vr[c].w, ac.w);
        }
        float acc = (ac.x + ac.y) + (ac.z + ac.w);
        int eid = base + tile * 32 + le;
        float* ob = (o < 4) ? aer1 : aer2;
        ob[(size_t)eid * 4 + (o & 3)] = acc;   // edge-order: coalesced
        if (tile < 7) { // write next tile into other buffer
            int g0 = t, g1 = t + 256;
            int nb = (tile + 1) & 1;
            *reinterpret_cast<float4*>(&sx[nb][(g0 >> 4) * 68 + (g0 & 15) * 4]) = a;
            *reinterpret_cast<float4*>(&sx[nb][(g1 >> 4) * 68 + (g1 & 15) * 4]) = b;
        }
        __syncthreads();
    }
}

// ---------------------------------------------------------------------------
// K4: layer-1 node projection, register-tiled 4 nodes x 4 cols per thread.
//     hp written as FP16. Runs BEFORE k3 so asn1 can be embedded.
// ---------------------------------------------------------------------------
__global__ void __launch_bounds__(256)
k4_proj1(const float* __restrict__ x, const float* __restrict__ W,
         const float* __restrict__ asf, const float* __restrict__ adf,
         __half* __restrict__ hp, float* __restrict__ asn, float* __restrict__ adn) {
    __shared__ float sxT[F_IN * 33]; // [f][i], i in [0,32), pad 1
    int t = threadIdx.x;
    int n0 = blockIdx.x * 32;
    {
        int f = t & 63, i0 = t >> 6;
#pragma unroll
        for (int s = 0; s < 8; ++s) {
            int i = i0 + s * 4;
            int n = n0 + i;
            sxT[f * 33 + i] = (n < N_NODES) ? x[(size_t)n * F_IN + f] : 0.f;
        }
    }
    __syncthreads();
    int kq = t & 31, nq = t >> 5;
    float acc[4][4] = {};
    for (int f = 0; f < F_IN; ++f) {
        float a0 = sxT[f * 33 + nq * 4 + 0];
        float a1 = sxT[f * 33 + nq * 4 + 1];
        float a2 = sxT[f * 33 + nq * 4 + 2];
        float a3 = sxT[f * 33 + nq * 4 + 3];
        float4 w4 = *reinterpret_cast<const float4*>(W + (size_t)f * K_DIM + kq * 4);
        acc[0][0] += a0 * w4.x; acc[0][1] += a0 * w4.y; acc[0][2] += a0 * w4.z; acc[0][3] += a0 * w4.w;
        acc[1][0] += a1 * w4.x; acc[1][1] += a1 * w4.y; acc[1][2] += a1 * w4.z; acc[1][3] += a1 * w4.w;
        acc[2][0] += a2 * w4.x; acc[2][1] += a2 * w4.y; acc[2][2] += a2 * w4.z; acc[2][3] += a2 * w4.w;
        acc[3][0] += a3 * w4.x; acc[3][1] += a3 * w4.y; acc[3][2] += a3 * w4.z; acc[3][3] += a3 * w4.w;
    }
    int head = kq >> 3;
    float4 va = *reinterpret_cast<const float4*>(asf + kq * 4);
    float4 vd = *reinterpret_cast<const float4*>(adf + kq * 4);
#pragma unroll
    for (int i = 0; i < 4; ++i) {
        int n = n0 + nq * 4 + i;
        if (n < N_NODES) {
            __half2* hp2 = reinterpret_cast<__half2*>(hp + (size_t)n * K_DIM + kq * 4);
            hp2[0] = __float22half2_rn(make_float2(acc[i][0], acc[i][1]));
            hp2[1] = __float22half2_rn(make_float2(acc[i][2], acc[i][3]));
        }
        float s = acc[i][0] * va.x + acc[i][1] * va.y + acc[i][2] * va.z + acc[i][3] * va.w;
        float d = acc[i][0] * vd.x + acc[i][1] * vd.y + acc[i][2] * vd.z + acc[i][3] * vd.w;
#pragma unroll
        for (int m = 1; m < 8; m <<= 1) {
            s += __shfl_xor(s, m, 8);
            d += __shfl_xor(d, m, 8);
        }
        if ((kq & 7) == 0 && n < N_NODES) {
            asn[(size_t)n * 4 + head] = s;
            adn[(size_t)n * 4 + head] = d;
        }
    }
}

// ---------------------------------------------------------------------------
// K3: scatter into dst-sorted 32 B fp16 edge records. NO ATOMIC (R12:
//     pos = starts[dst] + rank[e], rank captured in kc). Record (8 floats):
//     [src | h2(sa01) h2(sa23) | h2(ae1_01) h2(ae1_23) | h2(ae2_01)
//      h2(ae2_23) | pad]. Two float4 stores = one full 32 B sector.
// ---------------------------------------------------------------------------
__global__ void __launch_bounds__(256)
k3_scatter(const int* __restrict__ ei, const int* __restrict__ rank,
           const float4* __restrict__ aer1, const float4* __restrict__ aer2,
           const float* __restrict__ asn, const int* __restrict__ starts,
           float4* __restrict__ el) {
    int e = blockIdx.x * 256 + threadIdx.x;
    if (e >= N_EDGES) return;
    int dst = ei[N_EDGES + e];
    int src = ei[e];
    int pos = starts[dst] + rank[e];
    float4 a1 = aer1[e];
    float4 a2 = aer2[e];
    float4 as4 = *reinterpret_cast<const float4*>(asn + (size_t)src * 4);
    __half2 sa01 = __float22half2_rn(make_float2(as4.x + a1.x, as4.y + a1.y));
    __half2 sa23 = __float22half2_rn(make_float2(as4.z + a1.z, as4.w + a1.w));
    __half2 e101 = __float22half2_rn(make_float2(a1.x, a1.y));
    __half2 e123 = __float22half2_rn(make_float2(a1.z, a1.w));
    __half2 e201 = __float22half2_rn(make_float2(a2.x, a2.y));
    __half2 e223 = __float22half2_rn(make_float2(a2.z, a2.w));
    float4* r = el + (size_t)pos * 2;
    r[0] = make_float4(__int_as_float(src), h2bits(sa01), h2bits(sa23), h2bits(e101));
    r[1] = make_float4(h2bits(e123), h2bits(e201), h2bits(e223), 0.f);
}

// ---------------------------------------------------------------------------
// K5: FUSED layer-1 aggregation + layer-2 reduced projection (R12: k6's
//     128x128 GEMM collapses to 12 dots/node with u = W2-folds; x2 never
//     leaves LDS). One 64-lane wave per node (4 nodes/block); after the
//     gather loop, x2 rows land in LDS, one barrier, 16-lane groups compute
//     the 48 dots -> asg2/adn2.
// ---------------------------------------------------------------------------
__global__ void __launch_bounds__(256)
k5_fused(const int* __restrict__ starts, const float* __restrict__ el,
         const float* __restrict__ asn, const float* __restrict__ adn,
         const __half* __restrict__ hp, const float* __restrict__ b1,
         const float* __restrict__ u,
         float* __restrict__ asg, float* __restrict__ adn2) {
    __shared__ float su[12 * K_DIM]; // 6 KB
    __shared__ float sx2[4 * K_DIM]; // 2 KB
    int t = threadIdx.x;
    for (int i = t; i < 12 * K_DIM; i += 256) su[i] = u[i];
    int lane = t & 63;
    int wv = t >> 6;
    int node = blockIdx.x * 4 + wv; // N_NODES % 4 == 0: always valid
    int s = starts[node], e = starts[node + 1];
    int head = lane >> 4; // col pair = lane*2; head = (lane*2)>>5
    float adv = adn[(size_t)node * 4 + head];
    float accx = 0.f, accy = 0.f, dsum = 0.f, aesum = 0.f;
    int j = s;
    for (; j + 2 <= e; j += 2) {
        const float* r0 = el + (size_t)j * 8;
        const float* r1 = r0 + 8;
        float4 ra0 = *reinterpret_cast<const float4*>(r0);
        float  rb0 = r0[4];
        float4 ra1 = *reinterpret_cast<const float4*>(r1);
        float  rb1 = r1[4];
        int src0 = __float_as_int(ra0.x);
        int src1 = __float_as_int(ra1.x);
        float sa0 = pick_half(ra0.y, ra0.z, head);
        float sa1 = pick_half(ra1.y, ra1.z, head);
        float ar0 = pick_half(ra0.w, rb0, head);
        float ar1 = pick_half(ra1.w, rb1, head);
        float2 h0 = __half22float2(*reinterpret_cast<const __half2*>(hp + (size_t)src0 * K_DIM + lane * 2));
        float2 h1 = __half22float2(*reinterpret_cast<const __half2*>(hp + (size_t)src1 * K_DIM + lane * 2));
        float ex0 = __expf(lrelu(sa0 + adv));
        float ex1 = __expf(lrelu(sa1 + adv));
        accx = fmaf(ex0, h0.x, fmaf(ex1, h1.x, accx));
        accy = fmaf(ex0, h0.y, fmaf(ex1, h1.y, accy));
        dsum += ex0 + ex1;
        aesum += ar0 + ar1;
    }
    if (j < e) {
        const float* r0 = el + (size_t)j * 8;
        float4 ra0 = *reinterpret_cast<const float4*>(r0);
        float  rb0 = r0[4];
        int src = __float_as_int(ra0.x);
        float sa = pick_half(ra0.y, ra0.z, head);
        float ar = pick_half(ra0.w, rb0, head);
        float ex = __expf(lrelu(sa + adv));
        float2 hv = __half22float2(*reinterpret_cast<const __half2*>(hp + (size_t)src * K_DIM + lane * 2));
        accx = fmaf(ex, hv.x, accx);
        accy = fmaf(ex, hv.y, accy);
        dsum += ex;
        aesum += ar;
    }
    float deg = (float)(e - s);
    float al = aesum / fmaxf(deg, 1.f); // self-loop a_e = mean of incoming
    float exl = __expf(lrelu(asn[(size_t)node * 4 + head] + adv + al));
    float2 hv = __half22float2(*reinterpret_cast<const __half2*>(hp + (size_t)node * K_DIM + lane * 2));
    accx += exl * hv.x;
    accy += exl * hv.y;
    dsum += exl;
    float2 bb = *reinterpret_cast<const float2*>(b1 + lane * 2);
    sx2[wv * K_DIM + lane * 2 + 0] = fmaxf(accx / dsum + bb.x, 0.f);
    sx2[wv * K_DIM + lane * 2 + 1] = fmaxf(accy / dsum + bb.y, 0.f);
    __syncthreads();
    // ---- layer-2 reduced projection: 48 outputs (4 nodes x 12 folds) ----
    int g = t >> 4;      // 16 groups of 16 lanes
    int l16 = t & 15;
#pragma unroll
    for (int r = 0; r < 3; ++r) {
        int oid = g * 3 + r;      // 0..47
        int nl = oid / 12;
        int q  = oid % 12;        // h*3 + type
        int h = q / 3, type = q % 3;
        const float* xr = &sx2[nl * K_DIM];
        const float* ur = &su[q * K_DIM];
        float sv = 0.f;
#pragma unroll
        for (int i = 0; i < 8; ++i)
            sv = fmaf(xr[l16 + 16 * i], ur[l16 + 16 * i], sv);
#pragma unroll
        for (int m = 1; m < 16; m <<= 1) sv += __shfl_xor(sv, m, 16);
        if (l16 == 0) {
            int n = blockIdx.x * 4 + nl;
            if (type == 0)      asg[(size_t)n * 8 + h] = sv;
            else if (type == 1) adn2[(size_t)n * 4 + h] = sv;
            else                asg[(size_t)n * 8 + 4 + h] = sv;
        }
    }
}

// ---------------------------------------------------------------------------
// K7: layer-2 gather: 16-lane group per node, lanes stride the edge list.
//     Record reads: src (dword0) + float4 at +16 B (ae2 half2s in .y/.z).
// ---------------------------------------------------------------------------
__global__ void __launch_bounds__(256)
k7_l2(const int* __restrict__ starts, const float* __restrict__ el,
      const float* __restrict__ asg, const float* __restrict__ adn,
      const float* __restrict__ cbias, float* __restrict__ out) {
    int t = threadIdx.x;
    int g16 = t & 15;
    int node = blockIdx.x * 16 + (t >> 4);
    if (node >= N_NODES) return;
    int s = starts[node], e = starts[node + 1];
    float4 ad4 = *reinterpret_cast<const float4*>(adn + (size_t)node * 4);
    float4 dsum = make_float4(0, 0, 0, 0);
    float4 gsum = make_float4(0, 0, 0, 0);
    float4 aesum = make_float4(0, 0, 0, 0);
    for (int j = s + g16; j < e; j += 16) {
        const float* rb = el + (size_t)j * 8;
        int src = __float_as_int(rb[0]);
        float4 r2 = *reinterpret_cast<const float4*>(rb + 4); // f4..f7
        float f5 = r2.y, f6 = r2.z;
        __half2 h01 = *reinterpret_cast<__half2*>(&f5);
        __half2 h23 = *reinterpret_cast<__half2*>(&f6);
        float4 ae4 = make_float4(__low2float(h01), __high2float(h01),
                                 __low2float(h23), __high2float(h23));
        const float* ap = asg + (size_t)src * 8;
        float4 as4 = *reinterpret_cast<const float4*>(ap);
        float4 g4  = *reinterpret_cast<const float4*>(ap + 4);
        float e0 = __expf(lrelu(as4.x + ad4.x + ae4.x));
        float e1 = __expf(lrelu(as4.y + ad4.y + ae4.y));
        float e2 = __expf(lrelu(as4.z + ad4.z + ae4.z));
        float e3 = __expf(lrelu(as4.w + ad4.w + ae4.w));
        dsum.x += e0; dsum.y += e1; dsum.z += e2; dsum.w += e3;
        gsum.x += e0 * g4.x; gsum.y += e1 * g4.y; gsum.z += e2 * g4.z; gsum.w += e3 * g4.w;
        aesum.x += ae4.x; aesum.y += ae4.y; aesum.z += ae4.z; aesum.w += ae4.w;
    }
#pragma unroll
    for (int m = 1; m < 16; m <<= 1) {
        dsum.x += __shfl_xor(dsum.x, m, 16);  dsum.y += __shfl_xor(dsum.y, m, 16);
        dsum.z += __shfl_xor(dsum.z, m, 16);  dsum.w += __shfl_xor(dsum.w, m, 16);
        gsum.x += __shfl_xor(gsum.x, m, 16);  gsum.y += __shfl_xor(gsum.y, m, 16);
        gsum.z += __shfl_xor(gsum.z, m, 16);  gsum.w += __shfl_xor(gsum.w, m, 16);
        aesum.x += __shfl_xor(aesum.x, m, 16); aesum.y += __shfl_xor(aesum.y, m, 16);
        aesum.z += __shfl_xor(aesum.z, m, 16); aesum.w += __shfl_xor(aesum.w, m, 16);
    }
    if (g16 == 0) {
        float deg = fmaxf((float)(e - s), 1.f);
        const float* ap = asg + (size_t)node * 8;
        float4 mas = *reinterpret_cast<const float4*>(ap);
        float4 mg  = *reinterpret_cast<const float4*>(ap + 4);
        float r = cbias[0];
        float e0;
        e0 = __expf(lrelu(mas.x + ad4.x + aesum.x / deg)); r += (gsum.x + e0 * mg.x) / (dsum.x + e0);
        e0 = __expf(lrelu(mas.y + ad4.y + aesum.y / deg)); r += (gsum.y + e0 * mg.y) / (dsum.y + e0);
        e0 = __expf(lrelu(mas.z + ad4.z + aesum.z / deg)); r += (gsum.z + e0 * mg.z) / (dsum.z + e0);
        e0 = __expf(lrelu(mas.w + ad4.w + aesum.w / deg)); r += (gsum.w + e0 * mg.w) / (dsum.w + e0);
        out[node] = r;
    }
}

// ---------------------------------------------------------------------------
extern "C" void kernel_launch(void* const* d_in, const int* in_sizes, int n_in,
                              void* d_out, int out_size, void* d_ws, size_t ws_size,
                              hipStream_t stream) {
    (void)in_sizes; (void)n_in; (void)out_size;
    const float* x    = (const float*)d_in[0];
    const float* ea   = (const float*)d_in[1];
    const float* W1   = (const float*)d_in[2];
    const float* as1  = (const float*)d_in[3];
    const float* ad1  = (const float*)d_in[4];
    const float* We1  = (const float*)d_in[5];
    const float* ae1  = (const float*)d_in[6];
    const float* b1   = (const float*)d_in[7];
    const float* W2   = (const float*)d_in[8];
    const float* as2  = (const float*)d_in[9];
    const float* ad2  = (const float*)d_in[10];
    const float* We2  = (const float*)d_in[11];
    const float* ae2  = (const float*)d_in[12];
    const float* b2   = (const float*)d_in[13];
    const float* linw = (const float*)d_in[14];
    const float* linb = (const float*)d_in[15];
    const int*   ei   = (const int*)d_in[16];
    float* out = (float*)d_out;
    float* ws  = (float*)d_ws;

    const int SCAN_BLK = (N_NODES + 1023) / 1024; // 49

    size_t off = 0;
    __half* h1p  = (__half*)(ws + off); off += (size_t)N_NODES * K_DIM / 2; // fp16
    float* asn1  = ws + off; off += (size_t)N_NODES * 4;
    float* adn1  = ws + off; off += (size_t)N_NODES * 4;
    float* asg2  = ws + off; off += (size_t)N_NODES * 8;
    float* adn2  = ws + off; off += (size_t)N_NODES * 4;
    float* vbuf  = ws + off; off += 512;
    float* ubuf  = ws + off; off += 12 * K_DIM;
    float* cbias = ws + off; off += 64;
    int* starts  = (int*)(ws + off); off += (size_t)N_NODES + 8;
    int* bsum    = (int*)(ws + off); off += 64;
    int* rank    = (int*)(ws + off); off += (size_t)N_EDGES;
    // pad to 8-float (32 B) boundary for el records
    off = (off + 7) & ~(size_t)7;
    float* el    = ws + off; off += (size_t)N_EDGES * 8; // 32 B fp16 records
    float* aer1  = ws + off; off += (size_t)N_EDGES * 4;
    float* aer2  = ws + off; off += (size_t)N_EDGES * 4;
    int* cnt     = (int*)(ws + off); off += (size_t)N_NODES;

    if (ws_size < off * sizeof(float)) return; // workspace too small: fail visibly

    hipMemsetAsync(cnt, 0, N_NODES * sizeof(int), stream);

    kc_fold<<<N_EDGES / 256 + 1, 256, 0, stream>>>(ei, cnt, rank, We1, ae1, We2, ae2,
                                                   as2, ad2, W2, b2, linw, linb,
                                                   vbuf, ubuf, cbias);
    k2a_bsum<<<SCAN_BLK, 1024, 0, stream>>>(cnt, bsum);
    k2b_scan<<<SCAN_BLK, 1024, 0, stream>>>(cnt, bsum, starts, SCAN_BLK);
    k1_edge<<<N_EDGES / 256, 256, 0, stream>>>(ea, vbuf, aer1, aer2);
    k4_proj1<<<(N_NODES + 31) / 32, 256, 0, stream>>>(x, W1, as1, ad1, h1p, asn1, adn1);
    k3_scatter<<<N_EDGES / 256, 256, 0, stream>>>(ei, rank, (const float4*)aer1,
                                                  (const float4*)aer2, asn1, starts,
                                                  (float4*)el);
    k5_fused<<<N_NODES / 4, 256, 0, stream>>>(starts, el, asn1, adn1, h1p, b1,
                                              ubuf, asg2, adn2);
    k7_l2<<<(N_NODES + 15) / 16, 256, 0, stream>>>(starts, el, asg2, adn2, cbias, out);
}

// Round 14
// 240.058 us; speedup vs baseline: 1.6217x; 1.0738x over previous
//
#include <hip/hip_runtime.h>
#include <hip/hip_fp16.h>

#define N_NODES 50000
#define N_EDGES 800000
#define F_IN    64
#define HEADS   4
#define CH      32
#define K_DIM   128
#define NEG     0.2f

__device__ __forceinline__ float lrelu(float x) { return x > 0.f ? x : NEG * x; }

__device__ __forceinline__ float h2bits(__half2 h) {
    return *reinterpret_cast<float*>(&h);
}
// pick head-th fp16 from two packed half2 words (lo2 = heads 0,1; hi2 = heads 2,3)
__device__ __forceinline__ float pick_half(float lo2, float hi2, int head) {
    float f = (head < 2) ? lo2 : hi2;
    __half2 h = *reinterpret_cast<__half2*>(&f);
    return (head & 1) ? __high2float(h) : __low2float(h);
}

// ---------------------------------------------------------------------------
// KC: degree count + per-edge rank (atomic return value) from ei. LAST block
//     performs the weight folds instead: v[8][64] (We*ae), u[12][128]
//     (W2 folds: q=h*3+type, type 0=a_s2 1=a_d2 2=g), cbias.
// ---------------------------------------------------------------------------
__global__ void __launch_bounds__(256)
kc_fold(const int* __restrict__ ei, int* __restrict__ cnt, int* __restrict__ rank,
        const float* __restrict__ We1, const float* __restrict__ ae1,
        const float* __restrict__ We2, const float* __restrict__ ae2,
        const float* __restrict__ as2, const float* __restrict__ ad2,
        const float* __restrict__ W2,
        const float* __restrict__ b2,  const float* __restrict__ linw,
        const float* __restrict__ linb,
        float* __restrict__ v, float* __restrict__ u, float* __restrict__ cbias) {
    if (blockIdx.x >= N_EDGES / 256) { // fold block
        int t = threadIdx.x;
        for (int idx = t; idx < 512; idx += 256) {
            int o = idx >> 6, f = idx & 63;
            const float* We = (o < 4) ? We1 : We2;
            const float* ae = (o < 4) ? ae1 : ae2;
            int h = o & 3;
            float s = 0.f;
            for (int c = 0; c < CH; ++c)
                s += We[f * K_DIM + h * CH + c] * ae[h * CH + c];
            v[o * 64 + f] = s;
        }
        for (int idx = t; idx < 12 * K_DIM; idx += 256) {
            int q = idx >> 7, f = idx & 127;
            int h = q / 3, type = q % 3;
            const float* w = (type == 0) ? as2 : (type == 1) ? ad2 : linw;
            float s = 0.f;
            for (int c = 0; c < CH; ++c)
                s += W2[(size_t)f * K_DIM + h * CH + c] * w[h * CH + c];
            u[idx] = s;
        }
        if (t == 0) {
            float s = 0.f;
            for (int k = 0; k < K_DIM; ++k) s += b2[k] * linw[k];
            *cbias = s + linb[0];
        }
        return;
    }
    int e = blockIdx.x * 256 + threadIdx.x;
    rank[e] = atomicAdd(cnt + ei[N_EDGES + e], 1);
}

// ---------------------------------------------------------------------------
// K2a/K2b: hierarchical exclusive scan (starts only).
// ---------------------------------------------------------------------------
__global__ void __launch_bounds__(1024)
k2a_bsum(const int* __restrict__ cnt, int* __restrict__ bsum) {
    __shared__ int ws[16];
    int t = threadIdx.x, lane = t & 63, wid = t >> 6;
    int i = blockIdx.x * 1024 + t;
    int v = (i < N_NODES) ? cnt[i] : 0;
#pragma unroll
    for (int m = 1; m < 64; m <<= 1) v += __shfl_xor(v, m, 64);
    if (lane == 0) ws[wid] = v;
    __syncthreads();
    if (t == 0) {
        int s = 0;
#pragma unroll
        for (int k = 0; k < 16; ++k) s += ws[k];
        bsum[blockIdx.x] = s;
    }
}

__global__ void __launch_bounds__(1024)
k2b_scan(const int* __restrict__ cnt, const int* __restrict__ bsum,
         int* __restrict__ starts, int nblk) {
    __shared__ int wsum[16];
    __shared__ int s_off;
    int t = threadIdx.x, lane = t & 63, wid = t >> 6;
    int bid = blockIdx.x;
    if (t == 0) {
        int o = 0;
        for (int b = 0; b < bid; ++b) o += bsum[b];
        s_off = o;
    }
    int i = bid * 1024 + t;
    int v = (i < N_NODES) ? cnt[i] : 0;
    int sc = v; // inclusive wave scan
#pragma unroll
    for (int s = 1; s < 64; s <<= 1) {
        int u = __shfl_up(sc, s, 64);
        if (lane >= s) sc += u;
    }
    if (lane == 63) wsum[wid] = sc;
    __syncthreads();
    if (wid == 0 && lane < 16) {
        int ws = wsum[lane];
#pragma unroll
        for (int s = 1; s < 16; s <<= 1) {
            int u = __shfl_up(ws, s, 64);
            if (lane >= s) ws += u;
        }
        wsum[lane] = ws;
    }
    __syncthreads();
    int off = s_off + ((wid == 0) ? 0 : wsum[wid - 1]);
    int excl = off + sc - v;
    if (i < N_NODES) starts[i] = excl;
    if (bid == nblk - 1 && t == 1023) starts[N_NODES] = s_off + wsum[15];
}

// ---------------------------------------------------------------------------
// K4: layer-1 node projection, register-tiled 4 nodes x 4 cols per thread.
//     hp written as FP16. Runs BEFORE k1 so asn1 can be embedded there.
// ---------------------------------------------------------------------------
__global__ void __launch_bounds__(256)
k4_proj1(const float* __restrict__ x, const float* __restrict__ W,
         const float* __restrict__ asf, const float* __restrict__ adf,
         __half* __restrict__ hp, float* __restrict__ asn, float* __restrict__ adn) {
    __shared__ float sxT[F_IN * 33]; // [f][i], i in [0,32), pad 1
    int t = threadIdx.x;
    int n0 = blockIdx.x * 32;
    {
        int f = t & 63, i0 = t >> 6;
#pragma unroll
        for (int s = 0; s < 8; ++s) {
            int i = i0 + s * 4;
            int n = n0 + i;
            sxT[f * 33 + i] = (n < N_NODES) ? x[(size_t)n * F_IN + f] : 0.f;
        }
    }
    __syncthreads();
    int kq = t & 31, nq = t >> 5;
    float acc[4][4] = {};
    for (int f = 0; f < F_IN; ++f) {
        float a0 = sxT[f * 33 + nq * 4 + 0];
        float a1 = sxT[f * 33 + nq * 4 + 1];
        float a2 = sxT[f * 33 + nq * 4 + 2];
        float a3 = sxT[f * 33 + nq * 4 + 3];
        float4 w4 = *reinterpret_cast<const float4*>(W + (size_t)f * K_DIM + kq * 4);
        acc[0][0] += a0 * w4.x; acc[0][1] += a0 * w4.y; acc[0][2] += a0 * w4.z; acc[0][3] += a0 * w4.w;
        acc[1][0] += a1 * w4.x; acc[1][1] += a1 * w4.y; acc[1][2] += a1 * w4.z; acc[1][3] += a1 * w4.w;
        acc[2][0] += a2 * w4.x; acc[2][1] += a2 * w4.y; acc[2][2] += a2 * w4.z; acc[2][3] += a2 * w4.w;
        acc[3][0] += a3 * w4.x; acc[3][1] += a3 * w4.y; acc[3][2] += a3 * w4.z; acc[3][3] += a3 * w4.w;
    }
    int head = kq >> 3;
    float4 va = *reinterpret_cast<const float4*>(asf + kq * 4);
    float4 vd = *reinterpret_cast<const float4*>(adf + kq * 4);
#pragma unroll
    for (int i = 0; i < 4; ++i) {
        int n = n0 + nq * 4 + i;
        if (n < N_NODES) {
            __half2* hp2 = reinterpret_cast<__half2*>(hp + (size_t)n * K_DIM + kq * 4);
            hp2[0] = __float22half2_rn(make_float2(acc[i][0], acc[i][1]));
            hp2[1] = __float22half2_rn(make_float2(acc[i][2], acc[i][3]));
        }
        float s = acc[i][0] * va.x + acc[i][1] * va.y + acc[i][2] * va.z + acc[i][3] * va.w;
        float d = acc[i][0] * vd.x + acc[i][1] * vd.y + acc[i][2] * vd.z + acc[i][3] * vd.w;
#pragma unroll
        for (int m = 1; m < 8; m <<= 1) {
            s += __shfl_xor(s, m, 8);
            d += __shfl_xor(d, m, 8);
        }
        if ((kq & 7) == 0 && n < N_NODES) {
            asn[(size_t)n * 4 + head] = s;
            adn[(size_t)n * 4 + head] = d;
        }
    }
}

// ---------------------------------------------------------------------------
// K1: FUSED edge projection + scatter (R13: k3's 64 MB aer round-trip was
//     pure data motion). Pure-stream LDS-tile compute as before; raw accs
//     staged in srec (8 KB LDS, lane-consecutive writes); per-edge pos/src/
//     asn loaded COALESCED UP FRONT (no atomic — R7's poison chain); all 256
//     records written in ONE drain at block end (2x float4 = full 32 B
//     sector each). Record: [src | h2(sa01) h2(sa23) | h2(ae1_01) h2(ae1_23)
//     | h2(ae2_01) h2(ae2_23) | pad].
// ---------------------------------------------------------------------------
__global__ void __launch_bounds__(256)
k1_fused(const float* __restrict__ ea, const float* __restrict__ v,
         const int* __restrict__ ei, const int* __restrict__ rank,
         const int* __restrict__ starts, const float* __restrict__ asn,
         float4* __restrict__ el) {
    __shared__ float sx[2][32 * 68];
    __shared__ float srec[256 * 8]; // [tile*32+le][o]
    int t = threadIdx.x;
    int o  = t & 7;
    int le = t >> 3;
    int base = blockIdx.x * 256;
    // ---- front loads for end-phase (edge = base + t), all coalesced/early --
    int my_e   = base + t;
    int my_src = ei[my_e];
    int my_dst = ei[N_EDGES + my_e];
    int my_pos = starts[my_dst] + rank[my_e];
    float4 my_as = *reinterpret_cast<const float4*>(asn + (size_t)my_src * 4);
    float4 vr[16];
    {
        const float4* vrow = reinterpret_cast<const float4*>(v + o * 64);
#pragma unroll
        for (int c = 0; c < 16; ++c) vr[c] = vrow[c];
    }
    const float4* ea4 = reinterpret_cast<const float4*>(ea);
    {
        size_t gb = (size_t)base * 16;
        float4 a = ea4[gb + t];
        float4 b = ea4[gb + t + 256];
        int g0 = t, g1 = t + 256;
        *reinterpret_cast<float4*>(&sx[0][(g0 >> 4) * 68 + (g0 & 15) * 4]) = a;
        *reinterpret_cast<float4*>(&sx[0][(g1 >> 4) * 68 + (g1 & 15) * 4]) = b;
    }
    __syncthreads();
    for (int tile = 0; tile < 8; ++tile) {
        float4 a, b;
        if (tile < 7) { // prefetch next tile (coalesced)
            size_t gb = (size_t)(base + (tile + 1) * 32) * 16;
            a = ea4[gb + t];
            b = ea4[gb + t + 256];
        }
        const float* row = &sx[tile & 1][le * 68];
        float4 ac = make_float4(0.f, 0.f, 0.f, 0.f);
#pragma unroll
        for (int c = 0; c < 16; ++c) {
            float4 x4 = *reinterpret_cast<const float4*>(row + c * 4);
            ac.x = fmaf(x4.x, vr[c].x, ac.x);
            ac.y = fmaf(x4.y, vr[c].y, ac.y);
            ac.z = fmaf(x4.z, vr[c].z, ac.z);
            ac.w = fmaf(x4.w, vr[c].w, ac.w);
        }
        srec[(tile * 32 + le) * 8 + o] = (ac.x + ac.y) + (ac.z + ac.w);
        if (tile < 7) { // write next tile into other buffer
            int g0 = t, g1 = t + 256;
            int nb = (tile + 1) & 1;
            *reinterpret_cast<float4*>(&sx[nb][(g0 >> 4) * 68 + (g0 & 15) * 4]) = a;
            *reinterpret_cast<float4*>(&sx[nb][(g1 >> 4) * 68 + (g1 & 15) * 4]) = b;
        }
        __syncthreads();
    }
    // ---- end phase: thread t emits the record for edge base + t -----------
    const float* rp = &srec[t * 8];
    float4 a1 = *reinterpret_cast<const float4*>(rp);     // layer-1 a_e
    float4 a2 = *reinterpret_cast<const float4*>(rp + 4); // layer-2 a_e
    __half2 sa01 = __float22half2_rn(make_float2(my_as.x + a1.x, my_as.y + a1.y));
    __half2 sa23 = __float22half2_rn(make_float2(my_as.z + a1.z, my_as.w + a1.w));
    __half2 e101 = __float22half2_rn(make_float2(a1.x, a1.y));
    __half2 e123 = __float22half2_rn(make_float2(a1.z, a1.w));
    __half2 e201 = __float22half2_rn(make_float2(a2.x, a2.y));
    __half2 e223 = __float22half2_rn(make_float2(a2.z, a2.w));
    float4* r = el + (size_t)my_pos * 2;
    r[0] = make_float4(__int_as_float(my_src), h2bits(sa01), h2bits(sa23), h2bits(e101));
    r[1] = make_float4(h2bits(e123), h2bits(e201), h2bits(e223), 0.f);
}

// ---------------------------------------------------------------------------
// K5: FUSED layer-1 aggregation + layer-2 reduced projection. One 64-lane
//     wave per node (4 nodes/block); x2 stays in LDS; 16-lane groups compute
//     the 48 u-dots -> asg2/adn2.
// ---------------------------------------------------------------------------
__global__ void __launch_bounds__(256)
k5_fused(const int* __restrict__ starts, const float* __restrict__ el,
         const float* __restrict__ asn, const float* __restrict__ adn,
         const __half* __restrict__ hp, const float* __restrict__ b1,
         const float* __restrict__ u,
         float* __restrict__ asg, float* __restrict__ adn2) {
    __shared__ float su[12 * K_DIM]; // 6 KB
    __shared__ float sx2[4 * K_DIM]; // 2 KB
    int t = threadIdx.x;
    for (int i = t; i < 12 * K_DIM; i += 256) su[i] = u[i];
    int lane = t & 63;
    int wv = t >> 6;
    int node = blockIdx.x * 4 + wv; // N_NODES % 4 == 0: always valid
    int s = starts[node], e = starts[node + 1];
    int head = lane >> 4; // col pair = lane*2; head = (lane*2)>>5
    float adv = adn[(size_t)node * 4 + head];
    float accx = 0.f, accy = 0.f, dsum = 0.f, aesum = 0.f;
    int j = s;
    for (; j + 2 <= e; j += 2) {
        const float* r0 = el + (size_t)j * 8;
        const float* r1 = r0 + 8;
        float4 ra0 = *reinterpret_cast<const float4*>(r0);
        float  rb0 = r0[4];
        float4 ra1 = *reinterpret_cast<const float4*>(r1);
        float  rb1 = r1[4];
        int src0 = __float_as_int(ra0.x);
        int src1 = __float_as_int(ra1.x);
        float sa0 = pick_half(ra0.y, ra0.z, head);
        float sa1 = pick_half(ra1.y, ra1.z, head);
        float ar0 = pick_half(ra0.w, rb0, head);
        float ar1 = pick_half(ra1.w, rb1, head);
        float2 h0 = __half22float2(*reinterpret_cast<const __half2*>(hp + (size_t)src0 * K_DIM + lane * 2));
        float2 h1 = __half22float2(*reinterpret_cast<const __half2*>(hp + (size_t)src1 * K_DIM + lane * 2));
        float ex0 = __expf(lrelu(sa0 + adv));
        float ex1 = __expf(lrelu(sa1 + adv));
        accx = fmaf(ex0, h0.x, fmaf(ex1, h1.x, accx));
        accy = fmaf(ex0, h0.y, fmaf(ex1, h1.y, accy));
        dsum += ex0 + ex1;
        aesum += ar0 + ar1;
    }
    if (j < e) {
        const float* r0 = el + (size_t)j * 8;
        float4 ra0 = *reinterpret_cast<const float4*>(r0);
        float  rb0 = r0[4];
        int src = __float_as_int(ra0.x);
        float sa = pick_half(ra0.y, ra0.z, head);
        float ar = pick_half(ra0.w, rb0, head);
        float ex = __expf(lrelu(sa + adv));
        float2 hv = __half22float2(*reinterpret_cast<const __half2*>(hp + (size_t)src * K_DIM + lane * 2));
        accx = fmaf(ex, hv.x, accx);
        accy = fmaf(ex, hv.y, accy);
        dsum += ex;
        aesum += ar;
    }
    float deg = (float)(e - s);
    float al = aesum / fmaxf(deg, 1.f); // self-loop a_e = mean of incoming
    float exl = __expf(lrelu(asn[(size_t)node * 4 + head] + adv + al));
    float2 hv = __half22float2(*reinterpret_cast<const __half2*>(hp + (size_t)node * K_DIM + lane * 2));
    accx += exl * hv.x;
    accy += exl * hv.y;
    dsum += exl;
    float2 bb = *reinterpret_cast<const float2*>(b1 + lane * 2);
    sx2[wv * K_DIM + lane * 2 + 0] = fmaxf(accx / dsum + bb.x, 0.f);
    sx2[wv * K_DIM + lane * 2 + 1] = fmaxf(accy / dsum + bb.y, 0.f);
    __syncthreads();
    // ---- layer-2 reduced projection: 48 outputs (4 nodes x 12 folds) ----
    int g = t >> 4;      // 16 groups of 16 lanes
    int l16 = t & 15;
#pragma unroll
    for (int r = 0; r < 3; ++r) {
        int oid = g * 3 + r;      // 0..47
        int nl = oid / 12;
        int q  = oid % 12;        // h*3 + type
        int h = q / 3, type = q % 3;
        const float* xr = &sx2[nl * K_DIM];
        const float* ur = &su[q * K_DIM];
        float sv = 0.f;
#pragma unroll
        for (int i = 0; i < 8; ++i)
            sv = fmaf(xr[l16 + 16 * i], ur[l16 + 16 * i], sv);
#pragma unroll
        for (int m = 1; m < 16; m <<= 1) sv += __shfl_xor(sv, m, 16);
        if (l16 == 0) {
            int n = blockIdx.x * 4 + nl;
            if (type == 0)      asg[(size_t)n * 8 + h] = sv;
            else if (type == 1) adn2[(size_t)n * 4 + h] = sv;
            else                asg[(size_t)n * 8 + 4 + h] = sv;
        }
    }
}

// ---------------------------------------------------------------------------
// K7: layer-2 gather: 16-lane group per node, lanes stride the edge list.
// ---------------------------------------------------------------------------
__global__ void __launch_bounds__(256)
k7_l2(const int* __restrict__ starts, const float* __restrict__ el,
      const float* __restrict__ asg, const float* __restrict__ adn,
      const float* __restrict__ cbias, float* __restrict__ out) {
    int t = threadIdx.x;
    int g16 = t & 15;
    int node = blockIdx.x * 16 + (t >> 4);
    if (node >= N_NODES) return;
    int s = starts[node], e = starts[node + 1];
    float4 ad4 = *reinterpret_cast<const float4*>(adn + (size_t)node * 4);
    float4 dsum = make_float4(0, 0, 0, 0);
    float4 gsum = make_float4(0, 0, 0, 0);
    float4 aesum = make_float4(0, 0, 0, 0);
    for (int j = s + g16; j < e; j += 16) {
        const float* rb = el + (size_t)j * 8;
        int src = __float_as_int(rb[0]);
        float4 r2 = *reinterpret_cast<const float4*>(rb + 4); // f4..f7
        float f5 = r2.y, f6 = r2.z;
        __half2 h01 = *reinterpret_cast<__half2*>(&f5);
        __half2 h23 = *reinterpret_cast<__half2*>(&f6);
        float4 ae4 = make_float4(__low2float(h01), __high2float(h01),
                                 __low2float(h23), __high2float(h23));
        const float* ap = asg + (size_t)src * 8;
        float4 as4 = *reinterpret_cast<const float4*>(ap);
        float4 g4  = *reinterpret_cast<const float4*>(ap + 4);
        float e0 = __expf(lrelu(as4.x + ad4.x + ae4.x));
        float e1 = __expf(lrelu(as4.y + ad4.y + ae4.y));
        float e2 = __expf(lrelu(as4.z + ad4.z + ae4.z));
        float e3 = __expf(lrelu(as4.w + ad4.w + ae4.w));
        dsum.x += e0; dsum.y += e1; dsum.z += e2; dsum.w += e3;
        gsum.x += e0 * g4.x; gsum.y += e1 * g4.y; gsum.z += e2 * g4.z; gsum.w += e3 * g4.w;
        aesum.x += ae4.x; aesum.y += ae4.y; aesum.z += ae4.z; aesum.w += ae4.w;
    }
#pragma unroll
    for (int m = 1; m < 16; m <<= 1) {
        dsum.x += __shfl_xor(dsum.x, m, 16);  dsum.y += __shfl_xor(dsum.y, m, 16);
        dsum.z += __shfl_xor(dsum.z, m, 16);  dsum.w += __shfl_xor(dsum.w, m, 16);
        gsum.x += __shfl_xor(gsum.x, m, 16);  gsum.y += __shfl_xor(gsum.y, m, 16);
        gsum.z += __shfl_xor(gsum.z, m, 16);  gsum.w += __shfl_xor(gsum.w, m, 16);
        aesum.x += __shfl_xor(aesum.x, m, 16); aesum.y += __shfl_xor(aesum.y, m, 16);
        aesum.z += __shfl_xor(aesum.z, m, 16); aesum.w += __shfl_xor(aesum.w, m, 16);
    }
    if (g16 == 0) {
        float deg = fmaxf((float)(e - s), 1.f);
        const float* ap = asg + (size_t)node * 8;
        float4 mas = *reinterpret_cast<const float4*>(ap);
        float4 mg  = *reinterpret_cast<const float4*>(ap + 4);
        float r = cbias[0];
        float e0;
        e0 = __expf(lrelu(mas.x + ad4.x + aesum.x / deg)); r += (gsum.x + e0 * mg.x) / (dsum.x + e0);
        e0 = __expf(lrelu(mas.y + ad4.y + aesum.y / deg)); r += (gsum.y + e0 * mg.y) / (dsum.y + e0);
        e0 = __expf(lrelu(mas.z + ad4.z + aesum.z / deg)); r += (gsum.z + e0 * mg.z) / (dsum.z + e0);
        e0 = __expf(lrelu(mas.w + ad4.w + aesum.w / deg)); r += (gsum.w + e0 * mg.w) / (dsum.w + e0);
        out[node] = r;
    }
}

// ---------------------------------------------------------------------------
extern "C" void kernel_launch(void* const* d_in, const int* in_sizes, int n_in,
                              void* d_out, int out_size, void* d_ws, size_t ws_size,
                              hipStream_t stream) {
    (void)in_sizes; (void)n_in; (void)out_size;
    const float* x    = (const float*)d_in[0];
    const float* ea   = (const float*)d_in[1];
    const float* W1   = (const float*)d_in[2];
    const float* as1  = (const float*)d_in[3];
    const float* ad1  = (const float*)d_in[4];
    const float* We1  = (const float*)d_in[5];
    const float* ae1  = (const float*)d_in[6];
    const float* b1   = (const float*)d_in[7];
    const float* W2   = (const float*)d_in[8];
    const float* as2  = (const float*)d_in[9];
    const float* ad2  = (const float*)d_in[10];
    const float* We2  = (const float*)d_in[11];
    const float* ae2  = (const float*)d_in[12];
    const float* b2   = (const float*)d_in[13];
    const float* linw = (const float*)d_in[14];
    const float* linb = (const float*)d_in[15];
    const int*   ei   = (const int*)d_in[16];
    float* out = (float*)d_out;
    float* ws  = (float*)d_ws;

    const int SCAN_BLK = (N_NODES + 1023) / 1024; // 49

    size_t off = 0;
    __half* h1p  = (__half*)(ws + off); off += (size_t)N_NODES * K_DIM / 2; // fp16
    float* asn1  = ws + off; off += (size_t)N_NODES * 4;
    float* adn1  = ws + off; off += (size_t)N_NODES * 4;
    float* asg2  = ws + off; off += (size_t)N_NODES * 8;
    float* adn2  = ws + off; off += (size_t)N_NODES * 4;
    float* vbuf  = ws + off; off += 512;
    float* ubuf  = ws + off; off += 12 * K_DIM;
    float* cbias = ws + off; off += 64;
    int* starts  = (int*)(ws + off); off += (size_t)N_NODES + 8;
    int* bsum    = (int*)(ws + off); off += 64;
    int* rank    = (int*)(ws + off); off += (size_t)N_EDGES;
    // pad to 8-float (32 B) boundary for el records
    off = (off + 7) & ~(size_t)7;
    float* el    = ws + off; off += (size_t)N_EDGES * 8; // 32 B fp16 records
    int* cnt     = (int*)(ws + off); off += (size_t)N_NODES;

    if (ws_size < off * sizeof(float)) return; // workspace too small: fail visibly

    hipMemsetAsync(cnt, 0, N_NODES * sizeof(int), stream);

    kc_fold<<<N_EDGES / 256 + 1, 256, 0, stream>>>(ei, cnt, rank, We1, ae1, We2, ae2,
                                                   as2, ad2, W2, b2, linw, linb,
                                                   vbuf, ubuf, cbias);
    k2a_bsum<<<SCAN_BLK, 1024, 0, stream>>>(cnt, bsum);
    k2b_scan<<<SCAN_BLK, 1024, 0, stream>>>(cnt, bsum, starts, SCAN_BLK);
    k4_proj1<<<(N_NODES + 31) / 32, 256, 0, stream>>>(x, W1, as1, ad1, h1p, asn1, adn1);
    k1_fused<<<N_EDGES / 256, 256, 0, stream>>>(ea, vbuf, ei, rank, starts, asn1,
                                                (float4*)el);
    k5_fused<<<N_NODES / 4, 256, 0, stream>>>(starts, el, asn1, adn1, h1p, b1,
                                              ubuf, asg2, adn2);
    k7_l2<<<(N_NODES + 15) / 16, 256, 0, stream>>>(starts, el, asg2, adn2, cbias, out);
}

// Round 15
// 227.516 us; speedup vs baseline: 1.7111x; 1.0551x over previous
//
#include <hip/hip_runtime.h>
#include <hip/hip_fp16.h>

#define N_NODES 50000
#define N_EDGES 800000
#define F_IN    64
#define HEADS   4
#define CH      32
#define K_DIM   128
#define NEG     0.2f

__device__ __forceinline__ float lrelu(float x) { return x > 0.f ? x : NEG * x; }

__device__ __forceinline__ float h2bits(__half2 h) {
    return *reinterpret_cast<float*>(&h);
}
// pick head-th fp16 from two packed half2 words (lo2 = heads 0,1; hi2 = heads 2,3)
__device__ __forceinline__ float pick_half(float lo2, float hi2, int head) {
    float f = (head < 2) ? lo2 : hi2;
    __half2 h = *reinterpret_cast<__half2*>(&f);
    return (head & 1) ? __high2float(h) : __low2float(h);
}

// ---------------------------------------------------------------------------
// KC: degree count + per-edge rank (atomic return value) from ei. LAST block
//     performs the weight folds instead: v[8][64] (We*ae), u[12][128]
//     (W2 folds: q=h*3+type, type 0=a_s2 1=a_d2 2=g), cbias.
// ---------------------------------------------------------------------------
__global__ void __launch_bounds__(256)
kc_fold(const int* __restrict__ ei, int* __restrict__ cnt, int* __restrict__ rank,
        const float* __restrict__ We1, const float* __restrict__ ae1,
        const float* __restrict__ We2, const float* __restrict__ ae2,
        const float* __restrict__ as2, const float* __restrict__ ad2,
        const float* __restrict__ W2,
        const float* __restrict__ b2,  const float* __restrict__ linw,
        const float* __restrict__ linb,
        float* __restrict__ v, float* __restrict__ u, float* __restrict__ cbias) {
    if (blockIdx.x >= N_EDGES / 256) { // fold block
        int t = threadIdx.x;
        for (int idx = t; idx < 512; idx += 256) {
            int o = idx >> 6, f = idx & 63;
            const float* We = (o < 4) ? We1 : We2;
            const float* ae = (o < 4) ? ae1 : ae2;
            int h = o & 3;
            float s = 0.f;
            for (int c = 0; c < CH; ++c)
                s += We[f * K_DIM + h * CH + c] * ae[h * CH + c];
            v[o * 64 + f] = s;
        }
        for (int idx = t; idx < 12 * K_DIM; idx += 256) {
            int q = idx >> 7, f = idx & 127;
            int h = q / 3, type = q % 3;
            const float* w = (type == 0) ? as2 : (type == 1) ? ad2 : linw;
            float s = 0.f;
            for (int c = 0; c < CH; ++c)
                s += W2[(size_t)f * K_DIM + h * CH + c] * w[h * CH + c];
            u[idx] = s;
        }
        if (t == 0) {
            float s = 0.f;
            for (int k = 0; k < K_DIM; ++k) s += b2[k] * linw[k];
            *cbias = s + linb[0];
        }
        return;
    }
    int e = blockIdx.x * 256 + threadIdx.x;
    rank[e] = atomicAdd(cnt + ei[N_EDGES + e], 1);
}

// ---------------------------------------------------------------------------
// K2a/K2b: hierarchical exclusive scan (starts only).
// ---------------------------------------------------------------------------
__global__ void __launch_bounds__(1024)
k2a_bsum(const int* __restrict__ cnt, int* __restrict__ bsum) {
    __shared__ int ws[16];
    int t = threadIdx.x, lane = t & 63, wid = t >> 6;
    int i = blockIdx.x * 1024 + t;
    int v = (i < N_NODES) ? cnt[i] : 0;
#pragma unroll
    for (int m = 1; m < 64; m <<= 1) v += __shfl_xor(v, m, 64);
    if (lane == 0) ws[wid] = v;
    __syncthreads();
    if (t == 0) {
        int s = 0;
#pragma unroll
        for (int k = 0; k < 16; ++k) s += ws[k];
        bsum[blockIdx.x] = s;
    }
}

__global__ void __launch_bounds__(1024)
k2b_scan(const int* __restrict__ cnt, const int* __restrict__ bsum,
         int* __restrict__ starts, int nblk) {
    __shared__ int wsum[16];
    __shared__ int s_off;
    int t = threadIdx.x, lane = t & 63, wid = t >> 6;
    int bid = blockIdx.x;
    if (t == 0) {
        int o = 0;
        for (int b = 0; b < bid; ++b) o += bsum[b];
        s_off = o;
    }
    int i = bid * 1024 + t;
    int v = (i < N_NODES) ? cnt[i] : 0;
    int sc = v; // inclusive wave scan
#pragma unroll
    for (int s = 1; s < 64; s <<= 1) {
        int u = __shfl_up(sc, s, 64);
        if (lane >= s) sc += u;
    }
    if (lane == 63) wsum[wid] = sc;
    __syncthreads();
    if (wid == 0 && lane < 16) {
        int ws = wsum[lane];
#pragma unroll
        for (int s = 1; s < 16; s <<= 1) {
            int u = __shfl_up(ws, s, 64);
            if (lane >= s) ws += u;
        }
        wsum[lane] = ws;
    }
    __syncthreads();
    int off = s_off + ((wid == 0) ? 0 : wsum[wid - 1]);
    int excl = off + sc - v;
    if (i < N_NODES) starts[i] = excl;
    if (bid == nblk - 1 && t == 1023) starts[N_NODES] = s_off + wsum[15];
}

// ---------------------------------------------------------------------------
// K4: layer-1 node projection, register-tiled 4 nodes x 4 cols per thread.
//     hp written as FP16. Runs BEFORE k1 so asn1 can be embedded there.
// ---------------------------------------------------------------------------
__global__ void __launch_bounds__(256)
k4_proj1(const float* __restrict__ x, const float* __restrict__ W,
         const float* __restrict__ asf, const float* __restrict__ adf,
         __half* __restrict__ hp, float* __restrict__ asn, float* __restrict__ adn) {
    __shared__ float sxT[F_IN * 33]; // [f][i], i in [0,32), pad 1
    int t = threadIdx.x;
    int n0 = blockIdx.x * 32;
    {
        int f = t & 63, i0 = t >> 6;
#pragma unroll
        for (int s = 0; s < 8; ++s) {
            int i = i0 + s * 4;
            int n = n0 + i;
            sxT[f * 33 + i] = (n < N_NODES) ? x[(size_t)n * F_IN + f] : 0.f;
        }
    }
    __syncthreads();
    int kq = t & 31, nq = t >> 5;
    float acc[4][4] = {};
    for (int f = 0; f < F_IN; ++f) {
        float a0 = sxT[f * 33 + nq * 4 + 0];
        float a1 = sxT[f * 33 + nq * 4 + 1];
        float a2 = sxT[f * 33 + nq * 4 + 2];
        float a3 = sxT[f * 33 + nq * 4 + 3];
        float4 w4 = *reinterpret_cast<const float4*>(W + (size_t)f * K_DIM + kq * 4);
        acc[0][0] += a0 * w4.x; acc[0][1] += a0 * w4.y; acc[0][2] += a0 * w4.z; acc[0][3] += a0 * w4.w;
        acc[1][0] += a1 * w4.x; acc[1][1] += a1 * w4.y; acc[1][2] += a1 * w4.z; acc[1][3] += a1 * w4.w;
        acc[2][0] += a2 * w4.x; acc[2][1] += a2 * w4.y; acc[2][2] += a2 * w4.z; acc[2][3] += a2 * w4.w;
        acc[3][0] += a3 * w4.x; acc[3][1] += a3 * w4.y; acc[3][2] += a3 * w4.z; acc[3][3] += a3 * w4.w;
    }
    int head = kq >> 3;
    float4 va = *reinterpret_cast<const float4*>(asf + kq * 4);
    float4 vd = *reinterpret_cast<const float4*>(adf + kq * 4);
#pragma unroll
    for (int i = 0; i < 4; ++i) {
        int n = n0 + nq * 4 + i;
        if (n < N_NODES) {
            __half2* hp2 = reinterpret_cast<__half2*>(hp + (size_t)n * K_DIM + kq * 4);
            hp2[0] = __float22half2_rn(make_float2(acc[i][0], acc[i][1]));
            hp2[1] = __float22half2_rn(make_float2(acc[i][2], acc[i][3]));
        }
        float s = acc[i][0] * va.x + acc[i][1] * va.y + acc[i][2] * va.z + acc[i][3] * va.w;
        float d = acc[i][0] * vd.x + acc[i][1] * vd.y + acc[i][2] * vd.z + acc[i][3] * vd.w;
#pragma unroll
        for (int m = 1; m < 8; m <<= 1) {
            s += __shfl_xor(s, m, 8);
            d += __shfl_xor(d, m, 8);
        }
        if ((kq & 7) == 0 && n < N_NODES) {
            asn[(size_t)n * 4 + head] = s;
            adn[(size_t)n * 4 + head] = d;
        }
    }
}

// ---------------------------------------------------------------------------
// K1: FUSED edge projection + scatter. Pure-stream LDS-tile compute; raw accs
//     staged in srec; per-edge pos/src/asn loaded coalesced up front; all 256
//     records written in one drain at block end.
// ---------------------------------------------------------------------------
__global__ void __launch_bounds__(256)
k1_fused(const float* __restrict__ ea, const float* __restrict__ v,
         const int* __restrict__ ei, const int* __restrict__ rank,
         const int* __restrict__ starts, const float* __restrict__ asn,
         float4* __restrict__ el) {
    __shared__ float sx[2][32 * 68];
    __shared__ float srec[256 * 8]; // [tile*32+le][o]
    int t = threadIdx.x;
    int o  = t & 7;
    int le = t >> 3;
    int base = blockIdx.x * 256;
    // ---- front loads for end-phase (edge = base + t), all coalesced/early --
    int my_e   = base + t;
    int my_src = ei[my_e];
    int my_dst = ei[N_EDGES + my_e];
    int my_pos = starts[my_dst] + rank[my_e];
    float4 my_as = *reinterpret_cast<const float4*>(asn + (size_t)my_src * 4);
    float4 vr[16];
    {
        const float4* vrow = reinterpret_cast<const float4*>(v + o * 64);
#pragma unroll
        for (int c = 0; c < 16; ++c) vr[c] = vrow[c];
    }
    const float4* ea4 = reinterpret_cast<const float4*>(ea);
    {
        size_t gb = (size_t)base * 16;
        float4 a = ea4[gb + t];
        float4 b = ea4[gb + t + 256];
        int g0 = t, g1 = t + 256;
        *reinterpret_cast<float4*>(&sx[0][(g0 >> 4) * 68 + (g0 & 15) * 4]) = a;
        *reinterpret_cast<float4*>(&sx[0][(g1 >> 4) * 68 + (g1 & 15) * 4]) = b;
    }
    __syncthreads();
    for (int tile = 0; tile < 8; ++tile) {
        float4 a, b;
        if (tile < 7) { // prefetch next tile (coalesced)
            size_t gb = (size_t)(base + (tile + 1) * 32) * 16;
            a = ea4[gb + t];
            b = ea4[gb + t + 256];
        }
        const float* row = &sx[tile & 1][le * 68];
        float4 ac = make_float4(0.f, 0.f, 0.f, 0.f);
#pragma unroll
        for (int c = 0; c < 16; ++c) {
            float4 x4 = *reinterpret_cast<const float4*>(row + c * 4);
            ac.x = fmaf(x4.x, vr[c].x, ac.x);
            ac.y = fmaf(x4.y, vr[c].y, ac.y);
            ac.z = fmaf(x4.z, vr[c].z, ac.z);
            ac.w = fmaf(x4.w, vr[c].w, ac.w);
        }
        srec[(tile * 32 + le) * 8 + o] = (ac.x + ac.y) + (ac.z + ac.w);
        if (tile < 7) { // write next tile into other buffer
            int g0 = t, g1 = t + 256;
            int nb = (tile + 1) & 1;
            *reinterpret_cast<float4*>(&sx[nb][(g0 >> 4) * 68 + (g0 & 15) * 4]) = a;
            *reinterpret_cast<float4*>(&sx[nb][(g1 >> 4) * 68 + (g1 & 15) * 4]) = b;
        }
        __syncthreads();
    }
    // ---- end phase: thread t emits the record for edge base + t -----------
    const float* rp = &srec[t * 8];
    float4 a1 = *reinterpret_cast<const float4*>(rp);     // layer-1 a_e
    float4 a2 = *reinterpret_cast<const float4*>(rp + 4); // layer-2 a_e
    __half2 sa01 = __float22half2_rn(make_float2(my_as.x + a1.x, my_as.y + a1.y));
    __half2 sa23 = __float22half2_rn(make_float2(my_as.z + a1.z, my_as.w + a1.w));
    __half2 e101 = __float22half2_rn(make_float2(a1.x, a1.y));
    __half2 e123 = __float22half2_rn(make_float2(a1.z, a1.w));
    __half2 e201 = __float22half2_rn(make_float2(a2.x, a2.y));
    __half2 e223 = __float22half2_rn(make_float2(a2.z, a2.w));
    float4* r = el + (size_t)my_pos * 2;
    r[0] = make_float4(__int_as_float(my_src), h2bits(sa01), h2bits(sa23), h2bits(e101));
    r[1] = make_float4(h2bits(e123), h2bits(e201), h2bits(e223), 0.f);
}

// ---------------------------------------------------------------------------
// K5: FUSED layer-1 aggregation + layer-2 reduced projection. One 64-lane
//     wave per node; 4-WAY unrolled gather loop (R14: 2-deep chain at ~8
//     serial iterations was the latency suspect; 4 records' loads now issue
//     back-to-back before any dependent use).
// ---------------------------------------------------------------------------
__global__ void __launch_bounds__(256)
k5_fused(const int* __restrict__ starts, const float* __restrict__ el,
         const float* __restrict__ asn, const float* __restrict__ adn,
         const __half* __restrict__ hp, const float* __restrict__ b1,
         const float* __restrict__ u,
         float* __restrict__ asg, float* __restrict__ adn2) {
    __shared__ float su[12 * K_DIM]; // 6 KB
    __shared__ float sx2[4 * K_DIM]; // 2 KB
    int t = threadIdx.x;
    for (int i = t; i < 12 * K_DIM; i += 256) su[i] = u[i];
    int lane = t & 63;
    int wv = t >> 6;
    int node = blockIdx.x * 4 + wv; // N_NODES % 4 == 0: always valid
    int s = starts[node], e = starts[node + 1];
    int head = lane >> 4; // col pair = lane*2; head = (lane*2)>>5
    float adv = adn[(size_t)node * 4 + head];
    float accx = 0.f, accy = 0.f, dsum = 0.f, aesum = 0.f;
    int j = s;
    for (; j + 4 <= e; j += 4) {
        const float* r0 = el + (size_t)j * 8;
        const float* r1 = r0 + 8;
        const float* r2 = r0 + 16;
        const float* r3 = r0 + 24;
        float4 ra0 = *reinterpret_cast<const float4*>(r0);
        float4 ra1 = *reinterpret_cast<const float4*>(r1);
        float4 ra2 = *reinterpret_cast<const float4*>(r2);
        float4 ra3 = *reinterpret_cast<const float4*>(r3);
        float  rb0 = r0[4];
        float  rb1 = r1[4];
        float  rb2 = r2[4];
        float  rb3 = r3[4];
        int src0 = __float_as_int(ra0.x);
        int src1 = __float_as_int(ra1.x);
        int src2 = __float_as_int(ra2.x);
        int src3 = __float_as_int(ra3.x);
        float2 h0 = __half22float2(*reinterpret_cast<const __half2*>(hp + (size_t)src0 * K_DIM + lane * 2));
        float2 h1 = __half22float2(*reinterpret_cast<const __half2*>(hp + (size_t)src1 * K_DIM + lane * 2));
        float2 h2 = __half22float2(*reinterpret_cast<const __half2*>(hp + (size_t)src2 * K_DIM + lane * 2));
        float2 h3 = __half22float2(*reinterpret_cast<const __half2*>(hp + (size_t)src3 * K_DIM + lane * 2));
        float sa0 = pick_half(ra0.y, ra0.z, head);
        float sa1 = pick_half(ra1.y, ra1.z, head);
        float sa2 = pick_half(ra2.y, ra2.z, head);
        float sa3 = pick_half(ra3.y, ra3.z, head);
        float ar0 = pick_half(ra0.w, rb0, head);
        float ar1 = pick_half(ra1.w, rb1, head);
        float ar2 = pick_half(ra2.w, rb2, head);
        float ar3 = pick_half(ra3.w, rb3, head);
        float ex0 = __expf(lrelu(sa0 + adv));
        float ex1 = __expf(lrelu(sa1 + adv));
        float ex2 = __expf(lrelu(sa2 + adv));
        float ex3 = __expf(lrelu(sa3 + adv));
        accx = fmaf(ex0, h0.x, fmaf(ex1, h1.x, fmaf(ex2, h2.x, fmaf(ex3, h3.x, accx))));
        accy = fmaf(ex0, h0.y, fmaf(ex1, h1.y, fmaf(ex2, h2.y, fmaf(ex3, h3.y, accy))));
        dsum += (ex0 + ex1) + (ex2 + ex3);
        aesum += (ar0 + ar1) + (ar2 + ar3);
    }
    for (; j < e; ++j) {
        const float* r0 = el + (size_t)j * 8;
        float4 ra0 = *reinterpret_cast<const float4*>(r0);
        float  rb0 = r0[4];
        int src = __float_as_int(ra0.x);
        float sa = pick_half(ra0.y, ra0.z, head);
        float ar = pick_half(ra0.w, rb0, head);
        float ex = __expf(lrelu(sa + adv));
        float2 hv = __half22float2(*reinterpret_cast<const __half2*>(hp + (size_t)src * K_DIM + lane * 2));
        accx = fmaf(ex, hv.x, accx);
        accy = fmaf(ex, hv.y, accy);
        dsum += ex;
        aesum += ar;
    }
    float deg = (float)(e - s);
    float al = aesum / fmaxf(deg, 1.f); // self-loop a_e = mean of incoming
    float exl = __expf(lrelu(asn[(size_t)node * 4 + head] + adv + al));
    float2 hv = __half22float2(*reinterpret_cast<const __half2*>(hp + (size_t)node * K_DIM + lane * 2));
    accx += exl * hv.x;
    accy += exl * hv.y;
    dsum += exl;
    float2 bb = *reinterpret_cast<const float2*>(b1 + lane * 2);
    sx2[wv * K_DIM + lane * 2 + 0] = fmaxf(accx / dsum + bb.x, 0.f);
    sx2[wv * K_DIM + lane * 2 + 1] = fmaxf(accy / dsum + bb.y, 0.f);
    __syncthreads();
    // ---- layer-2 reduced projection: 48 outputs (4 nodes x 12 folds) ----
    int g = t >> 4;      // 16 groups of 16 lanes
    int l16 = t & 15;
#pragma unroll
    for (int r = 0; r < 3; ++r) {
        int oid = g * 3 + r;      // 0..47
        int nl = oid / 12;
        int q  = oid % 12;        // h*3 + type
        int h = q / 3, type = q % 3;
        const float* xr = &sx2[nl * K_DIM];
        const float* ur = &su[q * K_DIM];
        float sv = 0.f;
#pragma unroll
        for (int i = 0; i < 8; ++i)
            sv = fmaf(xr[l16 + 16 * i], ur[l16 + 16 * i], sv);
#pragma unroll
        for (int m = 1; m < 16; m <<= 1) sv += __shfl_xor(sv, m, 16);
        if (l16 == 0) {
            int n = blockIdx.x * 4 + nl;
            if (type == 0)      asg[(size_t)n * 8 + h] = sv;
            else if (type == 1) adn2[(size_t)n * 4 + h] = sv;
            else                asg[(size_t)n * 8 + 4 + h] = sv;
        }
    }
}

// ---------------------------------------------------------------------------
// K7: layer-2 gather: 16-lane group per node, lanes stride the edge list.
//     2-way unrolled (records j, j+16 independent -> 2 outstanding chains).
// ---------------------------------------------------------------------------
__global__ void __launch_bounds__(256)
k7_l2(const int* __restrict__ starts, const float* __restrict__ el,
      const float* __restrict__ asg, const float* __restrict__ adn,
      const float* __restrict__ cbias, float* __restrict__ out) {
    int t = threadIdx.x;
    int g16 = t & 15;
    int node = blockIdx.x * 16 + (t >> 4);
    if (node >= N_NODES) return;
    int s = starts[node], e = starts[node + 1];
    float4 ad4 = *reinterpret_cast<const float4*>(adn + (size_t)node * 4);
    float4 dsum = make_float4(0, 0, 0, 0);
    float4 gsum = make_float4(0, 0, 0, 0);
    float4 aesum = make_float4(0, 0, 0, 0);
    int j = s + g16;
    for (; j + 16 < e; j += 32) {
        const float* rbA = el + (size_t)j * 8;
        const float* rbB = el + (size_t)(j + 16) * 8;
        int srcA = __float_as_int(rbA[0]);
        int srcB = __float_as_int(rbB[0]);
        float4 r2A = *reinterpret_cast<const float4*>(rbA + 4);
        float4 r2B = *reinterpret_cast<const float4*>(rbB + 4);
        const float* apA = asg + (size_t)srcA * 8;
        const float* apB = asg + (size_t)srcB * 8;
        float4 asA = *reinterpret_cast<const float4*>(apA);
        float4 gA  = *reinterpret_cast<const float4*>(apA + 4);
        float4 asB = *reinterpret_cast<const float4*>(apB);
        float4 gB  = *reinterpret_cast<const float4*>(apB + 4);
        float f5A = r2A.y, f6A = r2A.z;
        __half2 h01A = *reinterpret_cast<__half2*>(&f5A);
        __half2 h23A = *reinterpret_cast<__half2*>(&f6A);
        float4 aeA = make_float4(__low2float(h01A), __high2float(h01A),
                                 __low2float(h23A), __high2float(h23A));
        float f5B = r2B.y, f6B = r2B.z;
        __half2 h01B = *reinterpret_cast<__half2*>(&f5B);
        __half2 h23B = *reinterpret_cast<__half2*>(&f6B);
        float4 aeB = make_float4(__low2float(h01B), __high2float(h01B),
                                 __low2float(h23B), __high2float(h23B));
        float e0, e1, e2, e3;
        e0 = __expf(lrelu(asA.x + ad4.x + aeA.x));
        e1 = __expf(lrelu(asA.y + ad4.y + aeA.y));
        e2 = __expf(lrelu(asA.z + ad4.z + aeA.z));
        e3 = __expf(lrelu(asA.w + ad4.w + aeA.w));
        dsum.x += e0; dsum.y += e1; dsum.z += e2; dsum.w += e3;
        gsum.x += e0 * gA.x; gsum.y += e1 * gA.y; gsum.z += e2 * gA.z; gsum.w += e3 * gA.w;
        aesum.x += aeA.x; aesum.y += aeA.y; aesum.z += aeA.z; aesum.w += aeA.w;
        e0 = __expf(lrelu(asB.x + ad4.x + aeB.x));
        e1 = __expf(lrelu(asB.y + ad4.y + aeB.y));
        e2 = __expf(lrelu(asB.z + ad4.z + aeB.z));
        e3 = __expf(lrelu(asB.w + ad4.w + aeB.w));
        dsum.x += e0; dsum.y += e1; dsum.z += e2; dsum.w += e3;
        gsum.x += e0 * gB.x; gsum.y += e1 * gB.y; gsum.z += e2 * gB.z; gsum.w += e3 * gB.w;
        aesum.x += aeB.x; aesum.y += aeB.y; aesum.z += aeB.z; aesum.w += aeB.w;
    }
    if (j < e) {
        const float* rb = el + (size_t)j * 8;
        int src = __float_as_int(rb[0]);
        float4 r2 = *reinterpret_cast<const float4*>(rb + 4);
        float f5 = r2.y, f6 = r2.z;
        __half2 h01 = *reinterpret_cast<__half2*>(&f5);
        __half2 h23 = *reinterpret_cast<__half2*>(&f6);
        float4 ae4 = make_float4(__low2float(h01), __high2float(h01),
                                 __low2float(h23), __high2float(h23));
        const float* ap = asg + (size_t)src * 8;
        float4 as4 = *reinterpret_cast<const float4*>(ap);
        float4 g4  = *reinterpret_cast<const float4*>(ap + 4);
        float e0 = __expf(lrelu(as4.x + ad4.x + ae4.x));
        float e1 = __expf(lrelu(as4.y + ad4.y + ae4.y));
        float e2 = __expf(lrelu(as4.z + ad4.z + ae4.z));
        float e3 = __expf(lrelu(as4.w + ad4.w + ae4.w));
        dsum.x += e0; dsum.y += e1; dsum.z += e2; dsum.w += e3;
        gsum.x += e0 * g4.x; gsum.y += e1 * g4.y; gsum.z += e2 * g4.z; gsum.w += e3 * g4.w;
        aesum.x += ae4.x; aesum.y += ae4.y; aesum.z += ae4.z; aesum.w += ae4.w;
    }
#pragma unroll
    for (int m = 1; m < 16; m <<= 1) {
        dsum.x += __shfl_xor(dsum.x, m, 16);  dsum.y += __shfl_xor(dsum.y, m, 16);
        dsum.z += __shfl_xor(dsum.z, m, 16);  dsum.w += __shfl_xor(dsum.w, m, 16);
        gsum.x += __shfl_xor(gsum.x, m, 16);  gsum.y += __shfl_xor(gsum.y, m, 16);
        gsum.z += __shfl_xor(gsum.z, m, 16);  gsum.w += __shfl_xor(gsum.w, m, 16);
        aesum.x += __shfl_xor(aesum.x, m, 16); aesum.y += __shfl_xor(aesum.y, m, 16);
        aesum.z += __shfl_xor(aesum.z, m, 16); aesum.w += __shfl_xor(aesum.w, m, 16);
    }
    if (g16 == 0) {
        float deg = fmaxf((float)(e - s), 1.f);
        const float* ap = asg + (size_t)node * 8;
        float4 mas = *reinterpret_cast<const float4*>(ap);
        float4 mg  = *reinterpret_cast<const float4*>(ap + 4);
        float r = cbias[0];
        float e0;
        e0 = __expf(lrelu(mas.x + ad4.x + aesum.x / deg)); r += (gsum.x + e0 * mg.x) / (dsum.x + e0);
        e0 = __expf(lrelu(mas.y + ad4.y + aesum.y / deg)); r += (gsum.y + e0 * mg.y) / (dsum.y + e0);
        e0 = __expf(lrelu(mas.z + ad4.z + aesum.z / deg)); r += (gsum.z + e0 * mg.z) / (dsum.z + e0);
        e0 = __expf(lrelu(mas.w + ad4.w + aesum.w / deg)); r += (gsum.w + e0 * mg.w) / (dsum.w + e0);
        out[node] = r;
    }
}

// ---------------------------------------------------------------------------
extern "C" void kernel_launch(void* const* d_in, const int* in_sizes, int n_in,
                              void* d_out, int out_size, void* d_ws, size_t ws_size,
                              hipStream_t stream) {
    (void)in_sizes; (void)n_in; (void)out_size;
    const float* x    = (const float*)d_in[0];
    const float* ea   = (const float*)d_in[1];
    const float* W1   = (const float*)d_in[2];
    const float* as1  = (const float*)d_in[3];
    const float* ad1  = (const float*)d_in[4];
    const float* We1  = (const float*)d_in[5];
    const float* ae1  = (const float*)d_in[6];
    const float* b1   = (const float*)d_in[7];
    const float* W2   = (const float*)d_in[8];
    const float* as2  = (const float*)d_in[9];
    const float* ad2  = (const float*)d_in[10];
    const float* We2  = (const float*)d_in[11];
    const float* ae2  = (const float*)d_in[12];
    const float* b2   = (const float*)d_in[13];
    const float* linw = (const float*)d_in[14];
    const float* linb = (const float*)d_in[15];
    const int*   ei   = (const int*)d_in[16];
    float* out = (float*)d_out;
    float* ws  = (float*)d_ws;

    const int SCAN_BLK = (N_NODES + 1023) / 1024; // 49

    size_t off = 0;
    __half* h1p  = (__half*)(ws + off); off += (size_t)N_NODES * K_DIM / 2; // fp16
    float* asn1  = ws + off; off += (size_t)N_NODES * 4;
    float* adn1  = ws + off; off += (size_t)N_NODES * 4;
    float* asg2  = ws + off; off += (size_t)N_NODES * 8;
    float* adn2  = ws + off; off += (size_t)N_NODES * 4;
    float* vbuf  = ws + off; off += 512;
    float* ubuf  = ws + off; off += 12 * K_DIM;
    float* cbias = ws + off; off += 64;
    int* starts  = (int*)(ws + off); off += (size_t)N_NODES + 8;
    int* bsum    = (int*)(ws + off); off += 64;
    int* rank    = (int*)(ws + off); off += (size_t)N_EDGES;
    // pad to 8-float (32 B) boundary for el records
    off = (off + 7) & ~(size_t)7;
    float* el    = ws + off; off += (size_t)N_EDGES * 8; // 32 B fp16 records
    int* cnt     = (int*)(ws + off); off += (size_t)N_NODES;

    if (ws_size < off * sizeof(float)) return; // workspace too small: fail visibly

    hipMemsetAsync(cnt, 0, N_NODES * sizeof(int), stream);

    kc_fold<<<N_EDGES / 256 + 1, 256, 0, stream>>>(ei, cnt, rank, We1, ae1, We2, ae2,
                                                   as2, ad2, W2, b2, linw, linb,
                                                   vbuf, ubuf, cbias);
    k2a_bsum<<<SCAN_BLK, 1024, 0, stream>>>(cnt, bsum);
    k2b_scan<<<SCAN_BLK, 1024, 0, stream>>>(cnt, bsum, starts, SCAN_BLK);
    k4_proj1<<<(N_NODES + 31) / 32, 256, 0, stream>>>(x, W1, as1, ad1, h1p, asn1, adn1);
    k1_fused<<<N_EDGES / 256, 256, 0, stream>>>(ea, vbuf, ei, rank, starts, asn1,
                                                (float4*)el);
    k5_fused<<<N_NODES / 4, 256, 0, stream>>>(starts, el, asn1, adn1, h1p, b1,
                                              ubuf, asg2, adn2);
    k7_l2<<<(N_NODES + 15) / 16, 256, 0, stream>>>(starts, el, asg2, adn2, cbias, out);
}